// Round 1
// baseline (3488.074 us; speedup 1.0000x reference)
//
#include <hip/hip_runtime.h>
#include <hip/hip_bf16.h>
#include <math.h>

// Problem constants
#define B_    2
#define T_    2048
#define HID_  2048
#define H_    16
#define DK_   64
#define DV_   128
#define CC    16
#define NCHUNK (T_/CC)     // 128
#define M_    (B_*T_)      // 4096
#define SCALE_ 0.125f      // DK^-0.5

// ---------------- generic f32 GEMM: C[M,N] = A[M,K] @ B[K,N], row-major ----------------
// Requires M%64==0, N%64==0, K%16==0 (true for all shapes here).
__global__ __launch_bounds__(256) void gemm_f32(const float* __restrict__ A,
                                                const float* __restrict__ Bm,
                                                float* __restrict__ C,
                                                int M, int N, int K) {
  __shared__ float As[64][17];   // [row][k] pad to kill bank conflicts
  __shared__ float Bs[16][64];   // [k][col]
  const int tx = threadIdx.x & 15;
  const int ty = threadIdx.x >> 4;
  const int row0 = blockIdx.y * 64;
  const int col0 = blockIdx.x * 64;
  float acc[4][4] = {{0.f,0.f,0.f,0.f},{0.f,0.f,0.f,0.f},{0.f,0.f,0.f,0.f},{0.f,0.f,0.f,0.f}};
  for (int k0 = 0; k0 < K; k0 += 16) {
    #pragma unroll
    for (int i = threadIdx.x; i < 1024; i += 256) {
      int r = i >> 4, kk = i & 15;
      As[r][kk] = A[(size_t)(row0 + r) * K + (k0 + kk)];
    }
    #pragma unroll
    for (int i = threadIdx.x; i < 1024; i += 256) {
      int kk = i >> 6, c = i & 63;
      Bs[kk][c] = Bm[(size_t)(k0 + kk) * N + (col0 + c)];
    }
    __syncthreads();
    #pragma unroll
    for (int kk = 0; kk < 16; ++kk) {
      float a0 = As[ty*4+0][kk];
      float a1 = As[ty*4+1][kk];
      float a2 = As[ty*4+2][kk];
      float a3 = As[ty*4+3][kk];
      float4 b4 = *reinterpret_cast<const float4*>(&Bs[kk][tx<<2]);
      acc[0][0] = fmaf(a0,b4.x,acc[0][0]); acc[0][1] = fmaf(a0,b4.y,acc[0][1]);
      acc[0][2] = fmaf(a0,b4.z,acc[0][2]); acc[0][3] = fmaf(a0,b4.w,acc[0][3]);
      acc[1][0] = fmaf(a1,b4.x,acc[1][0]); acc[1][1] = fmaf(a1,b4.y,acc[1][1]);
      acc[1][2] = fmaf(a1,b4.z,acc[1][2]); acc[1][3] = fmaf(a1,b4.w,acc[1][3]);
      acc[2][0] = fmaf(a2,b4.x,acc[2][0]); acc[2][1] = fmaf(a2,b4.y,acc[2][1]);
      acc[2][2] = fmaf(a2,b4.z,acc[2][2]); acc[2][3] = fmaf(a2,b4.w,acc[2][3]);
      acc[3][0] = fmaf(a3,b4.x,acc[3][0]); acc[3][1] = fmaf(a3,b4.y,acc[3][1]);
      acc[3][2] = fmaf(a3,b4.z,acc[3][2]); acc[3][3] = fmaf(a3,b4.w,acc[3][3]);
    }
    __syncthreads();
  }
  #pragma unroll
  for (int i = 0; i < 4; ++i) {
    #pragma unroll
    for (int j = 0; j < 4; ++j) {
      C[(size_t)(row0 + ty*4 + i) * N + (col0 + tx*4 + j)] = acc[i][j];
    }
  }
}

// ---------------- low-rank gate, stage 1: t1[row][j] = x[row,:] @ Wgk1[:,j], j<16 ----------
__global__ __launch_bounds__(256) void lr1_kernel(const float* __restrict__ x,
                                                  const float* __restrict__ w1,
                                                  float* __restrict__ t1) {
  __shared__ float part[16][17];
  const int row = blockIdx.x;
  const int j = threadIdx.x & 15;
  const int p = threadIdx.x >> 4;
  const float* xr = x + (size_t)row * HID_;
  float acc = 0.f;
  const int k0 = p * 128;
  for (int kk = k0; kk < k0 + 128; ++kk)
    acc = fmaf(xr[kk], w1[kk * 16 + j], acc);
  part[p][j] = acc;
  __syncthreads();
  if (threadIdx.x < 16) {
    float s = 0.f;
    #pragma unroll
    for (int pp = 0; pp < 16; ++pp) s += part[pp][threadIdx.x];
    t1[(size_t)row * 16 + threadIdx.x] = s;
  }
}

// ---------------- low-rank gate, stage 2: gk = log_sigmoid(t1 @ Wgk2 + b) / 16 -------------
__global__ __launch_bounds__(256) void lr2_kernel(const float* __restrict__ t1,
                                                  const float* __restrict__ w2,
                                                  const float* __restrict__ bias,
                                                  float* __restrict__ gkout) {
  __shared__ float tr[16];
  const int row = blockIdx.x;
  if (threadIdx.x < 16) tr[threadIdx.x] = t1[(size_t)row * 16 + threadIdx.x];
  __syncthreads();
  for (int n = threadIdx.x; n < H_*DK_; n += 256) {
    float acc = bias[n];
    #pragma unroll
    for (int j = 0; j < 16; ++j) acc = fmaf(tr[j], w2[j * (H_*DK_) + n], acc);
    float z = acc;
    // log_sigmoid(z) = min(z,0) - log1p(exp(-|z|))
    float ls = fminf(z, 0.f) - log1pf(expf(-fabsf(z)));
    gkout[(size_t)row * (H_*DK_) + n] = ls * (1.f / 16.f);
  }
}

// ---------------- chunked GLA scan --------------------------------------------------------
// grid: B*H*4 blocks; block handles (b, h, 32-wide slice of DV). State S[64][32] in LDS.
__global__ __launch_bounds__(256) void gla_kernel(const float* __restrict__ q,
                                                  const float* __restrict__ k,
                                                  const float* __restrict__ v,
                                                  const float* __restrict__ gk,
                                                  float* __restrict__ o) {
  const int VS = 32;
  const int vs = blockIdx.x & 3;
  const int h  = (blockIdx.x >> 2) & 15;
  const int b  = blockIdx.x >> 6;
  __shared__ float S [64][32];
  __shared__ float gc[16][65];
  __shared__ float qe[16][65];
  __shared__ float ke[16][65];
  __shared__ float kd[16][65];
  __shared__ float vv[16][32];
  __shared__ float Am[16][17];
  const int t = threadIdx.x;
  for (int i = t; i < 64*VS; i += 256) S[i >> 5][i & 31] = 0.f;

  for (int ch = 0; ch < NCHUNK; ++ch) {
    __syncthreads();  // protect gc/qe/ke/kd/vv from prior iteration's readers
    // cumsum of gk within chunk (per d)
    if (t < 64) {
      float acc = 0.f;
      #pragma unroll
      for (int c = 0; c < CC; ++c) {
        size_t idx = ((size_t)(b*T_ + ch*CC + c)) * (H_*DK_) + h*DK_ + t;
        acc += gk[idx];
        gc[c][t] = acc;
      }
    }
    __syncthreads();
    // qe / ke / k_dec
    for (int i = t; i < CC*DK_; i += 256) {
      int c = i >> 6, d = i & 63;
      size_t idx = ((size_t)(b*T_ + ch*CC + c)) * (H_*DK_) + h*DK_ + d;
      float gcv = gc[c][d];
      float gl  = gc[CC-1][d];
      float qv  = q[idx];
      float kvl = k[idx];
      qe[c][d] = qv * expf(gcv) * SCALE_;
      ke[c][d] = kvl * expf(-gcv);
      kd[c][d] = kvl * expf(gl - gcv);
    }
    // v slice
    for (int i = t; i < CC*VS; i += 256) {
      int c = i >> 5, e = i & 31;
      size_t idx = ((size_t)(b*T_ + ch*CC + c)) * (H_*DV_) + h*DV_ + vs*VS + e;
      vv[c][e] = v[idx];
    }
    __syncthreads();
    // A = tril(qe @ ke^T)
    {
      int c = t >> 4, m = t & 15;
      float a = 0.f;
      if (m <= c) {
        #pragma unroll
        for (int d = 0; d < DK_; ++d) a = fmaf(qe[c][d], ke[m][d], a);
      }
      Am[c][m] = a;
    }
    __syncthreads();
    // o = qe @ S  +  A @ v
    for (int i = t; i < CC*VS; i += 256) {
      int c = i >> 5, e = i & 31;
      float acc = 0.f;
      #pragma unroll
      for (int d = 0; d < DK_; ++d) acc = fmaf(qe[c][d], S[d][e], acc);
      for (int m = 0; m <= c; ++m) acc = fmaf(Am[c][m], vv[m][e], acc);
      size_t idx = ((size_t)(b*T_ + ch*CC + c)) * (H_*DV_) + h*DV_ + vs*VS + e;
      o[idx] = acc;
    }
    __syncthreads();
    // S = diag(exp(g_last)) S + k_dec^T @ v
    for (int i = t; i < DK_*VS; i += 256) {
      int d = i >> 5, e = i & 31;
      float dec = expf(gc[CC-1][d]);
      float s = S[d][e] * dec;
      #pragma unroll
      for (int c = 0; c < CC; ++c) s = fmaf(kd[c][d], vv[c][e], s);
      S[d][e] = s;
    }
  }
}

// ---------------- fused RMSNorm(DV) * norm_w * SiLU(g) ------------------------------------
__global__ __launch_bounds__(256) void epilogue_kernel(const float* __restrict__ o,
                                                       const float* __restrict__ g,
                                                       const float* __restrict__ norm_w,
                                                       float* __restrict__ y) {
  const int row  = blockIdx.x;
  const int wave = threadIdx.x >> 6;
  const int lane = threadIdx.x & 63;
  #pragma unroll
  for (int it = 0; it < 4; ++it) {
    const int h = it * 4 + wave;
    const size_t base = (size_t)row * (H_*DV_) + (size_t)h * DV_;
    float o0 = o[base + lane];
    float o1 = o[base + 64 + lane];
    float ss = o0*o0 + o1*o1;
    #pragma unroll
    for (int off = 32; off > 0; off >>= 1) ss += __shfl_xor(ss, off, 64);
    float inv = rsqrtf(ss * (1.f/128.f) + 1e-5f);
    float g0 = g[base + lane];
    float g1 = g[base + 64 + lane];
    float s0 = g0 / (1.f + expf(-g0));
    float s1 = g1 / (1.f + expf(-g1));
    y[base + lane]      = o0 * inv * norm_w[lane]      * s0;
    y[base + 64 + lane] = o1 * inv * norm_w[64 + lane] * s1;
  }
}

// ------------------------------------------------------------------------------------------
extern "C" void kernel_launch(void* const* d_in, const int* in_sizes, int n_in,
                              void* d_out, int out_size, void* d_ws, size_t ws_size,
                              hipStream_t stream) {
  const float* x      = (const float*)d_in[0];
  const float* Wq     = (const float*)d_in[1];
  const float* Wk     = (const float*)d_in[2];
  const float* Wv     = (const float*)d_in[3];
  const float* Wg     = (const float*)d_in[4];
  const float* Wgk1   = (const float*)d_in[5];
  const float* Wgk2   = (const float*)d_in[6];
  const float* bgk2   = (const float*)d_in[7];
  const float* Wo     = (const float*)d_in[8];
  const float* norm_w = (const float*)d_in[9];
  float* out = (float*)d_out;
  float* ws  = (float*)d_ws;

  // ws layout (float elements)
  const size_t MQ = (size_t)M_ * (H_*DK_);   // 4096*1024
  const size_t MV = (size_t)M_ * (H_*DV_);   // 4096*2048
  float* q   = ws;                // [0,      4.19M)
  float* k   = ws + MQ;           // [4.19M,  8.39M)
  float* gkb = ws + 2*MQ;         // [8.39M, 12.58M)
  float* v   = ws + 3*MQ;         // [12.58M, 20.97M)
  float* g   = v + MV;            // [20.97M, 29.36M)
  float* o   = g + MV;            // [29.36M, 37.75M)
  float* t1  = o + MV;            // [37.75M, +65536)
  float* y   = ws;                // reuse q,k region (dead after gla)

  dim3 blk(256);
  gemm_f32<<<dim3((H_*DK_)/64, M_/64), blk, 0, stream>>>(x, Wq, q, M_, H_*DK_, HID_);
  gemm_f32<<<dim3((H_*DK_)/64, M_/64), blk, 0, stream>>>(x, Wk, k, M_, H_*DK_, HID_);
  gemm_f32<<<dim3((H_*DV_)/64, M_/64), blk, 0, stream>>>(x, Wv, v, M_, H_*DV_, HID_);
  gemm_f32<<<dim3((H_*DV_)/64, M_/64), blk, 0, stream>>>(x, Wg, g, M_, H_*DV_, HID_);
  lr1_kernel<<<M_, 256, 0, stream>>>(x, Wgk1, t1);
  lr2_kernel<<<M_, 256, 0, stream>>>(t1, Wgk2, bgk2, gkb);
  gla_kernel<<<B_*H_*4, 256, 0, stream>>>(q, k, v, gkb, o);
  epilogue_kernel<<<M_, 256, 0, stream>>>(o, g, norm_w, y);
  gemm_f32<<<dim3(HID_/64, M_/64), blk, 0, stream>>>(y, Wo, out, M_, HID_, HID_);
}

// Round 2
// 1142.590 us; speedup vs baseline: 3.0528x; 3.0528x over previous
//
#include <hip/hip_runtime.h>
#include <hip/hip_bf16.h>
#include <math.h>

// Problem constants
#define B_    2
#define T_    2048
#define HID_  2048
#define H_    16
#define DK_   64
#define DV_   128
#define CC    16
#define NCHUNK (T_/CC)     // 128
#define M_    (B_*T_)      // 4096
#define SCALE_ 0.125f      // DK^-0.5

typedef __attribute__((ext_vector_type(8))) __bf16 bf16x8;
typedef __attribute__((ext_vector_type(4))) float f32x4;

__device__ __forceinline__ unsigned short f2bf(float f) {
  unsigned int u = __float_as_uint(f);
  u += 0x7fff + ((u >> 16) & 1);   // RNE
  return (unsigned short)(u >> 16);
}

typedef const __attribute__((address_space(1))) void* as1cv;
typedef __attribute__((address_space(3))) void* as3v;
__device__ __forceinline__ void gload16(const void* g, void* l) {
  __builtin_amdgcn_global_load_lds((as1cv)g, (as3v)l, 16, 0, 0);
}

// ---------------- f32 -> bf16 convert (vectorized) ----------------------------------------
__global__ __launch_bounds__(256) void convert_f32_bf16(const float* __restrict__ in,
                                                        unsigned short* __restrict__ out,
                                                        int n4) {
  int i = blockIdx.x * 256 + threadIdx.x;
  if (i >= n4) return;
  float4 f = reinterpret_cast<const float4*>(in)[i];
  ushort4 u;
  u.x = f2bf(f.x); u.y = f2bf(f.y); u.z = f2bf(f.z); u.w = f2bf(f.w);
  reinterpret_cast<ushort4*>(out)[i] = u;
}

// ---------------- transpose + convert: in[K][N] f32 -> out[N][K] bf16 ---------------------
__global__ __launch_bounds__(256) void transpose_f32_bf16(const float* __restrict__ in,
                                                          unsigned short* __restrict__ out,
                                                          int K, int N) {
  __shared__ float tile[32][33];
  const int n0 = blockIdx.x * 32;
  const int k0 = blockIdx.y * 32;
  const int tx = threadIdx.x & 31;
  const int ty = threadIdx.x >> 5;
  #pragma unroll
  for (int i = 0; i < 4; ++i)
    tile[ty + i*8][tx] = in[(size_t)(k0 + ty + i*8) * N + n0 + tx];
  __syncthreads();
  #pragma unroll
  for (int i = 0; i < 4; ++i) {
    int r = ty + i*8;
    out[(size_t)(n0 + r) * K + k0 + tx] = f2bf(tile[tx][r]);
  }
}

// ---------------- bf16 MFMA GEMM: C[M,N] = A[M,K] @ Bt[N,K]^T, m97 structure --------------
// 128x128 tile, BK=32, 4 waves (2x2 of 64x64), 16x16x32 MFMA, global_load_lds width 16.
__global__ __launch_bounds__(256) void gemm_bf16(const unsigned short* __restrict__ A,
                                                 const unsigned short* __restrict__ Bt,
                                                 float* __restrict__ C,
                                                 int M, int N, int K) {
  __shared__ unsigned short As[128 * 32];
  __shared__ unsigned short Bs[128 * 32];
  const int t    = threadIdx.x;
  const int lane = t & 63;
  const int w    = t >> 6;
  const int wr   = w >> 1, wc = w & 1;
  const int row0 = blockIdx.y * 128;
  const int col0 = blockIdx.x * 128;
  const int lr   = lane & 15;     // row-in-16 (A) / col-in-16 (B,D)
  const int lk   = lane >> 4;     // k-quarter: k0 = lk*8

  f32x4 acc[4][4];
  #pragma unroll
  for (int m = 0; m < 4; ++m)
    #pragma unroll
    for (int n = 0; n < 4; ++n) acc[m][n] = (f32x4){0.f, 0.f, 0.f, 0.f};

  for (int k0 = 0; k0 < K; k0 += 32) {
    #pragma unroll
    for (int i = 0; i < 2; ++i) {
      int off = (i * 256 + t) * 16;   // byte offset in 8KB tile
      int r   = off >> 6;             // tile row (64B per row)
      int cb  = off & 63;             // byte within row
      gload16((const char*)A + ((size_t)(row0 + r) * K + k0) * 2 + cb, (char*)As + off);
    }
    #pragma unroll
    for (int i = 0; i < 2; ++i) {
      int off = (i * 256 + t) * 16;
      int r   = off >> 6;
      int cb  = off & 63;
      gload16((const char*)Bt + ((size_t)(col0 + r) * K + k0) * 2 + cb, (char*)Bs + off);
    }
    __syncthreads();
    bf16x8 fa[4], fb[4];
    #pragma unroll
    for (int m = 0; m < 4; ++m)
      fa[m] = *(const bf16x8*)((const char*)As + ((wr*64 + m*16 + lr) * 32 + lk*8) * 2);
    #pragma unroll
    for (int n = 0; n < 4; ++n)
      fb[n] = *(const bf16x8*)((const char*)Bs + ((wc*64 + n*16 + lr) * 32 + lk*8) * 2);
    #pragma unroll
    for (int m = 0; m < 4; ++m)
      #pragma unroll
      for (int n = 0; n < 4; ++n)
        acc[m][n] = __builtin_amdgcn_mfma_f32_16x16x32_bf16(fa[m], fb[n], acc[m][n], 0, 0, 0);
    __syncthreads();
  }
  #pragma unroll
  for (int m = 0; m < 4; ++m) {
    int row = row0 + wr*64 + m*16 + lk*4;
    #pragma unroll
    for (int n = 0; n < 4; ++n) {
      int col = col0 + wc*64 + n*16 + lr;
      #pragma unroll
      for (int j = 0; j < 4; ++j)
        C[(size_t)(row + j) * N + col] = acc[m][n][j];
    }
  }
}

// ---------------- low-rank gate, stage 1 --------------------------------------------------
__global__ __launch_bounds__(256) void lr1_kernel(const float* __restrict__ x,
                                                  const float* __restrict__ w1,
                                                  float* __restrict__ t1) {
  __shared__ float part[16][17];
  const int row = blockIdx.x;
  const int j = threadIdx.x & 15;
  const int p = threadIdx.x >> 4;
  const float* xr = x + (size_t)row * HID_;
  float acc = 0.f;
  const int k0 = p * 128;
  for (int kk = k0; kk < k0 + 128; ++kk)
    acc = fmaf(xr[kk], w1[kk * 16 + j], acc);
  part[p][j] = acc;
  __syncthreads();
  if (threadIdx.x < 16) {
    float s = 0.f;
    #pragma unroll
    for (int pp = 0; pp < 16; ++pp) s += part[pp][threadIdx.x];
    t1[(size_t)row * 16 + threadIdx.x] = s;
  }
}

// ---------------- low-rank gate, stage 2 --------------------------------------------------
__global__ __launch_bounds__(256) void lr2_kernel(const float* __restrict__ t1,
                                                  const float* __restrict__ w2,
                                                  const float* __restrict__ bias,
                                                  float* __restrict__ gkout) {
  __shared__ float tr[16];
  const int row = blockIdx.x;
  if (threadIdx.x < 16) tr[threadIdx.x] = t1[(size_t)row * 16 + threadIdx.x];
  __syncthreads();
  for (int n = threadIdx.x; n < H_*DK_; n += 256) {
    float acc = bias[n];
    #pragma unroll
    for (int j = 0; j < 16; ++j) acc = fmaf(tr[j], w2[j * (H_*DK_) + n], acc);
    float z = acc;
    float ls = fminf(z, 0.f) - log1pf(expf(-fabsf(z)));
    gkout[(size_t)row * (H_*DK_) + n] = ls * (1.f / 16.f);
  }
}

// ---------------- chunked GLA scan --------------------------------------------------------
// qk: [M][2048] (q cols 0..1023, k cols 1024..2047); vg: [M][4096] (v cols 0..2047)
__global__ __launch_bounds__(256) void gla_kernel(const float* __restrict__ qk,
                                                  const float* __restrict__ vg,
                                                  const float* __restrict__ gk,
                                                  float* __restrict__ o) {
  const int VS = 32;
  const int vs = blockIdx.x & 3;
  const int h  = (blockIdx.x >> 2) & 15;
  const int b  = blockIdx.x >> 6;
  __shared__ float S [64][32];
  __shared__ float gc[16][65];
  __shared__ float qe[16][65];
  __shared__ float ke[16][65];
  __shared__ float kd[16][65];
  __shared__ float vv[16][32];
  __shared__ float Am[16][17];
  const int t = threadIdx.x;
  for (int i = t; i < 64*VS; i += 256) S[i >> 5][i & 31] = 0.f;

  for (int ch = 0; ch < NCHUNK; ++ch) {
    __syncthreads();
    if (t < 64) {
      float acc = 0.f;
      #pragma unroll
      for (int c = 0; c < CC; ++c) {
        size_t idx = ((size_t)(b*T_ + ch*CC + c)) * (H_*DK_) + h*DK_ + t;
        acc += gk[idx];
        gc[c][t] = acc;
      }
    }
    __syncthreads();
    for (int i = t; i < CC*DK_; i += 256) {
      int c = i >> 6, d = i & 63;
      size_t idx = ((size_t)(b*T_ + ch*CC + c)) * 2048 + h*DK_ + d;
      float gcv = gc[c][d];
      float gl  = gc[CC-1][d];
      float qv  = qk[idx];
      float kvl = qk[idx + 1024];
      qe[c][d] = qv * expf(gcv) * SCALE_;
      ke[c][d] = kvl * expf(-gcv);
      kd[c][d] = kvl * expf(gl - gcv);
    }
    for (int i = t; i < CC*VS; i += 256) {
      int c = i >> 5, e = i & 31;
      size_t idx = ((size_t)(b*T_ + ch*CC + c)) * 4096 + h*DV_ + vs*VS + e;
      vv[c][e] = vg[idx];
    }
    __syncthreads();
    {
      int c = t >> 4, m = t & 15;
      float a = 0.f;
      if (m <= c) {
        #pragma unroll
        for (int d = 0; d < DK_; ++d) a = fmaf(qe[c][d], ke[m][d], a);
      }
      Am[c][m] = a;
    }
    __syncthreads();
    for (int i = t; i < CC*VS; i += 256) {
      int c = i >> 5, e = i & 31;
      float acc = 0.f;
      #pragma unroll
      for (int d = 0; d < DK_; ++d) acc = fmaf(qe[c][d], S[d][e], acc);
      for (int m = 0; m <= c; ++m) acc = fmaf(Am[c][m], vv[m][e], acc);
      size_t idx = ((size_t)(b*T_ + ch*CC + c)) * 2048 + h*DV_ + vs*VS + e;
      o[idx] = acc;
    }
    __syncthreads();
    for (int i = t; i < DK_*VS; i += 256) {
      int d = i >> 5, e = i & 31;
      float dec = expf(gc[CC-1][d]);
      float s = S[d][e] * dec;
      #pragma unroll
      for (int c = 0; c < CC; ++c) s = fmaf(kd[c][d], vv[c][e], s);
      S[d][e] = s;
    }
  }
}

// ---------------- fused RMSNorm(DV) * norm_w * SiLU(g) -> bf16 y --------------------------
__global__ __launch_bounds__(256) void epilogue_kernel(const float* __restrict__ o,
                                                       const float* __restrict__ vg,
                                                       const float* __restrict__ norm_w,
                                                       unsigned short* __restrict__ yb) {
  const int row  = blockIdx.x;
  const int wave = threadIdx.x >> 6;
  const int lane = threadIdx.x & 63;
  #pragma unroll
  for (int it = 0; it < 4; ++it) {
    const int h = it * 4 + wave;
    const size_t ob = (size_t)row * 2048 + (size_t)h * DV_;
    const size_t gb = (size_t)row * 4096 + 2048 + (size_t)h * DV_;
    float o0 = o[ob + lane];
    float o1 = o[ob + 64 + lane];
    float ss = o0*o0 + o1*o1;
    #pragma unroll
    for (int off = 32; off > 0; off >>= 1) ss += __shfl_xor(ss, off, 64);
    float inv = rsqrtf(ss * (1.f/128.f) + 1e-5f);
    float g0 = vg[gb + lane];
    float g1 = vg[gb + 64 + lane];
    float s0 = g0 / (1.f + expf(-g0));
    float s1 = g1 / (1.f + expf(-g1));
    yb[ob + lane]      = f2bf(o0 * inv * norm_w[lane]      * s0);
    yb[ob + 64 + lane] = f2bf(o1 * inv * norm_w[64 + lane] * s1);
  }
}

// ------------------------------------------------------------------------------------------
extern "C" void kernel_launch(void* const* d_in, const int* in_sizes, int n_in,
                              void* d_out, int out_size, void* d_ws, size_t ws_size,
                              hipStream_t stream) {
  const float* x      = (const float*)d_in[0];
  const float* Wq     = (const float*)d_in[1];
  const float* Wk     = (const float*)d_in[2];
  const float* Wv     = (const float*)d_in[3];
  const float* Wg     = (const float*)d_in[4];
  const float* Wgk1   = (const float*)d_in[5];
  const float* Wgk2   = (const float*)d_in[6];
  const float* bgk2   = (const float*)d_in[7];
  const float* Wo     = (const float*)d_in[8];
  const float* norm_w = (const float*)d_in[9];
  float* out = (float*)d_out;
  float* ws  = (float*)d_ws;

  const size_t MQ = (size_t)M_ * 1024;   // 4194304
  const size_t MV = (size_t)M_ * 2048;   // 8388608

  float* qk  = ws;                       // [0, 8.39M) f32
  float* gkb = ws + 2*MQ;                // [8.39M, 12.58M)
  float* vg  = ws + 3*MQ;                // [12.58M, 29.36M)
  float* o   = ws + 3*MQ + 2*MV;         // [29.36M, 37.75M)
  float* t1  = o + MV;                   // [37.75M, +65536)

  // lifetime-disjoint aliases (all safe by stream order)
  unsigned short* xb   = (unsigned short*)gkb;            // dead before lr2 writes gkb
  unsigned short* WqkT = (unsigned short*)o;              // dead before gla writes o
  unsigned short* WvgT = (unsigned short*)(o + 2097152);  // dead before gla writes o
  unsigned short* yb   = (unsigned short*)ws;             // qk dead after gla
  unsigned short* WoT  = (unsigned short*)(ws + 4194304); // qk dead after gla

  dim3 blk(256);
  // x -> bf16
  convert_f32_bf16<<<dim3((2097152 + 255)/256), blk, 0, stream>>>(x, xb, 2097152);
  // weight transposes -> bf16 [N][K]
  transpose_f32_bf16<<<dim3(1024/32, 2048/32), blk, 0, stream>>>(Wq, WqkT, 2048, 1024);
  transpose_f32_bf16<<<dim3(1024/32, 2048/32), blk, 0, stream>>>(Wk, WqkT + (size_t)1024*2048, 2048, 1024);
  transpose_f32_bf16<<<dim3(2048/32, 2048/32), blk, 0, stream>>>(Wv, WvgT, 2048, 2048);
  transpose_f32_bf16<<<dim3(2048/32, 2048/32), blk, 0, stream>>>(Wg, WvgT + (size_t)2048*2048, 2048, 2048);
  // projections (bf16 MFMA)
  gemm_bf16<<<dim3(2048/128, 4096/128), blk, 0, stream>>>(xb, WqkT, qk, M_, 2048, HID_);
  gemm_bf16<<<dim3(4096/128, 4096/128), blk, 0, stream>>>(xb, WvgT, vg, M_, 4096, HID_);
  // gate path (f32-exact)
  lr1_kernel<<<M_, blk, 0, stream>>>(x, Wgk1, t1);
  lr2_kernel<<<M_, blk, 0, stream>>>(t1, Wgk2, bgk2, gkb);
  // GLA scan
  gla_kernel<<<B_*H_*4, blk, 0, stream>>>(qk, vg, gkb, o);
  // epilogue -> bf16 y
  epilogue_kernel<<<M_, blk, 0, stream>>>(o, vg, norm_w, yb);
  // output projection
  transpose_f32_bf16<<<dim3(2048/32, 2048/32), blk, 0, stream>>>(Wo, WoT, 2048, 2048);
  gemm_bf16<<<dim3(2048/128, 4096/128), blk, 0, stream>>>(yb, WoT, out, M_, HID_, HID_);
}

// Round 3
// 578.682 us; speedup vs baseline: 6.0276x; 1.9745x over previous
//
#include <hip/hip_runtime.h>
#include <hip/hip_bf16.h>
#include <math.h>

// Problem constants
#define B_    2
#define T_    2048
#define HID_  2048
#define H_    16
#define DK_   64
#define DV_   128
#define CC    16
#define NCHUNK (T_/CC)     // 128
#define NSEG  16           // segments per (b,h); 8 chunks each
#define M_    (B_*T_)      // 4096
#define SCALE_ 0.125f      // DK^-0.5

typedef __attribute__((ext_vector_type(8))) __bf16 bf16x8;
typedef __attribute__((ext_vector_type(4))) float f32x4;

__device__ __forceinline__ unsigned short f2bf(float f) {
  unsigned int u = __float_as_uint(f);
  u += 0x7fff + ((u >> 16) & 1);   // RNE
  return (unsigned short)(u >> 16);
}
__device__ __forceinline__ float bf2f(unsigned short u) {
  return __uint_as_float(((unsigned int)u) << 16);
}

typedef const __attribute__((address_space(1))) void* as1cv;
typedef __attribute__((address_space(3))) void* as3v;
__device__ __forceinline__ void gload16(const void* g, void* l) {
  __builtin_amdgcn_global_load_lds((as1cv)g, (as3v)l, 16, 0, 0);
}

// ---------------- f32 -> bf16 convert (vectorized) ----------------------------------------
__global__ __launch_bounds__(256) void convert_f32_bf16(const float* __restrict__ in,
                                                        unsigned short* __restrict__ out,
                                                        int n4) {
  int i = blockIdx.x * 256 + threadIdx.x;
  if (i >= n4) return;
  float4 f = reinterpret_cast<const float4*>(in)[i];
  ushort4 u;
  u.x = f2bf(f.x); u.y = f2bf(f.y); u.z = f2bf(f.z); u.w = f2bf(f.w);
  reinterpret_cast<ushort4*>(out)[i] = u;
}

// ---------------- transpose + convert: in[K][N] f32 -> out[N][K] bf16 ---------------------
__global__ __launch_bounds__(256) void transpose_f32_bf16(const float* __restrict__ in,
                                                          unsigned short* __restrict__ out,
                                                          int K, int N) {
  __shared__ float tile[32][33];
  const int n0 = blockIdx.x * 32;
  const int k0 = blockIdx.y * 32;
  const int tx = threadIdx.x & 31;
  const int ty = threadIdx.x >> 5;
  #pragma unroll
  for (int i = 0; i < 4; ++i)
    tile[ty + i*8][tx] = in[(size_t)(k0 + ty + i*8) * N + n0 + tx];
  __syncthreads();
  #pragma unroll
  for (int i = 0; i < 4; ++i) {
    int r = ty + i*8;
    out[(size_t)(n0 + r) * K + k0 + tx] = f2bf(tile[tx][r]);
  }
}

// ---------------- bf16 MFMA GEMM: C[M,N] = A[M,K] @ Bt[N,K]^T, m97 structure --------------
template<bool OBF>
__global__ __launch_bounds__(256) void gemm_bf16(const unsigned short* __restrict__ A,
                                                 const unsigned short* __restrict__ Bt,
                                                 void* __restrict__ Cv,
                                                 int M, int N, int K) {
  __shared__ unsigned short As[128 * 32];
  __shared__ unsigned short Bs[128 * 32];
  const int t    = threadIdx.x;
  const int lane = t & 63;
  const int w    = t >> 6;
  const int wr   = w >> 1, wc = w & 1;
  const int row0 = blockIdx.y * 128;
  const int col0 = blockIdx.x * 128;
  const int lr   = lane & 15;
  const int lk   = lane >> 4;

  f32x4 acc[4][4];
  #pragma unroll
  for (int m = 0; m < 4; ++m)
    #pragma unroll
    for (int n = 0; n < 4; ++n) acc[m][n] = (f32x4){0.f, 0.f, 0.f, 0.f};

  for (int k0 = 0; k0 < K; k0 += 32) {
    #pragma unroll
    for (int i = 0; i < 2; ++i) {
      int off = (i * 256 + t) * 16;
      int r   = off >> 6;
      int cb  = off & 63;
      gload16((const char*)A + ((size_t)(row0 + r) * K + k0) * 2 + cb, (char*)As + off);
    }
    #pragma unroll
    for (int i = 0; i < 2; ++i) {
      int off = (i * 256 + t) * 16;
      int r   = off >> 6;
      int cb  = off & 63;
      gload16((const char*)Bt + ((size_t)(col0 + r) * K + k0) * 2 + cb, (char*)Bs + off);
    }
    __syncthreads();
    bf16x8 fa[4], fb[4];
    #pragma unroll
    for (int m = 0; m < 4; ++m)
      fa[m] = *(const bf16x8*)((const char*)As + ((wr*64 + m*16 + lr) * 32 + lk*8) * 2);
    #pragma unroll
    for (int n = 0; n < 4; ++n)
      fb[n] = *(const bf16x8*)((const char*)Bs + ((wc*64 + n*16 + lr) * 32 + lk*8) * 2);
    #pragma unroll
    for (int m = 0; m < 4; ++m)
      #pragma unroll
      for (int n = 0; n < 4; ++n)
        acc[m][n] = __builtin_amdgcn_mfma_f32_16x16x32_bf16(fa[m], fb[n], acc[m][n], 0, 0, 0);
    __syncthreads();
  }
  #pragma unroll
  for (int m = 0; m < 4; ++m) {
    int row = row0 + wr*64 + m*16 + lk*4;
    #pragma unroll
    for (int n = 0; n < 4; ++n) {
      int col = col0 + wc*64 + n*16 + lr;
      #pragma unroll
      for (int j = 0; j < 4; ++j) {
        if (OBF) ((unsigned short*)Cv)[(size_t)(row + j) * N + col] = f2bf(acc[m][n][j]);
        else     ((float*)Cv)[(size_t)(row + j) * N + col] = acc[m][n][j];
      }
    }
  }
}

// ---------------- low-rank gate, stage 1 --------------------------------------------------
__global__ __launch_bounds__(256) void lr1_kernel(const float* __restrict__ x,
                                                  const float* __restrict__ w1,
                                                  float* __restrict__ t1) {
  __shared__ float part[16][17];
  const int row = blockIdx.x;
  const int j = threadIdx.x & 15;
  const int p = threadIdx.x >> 4;
  const float* xr = x + (size_t)row * HID_;
  float acc = 0.f;
  const int k0 = p * 128;
  for (int kk = k0; kk < k0 + 128; ++kk)
    acc = fmaf(xr[kk], w1[kk * 16 + j], acc);
  part[p][j] = acc;
  __syncthreads();
  if (threadIdx.x < 16) {
    float s = 0.f;
    #pragma unroll
    for (int pp = 0; pp < 16; ++pp) s += part[pp][threadIdx.x];
    t1[(size_t)row * 16 + threadIdx.x] = s;
  }
}

// ---------------- low-rank gate, stage 2 --------------------------------------------------
__global__ __launch_bounds__(256) void lr2_kernel(const float* __restrict__ t1,
                                                  const float* __restrict__ w2,
                                                  const float* __restrict__ bias,
                                                  float* __restrict__ gkout) {
  __shared__ float tr[16];
  const int row = blockIdx.x;
  if (threadIdx.x < 16) tr[threadIdx.x] = t1[(size_t)row * 16 + threadIdx.x];
  __syncthreads();
  for (int n = threadIdx.x; n < H_*DK_; n += 256) {
    float acc = bias[n];
    #pragma unroll
    for (int j = 0; j < 16; ++j) acc = fmaf(tr[j], w2[j * (H_*DK_) + n], acc);
    float z = acc;
    float ls = fminf(z, 0.f) - log1pf(expf(-fabsf(z)));
    gkout[(size_t)row * (H_*DK_) + n] = ls * (1.f / 16.f);
  }
}

// ---------------- GLA phase A: per-segment local state (from S=0) -------------------------
// block = (b, h, seg, vs). 8 chunks per segment. Writes S_local and segment decay.
__global__ __launch_bounds__(256) void gla_phase_a(const float* __restrict__ qk,
                                                   const unsigned short* __restrict__ vg,
                                                   const float* __restrict__ gk,
                                                   float* __restrict__ Sseg,
                                                   float* __restrict__ Dseg) {
  const int vs  = blockIdx.x & 3;
  const int seg = (blockIdx.x >> 2) & 15;
  const int h   = (blockIdx.x >> 6) & 15;
  const int b   = blockIdx.x >> 10;
  __shared__ float S [64][32];
  __shared__ float gc[16][65];
  __shared__ float kd[16][65];
  __shared__ float vv[16][32];
  const int t = threadIdx.x;
  for (int i = t; i < 64*32; i += 256) S[i >> 5][i & 31] = 0.f;
  float gt = 0.f;

  for (int c8 = 0; c8 < NCHUNK/NSEG; ++c8) {
    const int ch = seg * (NCHUNK/NSEG) + c8;
    __syncthreads();
    if (t < 64) {
      float acc = 0.f;
      #pragma unroll
      for (int c = 0; c < CC; ++c) {
        size_t idx = ((size_t)(b*T_ + ch*CC + c)) * 1024 + h*DK_ + t;
        acc += gk[idx];
        gc[c][t] = acc;
      }
      gt += acc;
    }
    __syncthreads();
    for (int i = t; i < CC*DK_; i += 256) {
      int c = i >> 6, d = i & 63;
      size_t idx = ((size_t)(b*T_ + ch*CC + c)) * 2048 + 1024 + h*DK_ + d;
      kd[c][d] = qk[idx] * expf(gc[CC-1][d] - gc[c][d]);
    }
    for (int i = t; i < CC*32; i += 256) {
      int c = i >> 5, e = i & 31;
      size_t idx = ((size_t)(b*T_ + ch*CC + c)) * 4096 + h*DV_ + vs*32 + e;
      vv[c][e] = bf2f(vg[idx]);
    }
    __syncthreads();
    for (int i = t; i < 64*32; i += 256) {
      int d = i >> 5, e = i & 31;
      float s = S[d][e] * expf(gc[CC-1][d]);
      #pragma unroll
      for (int c = 0; c < CC; ++c) s = fmaf(kd[c][d], vv[c][e], s);
      S[d][e] = s;
    }
  }
  __syncthreads();
  const size_t base = ((size_t)((b*H_ + h)*NSEG + seg)) * (DK_*DV_);
  for (int i = t; i < 64*32; i += 256)
    Sseg[base + (size_t)(i >> 5) * DV_ + vs*32 + (i & 31)] = S[i >> 5][i & 31];
  if (vs == 0 && t < 64)
    Dseg[(size_t)((b*H_ + h)*NSEG + seg) * DK_ + t] = expf(gt);
}

// ---------------- GLA phase B: sequential combine over segments (in place) ----------------
// Sseg[seg] : S_local -> S_in (state at segment start). 32 blocks (one per b,h).
__global__ __launch_bounds__(256) void gla_combine(float* __restrict__ Sseg,
                                                   const float* __restrict__ Dseg) {
  const int bh = blockIdx.x;
  const int t = threadIdx.x;
  __shared__ float Dl[64];
  float S_run[32];
  #pragma unroll
  for (int j = 0; j < 32; ++j) S_run[j] = 0.f;
  for (int seg = 0; seg < NSEG; ++seg) {
    const size_t base = ((size_t)bh*NSEG + seg) * (DK_*DV_);
    if (t < 64) Dl[t] = Dseg[((size_t)bh*NSEG + seg) * DK_ + t];
    __syncthreads();
    #pragma unroll
    for (int j = 0; j < 32; ++j) {
      int idx = j*256 + t;
      float sl = Sseg[base + idx];
      Sseg[base + idx] = S_run[j];
      S_run[j] = fmaf(Dl[idx >> 7], S_run[j], sl);
    }
    __syncthreads();
  }
}

// ---------------- GLA phase C: outputs, starting from S_in --------------------------------
__global__ __launch_bounds__(256) void gla_phase_c(const float* __restrict__ qk,
                                                   const unsigned short* __restrict__ vg,
                                                   const float* __restrict__ gk,
                                                   const float* __restrict__ Sseg,
                                                   float* __restrict__ o) {
  const int vs  = blockIdx.x & 3;
  const int seg = (blockIdx.x >> 2) & 15;
  const int h   = (blockIdx.x >> 6) & 15;
  const int b   = blockIdx.x >> 10;
  __shared__ float S [64][32];
  __shared__ float gc[16][65];
  __shared__ float qe[16][65];
  __shared__ float ke[16][65];
  __shared__ float kd[16][65];
  __shared__ float vv[16][32];
  __shared__ float Am[16][17];
  const int t = threadIdx.x;
  {
    const size_t base = ((size_t)((b*H_ + h)*NSEG + seg)) * (DK_*DV_);
    for (int i = t; i < 64*32; i += 256)
      S[i >> 5][i & 31] = Sseg[base + (size_t)(i >> 5) * DV_ + vs*32 + (i & 31)];
  }

  for (int c8 = 0; c8 < NCHUNK/NSEG; ++c8) {
    const int ch = seg * (NCHUNK/NSEG) + c8;
    __syncthreads();
    if (t < 64) {
      float acc = 0.f;
      #pragma unroll
      for (int c = 0; c < CC; ++c) {
        size_t idx = ((size_t)(b*T_ + ch*CC + c)) * 1024 + h*DK_ + t;
        acc += gk[idx];
        gc[c][t] = acc;
      }
    }
    __syncthreads();
    for (int i = t; i < CC*DK_; i += 256) {
      int c = i >> 6, d = i & 63;
      size_t idx = ((size_t)(b*T_ + ch*CC + c)) * 2048 + h*DK_ + d;
      float gcv = gc[c][d];
      float gl  = gc[CC-1][d];
      float qv  = qk[idx];
      float kvl = qk[idx + 1024];
      qe[c][d] = qv * expf(gcv) * SCALE_;
      ke[c][d] = kvl * expf(-gcv);
      kd[c][d] = kvl * expf(gl - gcv);
    }
    for (int i = t; i < CC*32; i += 256) {
      int c = i >> 5, e = i & 31;
      size_t idx = ((size_t)(b*T_ + ch*CC + c)) * 4096 + h*DV_ + vs*32 + e;
      vv[c][e] = bf2f(vg[idx]);
    }
    __syncthreads();
    {
      int c = t >> 4, m = t & 15;
      float a = 0.f;
      if (m <= c) {
        #pragma unroll
        for (int d = 0; d < DK_; ++d) a = fmaf(qe[c][d], ke[m][d], a);
      }
      Am[c][m] = a;
    }
    __syncthreads();
    for (int i = t; i < CC*32; i += 256) {
      int c = i >> 5, e = i & 31;
      float acc = 0.f;
      #pragma unroll
      for (int d = 0; d < DK_; ++d) acc = fmaf(qe[c][d], S[d][e], acc);
      for (int m = 0; m <= c; ++m) acc = fmaf(Am[c][m], vv[m][e], acc);
      size_t idx = ((size_t)(b*T_ + ch*CC + c)) * 2048 + h*DV_ + vs*32 + e;
      o[idx] = acc;
    }
    __syncthreads();
    for (int i = t; i < DK_*32; i += 256) {
      int d = i >> 5, e = i & 31;
      float s = S[d][e] * expf(gc[CC-1][d]);
      #pragma unroll
      for (int c = 0; c < CC; ++c) s = fmaf(kd[c][d], vv[c][e], s);
      S[d][e] = s;
    }
  }
}

// ---------------- fused RMSNorm(DV) * norm_w * SiLU(g) -> bf16 y --------------------------
__global__ __launch_bounds__(256) void epilogue_kernel(const float* __restrict__ o,
                                                       const unsigned short* __restrict__ vg,
                                                       const float* __restrict__ norm_w,
                                                       unsigned short* __restrict__ yb) {
  const int row  = blockIdx.x;
  const int wave = threadIdx.x >> 6;
  const int lane = threadIdx.x & 63;
  #pragma unroll
  for (int it = 0; it < 4; ++it) {
    const int h = it * 4 + wave;
    const size_t ob = (size_t)row * 2048 + (size_t)h * DV_;
    const size_t gb = (size_t)row * 4096 + 2048 + (size_t)h * DV_;
    float o0 = o[ob + lane];
    float o1 = o[ob + 64 + lane];
    float ss = o0*o0 + o1*o1;
    #pragma unroll
    for (int off = 32; off > 0; off >>= 1) ss += __shfl_xor(ss, off, 64);
    float inv = rsqrtf(ss * (1.f/128.f) + 1e-5f);
    float g0 = bf2f(vg[gb + lane]);
    float g1 = bf2f(vg[gb + 64 + lane]);
    float s0 = g0 / (1.f + expf(-g0));
    float s1 = g1 / (1.f + expf(-g1));
    yb[ob + lane]      = f2bf(o0 * inv * norm_w[lane]      * s0);
    yb[ob + 64 + lane] = f2bf(o1 * inv * norm_w[64 + lane] * s1);
  }
}

// ------------------------------------------------------------------------------------------
extern "C" void kernel_launch(void* const* d_in, const int* in_sizes, int n_in,
                              void* d_out, int out_size, void* d_ws, size_t ws_size,
                              hipStream_t stream) {
  const float* x      = (const float*)d_in[0];
  const float* Wq     = (const float*)d_in[1];
  const float* Wk     = (const float*)d_in[2];
  const float* Wv     = (const float*)d_in[3];
  const float* Wg     = (const float*)d_in[4];
  const float* Wgk1   = (const float*)d_in[5];
  const float* Wgk2   = (const float*)d_in[6];
  const float* bgk2   = (const float*)d_in[7];
  const float* Wo     = (const float*)d_in[8];
  const float* norm_w = (const float*)d_in[9];
  float* out = (float*)d_out;
  float* ws  = (float*)d_ws;

  // ws layout (float-element offsets)
  float*          qk   = ws;                               // [0, 8388608) f32 [M][2048] q|k
  float*          gkb  = ws + 8388608;                     // [8388608, 12582912) f32 [M][1024]
  unsigned short* vg   = (unsigned short*)(ws + 12582912); // 16.78M bf16 [M][4096] v|g (8388608 f-equiv)
  float*          o    = ws + 20971520;                    // [20971520, 29360128) f32 [M][2048]
  float*          Sseg = ws + 29360128;                    // 4194304 f32 [B*H*NSEG][64][128]
  float*          Dseg = ws + 33554432;                    // 32768 f32
  float*          t1   = ws + 33587200;                    // 65536 f32

  // lifetime-disjoint aliases (stream order makes these safe)
  unsigned short* xb   = (unsigned short*)gkb;             // dead before lr2 writes gkb
  unsigned short* WqkT = (unsigned short*)o;               // dead before phase C writes o
  unsigned short* WvgT = (unsigned short*)(o + 2097152);   // dead before phase C writes o
  unsigned short* yb   = (unsigned short*)ws;              // qk dead after phase C
  unsigned short* WoT  = (unsigned short*)(ws + 4194304);  // qk dead after phase C

  dim3 blk(256);
  convert_f32_bf16<<<dim3((2097152 + 255)/256), blk, 0, stream>>>(x, xb, 2097152);
  transpose_f32_bf16<<<dim3(1024/32, 2048/32), blk, 0, stream>>>(Wq, WqkT, 2048, 1024);
  transpose_f32_bf16<<<dim3(1024/32, 2048/32), blk, 0, stream>>>(Wk, WqkT + (size_t)1024*2048, 2048, 1024);
  transpose_f32_bf16<<<dim3(2048/32, 2048/32), blk, 0, stream>>>(Wv, WvgT, 2048, 2048);
  transpose_f32_bf16<<<dim3(2048/32, 2048/32), blk, 0, stream>>>(Wg, WvgT + (size_t)2048*2048, 2048, 2048);
  gemm_bf16<false><<<dim3(2048/128, 4096/128), blk, 0, stream>>>(xb, WqkT, qk, M_, 2048, HID_);
  gemm_bf16<true ><<<dim3(4096/128, 4096/128), blk, 0, stream>>>(xb, WvgT, vg, M_, 4096, HID_);
  lr1_kernel<<<M_, blk, 0, stream>>>(x, Wgk1, t1);
  lr2_kernel<<<M_, blk, 0, stream>>>(t1, Wgk2, bgk2, gkb);
  gla_phase_a<<<B_*H_*NSEG*4, blk, 0, stream>>>(qk, vg, gkb, Sseg, Dseg);
  gla_combine<<<B_*H_, blk, 0, stream>>>(Sseg, Dseg);
  gla_phase_c<<<B_*H_*NSEG*4, blk, 0, stream>>>(qk, vg, gkb, Sseg, o);
  epilogue_kernel<<<M_, blk, 0, stream>>>(o, vg, norm_w, yb);
  transpose_f32_bf16<<<dim3(2048/32, 2048/32), blk, 0, stream>>>(Wo, WoT, 2048, 2048);
  gemm_bf16<false><<<dim3(2048/128, 4096/128), blk, 0, stream>>>(yb, WoT, out, M_, HID_, HID_);
}

// Round 4
// 504.110 us; speedup vs baseline: 6.9193x; 1.1479x over previous
//
#include <hip/hip_runtime.h>
#include <hip/hip_bf16.h>
#include <math.h>

// Problem constants
#define B_    2
#define T_    2048
#define HID_  2048
#define H_    16
#define DK_   64
#define DV_   128
#define CC    16
#define NCHUNK (T_/CC)     // 128
#define NSEG  16           // segments per (b,h); 8 chunks each
#define M_    (B_*T_)      // 4096
#define SCALE_ 0.125f      // DK^-0.5

typedef __attribute__((ext_vector_type(8))) __bf16 bf16x8;
typedef __attribute__((ext_vector_type(4))) float f32x4;

__device__ __forceinline__ unsigned short f2bf(float f) {
  unsigned int u = __float_as_uint(f);
  u += 0x7fff + ((u >> 16) & 1);   // RNE
  return (unsigned short)(u >> 16);
}
__device__ __forceinline__ float bf2f(unsigned short u) {
  return __uint_as_float(((unsigned int)u) << 16);
}

typedef const __attribute__((address_space(1))) void* as1cv;
typedef __attribute__((address_space(3))) void* as3v;
__device__ __forceinline__ void gload16(const void* g, void* l) {
  __builtin_amdgcn_global_load_lds((as1cv)g, (as3v)l, 16, 0, 0);
}

// ---------------- f32 -> bf16 convert (vectorized) ----------------------------------------
__global__ __launch_bounds__(256) void convert_f32_bf16(const float* __restrict__ in,
                                                        unsigned short* __restrict__ out,
                                                        int n4) {
  int i = blockIdx.x * 256 + threadIdx.x;
  if (i >= n4) return;
  float4 f = reinterpret_cast<const float4*>(in)[i];
  ushort4 u;
  u.x = f2bf(f.x); u.y = f2bf(f.y); u.z = f2bf(f.z); u.w = f2bf(f.w);
  reinterpret_cast<ushort4*>(out)[i] = u;
}

// ---------------- transpose + convert: in[K][N] f32 -> out[N][K] bf16 ---------------------
__global__ __launch_bounds__(256) void transpose_f32_bf16(const float* __restrict__ in,
                                                          unsigned short* __restrict__ out,
                                                          int K, int N) {
  __shared__ float tile[32][33];
  const int n0 = blockIdx.x * 32;
  const int k0 = blockIdx.y * 32;
  const int tx = threadIdx.x & 31;
  const int ty = threadIdx.x >> 5;
  #pragma unroll
  for (int i = 0; i < 4; ++i)
    tile[ty + i*8][tx] = in[(size_t)(k0 + ty + i*8) * N + n0 + tx];
  __syncthreads();
  #pragma unroll
  for (int i = 0; i < 4; ++i) {
    int r = ty + i*8;
    out[(size_t)(n0 + r) * K + k0 + tx] = f2bf(tile[tx][r]);
  }
}

// ---------------- bf16 MFMA GEMM: C[M,N] = A[M,K] @ Bt[N,K]^T, m97 structure --------------
template<bool OBF>
__global__ __launch_bounds__(256) void gemm_bf16(const unsigned short* __restrict__ A,
                                                 const unsigned short* __restrict__ Bt,
                                                 void* __restrict__ Cv,
                                                 int M, int N, int K) {
  __shared__ unsigned short As[128 * 32];
  __shared__ unsigned short Bs[128 * 32];
  const int t    = threadIdx.x;
  const int lane = t & 63;
  const int w    = t >> 6;
  const int wr   = w >> 1, wc = w & 1;
  const int row0 = blockIdx.y * 128;
  const int col0 = blockIdx.x * 128;
  const int lr   = lane & 15;
  const int lk   = lane >> 4;

  f32x4 acc[4][4];
  #pragma unroll
  for (int m = 0; m < 4; ++m)
    #pragma unroll
    for (int n = 0; n < 4; ++n) acc[m][n] = (f32x4){0.f, 0.f, 0.f, 0.f};

  for (int k0 = 0; k0 < K; k0 += 32) {
    #pragma unroll
    for (int i = 0; i < 2; ++i) {
      int off = (i * 256 + t) * 16;
      int r   = off >> 6;
      int cb  = off & 63;
      gload16((const char*)A + ((size_t)(row0 + r) * K + k0) * 2 + cb, (char*)As + off);
    }
    #pragma unroll
    for (int i = 0; i < 2; ++i) {
      int off = (i * 256 + t) * 16;
      int r   = off >> 6;
      int cb  = off & 63;
      gload16((const char*)Bt + ((size_t)(col0 + r) * K + k0) * 2 + cb, (char*)Bs + off);
    }
    __syncthreads();
    bf16x8 fa[4], fb[4];
    #pragma unroll
    for (int m = 0; m < 4; ++m)
      fa[m] = *(const bf16x8*)((const char*)As + ((wr*64 + m*16 + lr) * 32 + lk*8) * 2);
    #pragma unroll
    for (int n = 0; n < 4; ++n)
      fb[n] = *(const bf16x8*)((const char*)Bs + ((wc*64 + n*16 + lr) * 32 + lk*8) * 2);
    #pragma unroll
    for (int m = 0; m < 4; ++m)
      #pragma unroll
      for (int n = 0; n < 4; ++n)
        acc[m][n] = __builtin_amdgcn_mfma_f32_16x16x32_bf16(fa[m], fb[n], acc[m][n], 0, 0, 0);
    __syncthreads();
  }
  #pragma unroll
  for (int m = 0; m < 4; ++m) {
    int row = row0 + wr*64 + m*16 + lk*4;
    #pragma unroll
    for (int n = 0; n < 4; ++n) {
      int col = col0 + wc*64 + n*16 + lr;
      #pragma unroll
      for (int j = 0; j < 4; ++j) {
        if (OBF) ((unsigned short*)Cv)[(size_t)(row + j) * N + col] = f2bf(acc[m][n][j]);
        else     ((float*)Cv)[(size_t)(row + j) * N + col] = acc[m][n][j];
      }
    }
  }
}

// ---------------- low-rank gate, stage 1 --------------------------------------------------
__global__ __launch_bounds__(256) void lr1_kernel(const float* __restrict__ x,
                                                  const float* __restrict__ w1,
                                                  float* __restrict__ t1) {
  __shared__ float part[16][17];
  const int row = blockIdx.x;
  const int j = threadIdx.x & 15;
  const int p = threadIdx.x >> 4;
  const float* xr = x + (size_t)row * HID_;
  float acc = 0.f;
  const int k0 = p * 128;
  for (int kk = k0; kk < k0 + 128; ++kk)
    acc = fmaf(xr[kk], w1[kk * 16 + j], acc);
  part[p][j] = acc;
  __syncthreads();
  if (threadIdx.x < 16) {
    float s = 0.f;
    #pragma unroll
    for (int pp = 0; pp < 16; ++pp) s += part[pp][threadIdx.x];
    t1[(size_t)row * 16 + threadIdx.x] = s;
  }
}

// ---------------- low-rank gate, stage 2 --------------------------------------------------
__global__ __launch_bounds__(256) void lr2_kernel(const float* __restrict__ t1,
                                                  const float* __restrict__ w2,
                                                  const float* __restrict__ bias,
                                                  float* __restrict__ gkout) {
  __shared__ float tr[16];
  const int row = blockIdx.x;
  if (threadIdx.x < 16) tr[threadIdx.x] = t1[(size_t)row * 16 + threadIdx.x];
  __syncthreads();
  for (int n = threadIdx.x; n < H_*DK_; n += 256) {
    float acc = bias[n];
    #pragma unroll
    for (int j = 0; j < 16; ++j) acc = fmaf(tr[j], w2[j * (H_*DK_) + n], acc);
    float z = acc;
    float ls = fminf(z, 0.f) - log1pf(expf(-fabsf(z)));
    gkout[(size_t)row * (H_*DK_) + n] = ls * (1.f / 16.f);
  }
}

// ---------------- GLA phase A: per-segment local state (from S=0), full DV ----------------
// 512 blocks = (b, h, seg). Register-blocked float4 S update.
__global__ __launch_bounds__(256) void gla_phase_a(const float* __restrict__ qk,
                                                   const unsigned short* __restrict__ vg,
                                                   const float* __restrict__ gk,
                                                   float* __restrict__ Sseg,
                                                   float* __restrict__ Dseg) {
  const int seg = blockIdx.x & 15;
  const int h   = (blockIdx.x >> 4) & 15;
  const int b   = blockIdx.x >> 8;
  __shared__ float S [64][128];
  __shared__ float gc[16][68];
  __shared__ float kd[16][68];
  __shared__ float vv[16][128];
  __shared__ float dec_[64];
  const int t = threadIdx.x;
  for (int i = t; i < 2048; i += 256)
    *reinterpret_cast<float4*>(&S[i >> 5][(i & 31) * 4]) = (float4){0.f,0.f,0.f,0.f};
  float gt = 0.f;

  for (int c8 = 0; c8 < NCHUNK/NSEG; ++c8) {
    const int ch = seg * (NCHUNK/NSEG) + c8;
    __syncthreads();
    if (t < 64) {
      float acc = 0.f;
      #pragma unroll
      for (int c = 0; c < CC; ++c) {
        acc += gk[((size_t)(b*T_ + ch*CC + c)) * 1024 + h*DK_ + t];
        gc[c][t] = acc;
      }
      gt += acc;
    }
    __syncthreads();
    // kd (float4 over d) + dec
    {
      int c = t >> 4, d0 = (t & 15) * 4;
      float4 k4 = *reinterpret_cast<const float4*>(
          &qk[((size_t)(b*T_ + ch*CC + c)) * 2048 + 1024 + h*DK_ + d0]);
      float ka[4] = {k4.x, k4.y, k4.z, k4.w};
      #pragma unroll
      for (int j = 0; j < 4; ++j)
        kd[c][d0 + j] = ka[j] * expf(gc[CC-1][d0 + j] - gc[c][d0 + j]);
    }
    if (t < 64) dec_[t] = expf(gc[CC-1][t]);
    // vv (ushort4 -> f32)
    for (int i = t; i < 512; i += 256) {
      int c = i >> 5, e0 = (i & 31) * 4;
      ushort4 u = *reinterpret_cast<const ushort4*>(
          &vg[((size_t)(b*T_ + ch*CC + c)) * 4096 + h*DV_ + e0]);
      vv[c][e0+0] = bf2f(u.x); vv[c][e0+1] = bf2f(u.y);
      vv[c][e0+2] = bf2f(u.z); vv[c][e0+3] = bf2f(u.w);
    }
    __syncthreads();
    // S update: tasks (d, d+32) x e4
    #pragma unroll
    for (int rep = 0; rep < 4; ++rep) {
      int task = rep * 256 + t;
      int d0 = task >> 5, e0 = (task & 31) * 4;
      int d1 = d0 + 32;
      float4 s0 = *reinterpret_cast<float4*>(&S[d0][e0]);
      float4 s1 = *reinterpret_cast<float4*>(&S[d1][e0]);
      float m0 = dec_[d0], m1 = dec_[d1];
      s0.x *= m0; s0.y *= m0; s0.z *= m0; s0.w *= m0;
      s1.x *= m1; s1.y *= m1; s1.z *= m1; s1.w *= m1;
      #pragma unroll
      for (int c = 0; c < CC; ++c) {
        float4 vb = *reinterpret_cast<const float4*>(&vv[c][e0]);
        float k0v = kd[c][d0], k1v = kd[c][d1];
        s0.x = fmaf(k0v, vb.x, s0.x); s0.y = fmaf(k0v, vb.y, s0.y);
        s0.z = fmaf(k0v, vb.z, s0.z); s0.w = fmaf(k0v, vb.w, s0.w);
        s1.x = fmaf(k1v, vb.x, s1.x); s1.y = fmaf(k1v, vb.y, s1.y);
        s1.z = fmaf(k1v, vb.z, s1.z); s1.w = fmaf(k1v, vb.w, s1.w);
      }
      *reinterpret_cast<float4*>(&S[d0][e0]) = s0;
      *reinterpret_cast<float4*>(&S[d1][e0]) = s1;
    }
  }
  __syncthreads();
  const size_t base = ((size_t)((b*H_ + h)*NSEG + seg)) * (DK_*DV_);
  for (int i = t; i < 2048; i += 256)
    *reinterpret_cast<float4*>(&Sseg[base + i*4]) =
        *reinterpret_cast<float4*>(&S[i >> 5][(i & 31) * 4]);
  if (t < 64)
    Dseg[(size_t)((b*H_ + h)*NSEG + seg) * DK_ + t] = expf(gt);
}

// ---------------- GLA phase B: sequential combine over segments (in place) ----------------
__global__ __launch_bounds__(256) void gla_combine(float* __restrict__ Sseg,
                                                   const float* __restrict__ Dseg) {
  const int bh = blockIdx.x;
  const int t = threadIdx.x;
  __shared__ float Dl[64];
  float4 S_run[8];
  #pragma unroll
  for (int j = 0; j < 8; ++j) S_run[j] = (float4){0.f,0.f,0.f,0.f};
  for (int seg = 0; seg < NSEG; ++seg) {
    const size_t base = ((size_t)bh*NSEG + seg) * (DK_*DV_);
    if (t < 64) Dl[t] = Dseg[((size_t)bh*NSEG + seg) * DK_ + t];
    __syncthreads();
    #pragma unroll
    for (int j = 0; j < 8; ++j) {
      int idx = j*1024 + t*4;
      float dm = Dl[idx >> 7];
      float4 sl = *reinterpret_cast<float4*>(&Sseg[base + idx]);
      *reinterpret_cast<float4*>(&Sseg[base + idx]) = S_run[j];
      S_run[j].x = fmaf(dm, S_run[j].x, sl.x);
      S_run[j].y = fmaf(dm, S_run[j].y, sl.y);
      S_run[j].z = fmaf(dm, S_run[j].z, sl.z);
      S_run[j].w = fmaf(dm, S_run[j].w, sl.w);
    }
    __syncthreads();
  }
}

// ---------------- GLA phase C: outputs, starting from S_in, full DV -----------------------
// 512 blocks = (b, h, seg). Register-blocked float4 inner loops.
__global__ __launch_bounds__(256) void gla_phase_c(const float* __restrict__ qk,
                                                   const unsigned short* __restrict__ vg,
                                                   const float* __restrict__ gk,
                                                   const float* __restrict__ Sseg,
                                                   float* __restrict__ o) {
  const int seg = blockIdx.x & 15;
  const int h   = (blockIdx.x >> 4) & 15;
  const int b   = blockIdx.x >> 8;
  __shared__ float S [64][128];
  __shared__ float gc[16][68];
  __shared__ float qe[16][68];
  __shared__ float ke[16][68];
  __shared__ float kd[16][68];
  __shared__ float vv[16][128];
  __shared__ float Am[16][16];
  __shared__ float dec_[64];
  const int t = threadIdx.x;
  {
    const size_t base = ((size_t)((b*H_ + h)*NSEG + seg)) * (DK_*DV_);
    for (int i = t; i < 2048; i += 256)
      *reinterpret_cast<float4*>(&S[i >> 5][(i & 31) * 4]) =
          *reinterpret_cast<const float4*>(&Sseg[base + i*4]);
  }

  for (int c8 = 0; c8 < NCHUNK/NSEG; ++c8) {
    const int ch = seg * (NCHUNK/NSEG) + c8;
    __syncthreads();
    if (t < 64) {
      float acc = 0.f;
      #pragma unroll
      for (int c = 0; c < CC; ++c) {
        acc += gk[((size_t)(b*T_ + ch*CC + c)) * 1024 + h*DK_ + t];
        gc[c][t] = acc;
      }
    }
    __syncthreads();
    // qe / ke / kd (float4 over d)
    {
      int c = t >> 4, d0 = (t & 15) * 4;
      const size_t base = ((size_t)(b*T_ + ch*CC + c)) * 2048 + h*DK_ + d0;
      float4 q4 = *reinterpret_cast<const float4*>(&qk[base]);
      float4 k4 = *reinterpret_cast<const float4*>(&qk[base + 1024]);
      float qa[4] = {q4.x, q4.y, q4.z, q4.w};
      float ka[4] = {k4.x, k4.y, k4.z, k4.w};
      #pragma unroll
      for (int j = 0; j < 4; ++j) {
        float gcv = gc[c][d0 + j];
        float gl  = gc[CC-1][d0 + j];
        qe[c][d0 + j] = qa[j] * expf(gcv) * SCALE_;
        ke[c][d0 + j] = ka[j] * expf(-gcv);
        kd[c][d0 + j] = ka[j] * expf(gl - gcv);
      }
    }
    if (t < 64) dec_[t] = expf(gc[CC-1][t]);
    for (int i = t; i < 512; i += 256) {
      int c = i >> 5, e0 = (i & 31) * 4;
      ushort4 u = *reinterpret_cast<const ushort4*>(
          &vg[((size_t)(b*T_ + ch*CC + c)) * 4096 + h*DV_ + e0]);
      vv[c][e0+0] = bf2f(u.x); vv[c][e0+1] = bf2f(u.y);
      vv[c][e0+2] = bf2f(u.z); vv[c][e0+3] = bf2f(u.w);
    }
    __syncthreads();
    // A = tril(qe @ ke^T): thread (c,m), float4 over d
    {
      int c = t >> 4, m = t & 15;
      float a = 0.f;
      if (m <= c) {
        #pragma unroll
        for (int d4 = 0; d4 < 16; ++d4) {
          float4 qv = *reinterpret_cast<const float4*>(&qe[c][d4*4]);
          float4 kv = *reinterpret_cast<const float4*>(&ke[m][d4*4]);
          a = fmaf(qv.x, kv.x, a); a = fmaf(qv.y, kv.y, a);
          a = fmaf(qv.z, kv.z, a); a = fmaf(qv.w, kv.w, a);
        }
      }
      Am[c][m] = (m <= c) ? a : 0.f;   // zero-fill upper so o-loop needs no guard
    }
    __syncthreads();
    // o-loop: thread = (p, e4); computes rows c0=p and c1=p+8
    {
      int p  = t >> 5;
      int e0 = (t & 31) * 4;
      int c0 = p, c1 = p + 8;
      float4 a0 = (float4){0.f,0.f,0.f,0.f};
      float4 a1 = (float4){0.f,0.f,0.f,0.f};
      #pragma unroll 16
      for (int d = 0; d < 64; ++d) {
        float4 sv = *reinterpret_cast<const float4*>(&S[d][e0]);
        float q0 = qe[c0][d], q1 = qe[c1][d];
        a0.x = fmaf(q0, sv.x, a0.x); a0.y = fmaf(q0, sv.y, a0.y);
        a0.z = fmaf(q0, sv.z, a0.z); a0.w = fmaf(q0, sv.w, a0.w);
        a1.x = fmaf(q1, sv.x, a1.x); a1.y = fmaf(q1, sv.y, a1.y);
        a1.z = fmaf(q1, sv.z, a1.z); a1.w = fmaf(q1, sv.w, a1.w);
      }
      for (int m = 0; m <= c1; ++m) {
        float4 vb = *reinterpret_cast<const float4*>(&vv[m][e0]);
        float w0 = Am[c0][m], w1 = Am[c1][m];   // Am upper-tri is 0
        a0.x = fmaf(w0, vb.x, a0.x); a0.y = fmaf(w0, vb.y, a0.y);
        a0.z = fmaf(w0, vb.z, a0.z); a0.w = fmaf(w0, vb.w, a0.w);
        a1.x = fmaf(w1, vb.x, a1.x); a1.y = fmaf(w1, vb.y, a1.y);
        a1.z = fmaf(w1, vb.z, a1.z); a1.w = fmaf(w1, vb.w, a1.w);
      }
      *reinterpret_cast<float4*>(&o[((size_t)(b*T_ + ch*CC + c0)) * 2048 + h*DV_ + e0]) = a0;
      *reinterpret_cast<float4*>(&o[((size_t)(b*T_ + ch*CC + c1)) * 2048 + h*DV_ + e0]) = a1;
    }
    __syncthreads();   // o-loop reads of S done before update writes
    // S update: tasks (d, d+32) x e4
    #pragma unroll
    for (int rep = 0; rep < 4; ++rep) {
      int task = rep * 256 + t;
      int d0 = task >> 5, e0 = (task & 31) * 4;
      int d1 = d0 + 32;
      float4 s0 = *reinterpret_cast<float4*>(&S[d0][e0]);
      float4 s1 = *reinterpret_cast<float4*>(&S[d1][e0]);
      float m0 = dec_[d0], m1 = dec_[d1];
      s0.x *= m0; s0.y *= m0; s0.z *= m0; s0.w *= m0;
      s1.x *= m1; s1.y *= m1; s1.z *= m1; s1.w *= m1;
      #pragma unroll
      for (int c = 0; c < CC; ++c) {
        float4 vb = *reinterpret_cast<const float4*>(&vv[c][e0]);
        float k0v = kd[c][d0], k1v = kd[c][d1];
        s0.x = fmaf(k0v, vb.x, s0.x); s0.y = fmaf(k0v, vb.y, s0.y);
        s0.z = fmaf(k0v, vb.z, s0.z); s0.w = fmaf(k0v, vb.w, s0.w);
        s1.x = fmaf(k1v, vb.x, s1.x); s1.y = fmaf(k1v, vb.y, s1.y);
        s1.z = fmaf(k1v, vb.z, s1.z); s1.w = fmaf(k1v, vb.w, s1.w);
      }
      *reinterpret_cast<float4*>(&S[d0][e0]) = s0;
      *reinterpret_cast<float4*>(&S[d1][e0]) = s1;
    }
  }
}

// ---------------- fused RMSNorm(DV) * norm_w * SiLU(g) -> bf16 y --------------------------
__global__ __launch_bounds__(256) void epilogue_kernel(const float* __restrict__ o,
                                                       const unsigned short* __restrict__ vg,
                                                       const float* __restrict__ norm_w,
                                                       unsigned short* __restrict__ yb) {
  const int row  = blockIdx.x;
  const int wave = threadIdx.x >> 6;
  const int lane = threadIdx.x & 63;
  #pragma unroll
  for (int it = 0; it < 4; ++it) {
    const int h = it * 4 + wave;
    const size_t ob = (size_t)row * 2048 + (size_t)h * DV_;
    const size_t gb = (size_t)row * 4096 + 2048 + (size_t)h * DV_;
    float o0 = o[ob + lane];
    float o1 = o[ob + 64 + lane];
    float ss = o0*o0 + o1*o1;
    #pragma unroll
    for (int off = 32; off > 0; off >>= 1) ss += __shfl_xor(ss, off, 64);
    float inv = rsqrtf(ss * (1.f/128.f) + 1e-5f);
    float g0 = bf2f(vg[gb + lane]);
    float g1 = bf2f(vg[gb + 64 + lane]);
    float s0 = g0 / (1.f + expf(-g0));
    float s1 = g1 / (1.f + expf(-g1));
    yb[ob + lane]      = f2bf(o0 * inv * norm_w[lane]      * s0);
    yb[ob + 64 + lane] = f2bf(o1 * inv * norm_w[64 + lane] * s1);
  }
}

// ------------------------------------------------------------------------------------------
extern "C" void kernel_launch(void* const* d_in, const int* in_sizes, int n_in,
                              void* d_out, int out_size, void* d_ws, size_t ws_size,
                              hipStream_t stream) {
  const float* x      = (const float*)d_in[0];
  const float* Wq     = (const float*)d_in[1];
  const float* Wk     = (const float*)d_in[2];
  const float* Wv     = (const float*)d_in[3];
  const float* Wg     = (const float*)d_in[4];
  const float* Wgk1   = (const float*)d_in[5];
  const float* Wgk2   = (const float*)d_in[6];
  const float* bgk2   = (const float*)d_in[7];
  const float* Wo     = (const float*)d_in[8];
  const float* norm_w = (const float*)d_in[9];
  float* out = (float*)d_out;
  float* ws  = (float*)d_ws;

  // ws layout (float-element offsets)
  float*          qk   = ws;                               // [0, 8388608) f32 [M][2048] q|k
  float*          gkb  = ws + 8388608;                     // [8388608, 12582912) f32 [M][1024]
  unsigned short* vg   = (unsigned short*)(ws + 12582912); // bf16 [M][4096] v|g
  float*          o    = ws + 20971520;                    // f32 [M][2048]
  float*          Sseg = ws + 29360128;                    // f32 [B*H*NSEG][64][128]
  float*          Dseg = ws + 33554432;                    // 32768 f32
  float*          t1   = ws + 33587200;                    // 65536 f32

  // lifetime-disjoint aliases (stream order makes these safe)
  unsigned short* xb   = (unsigned short*)gkb;             // dead before lr2 writes gkb
  unsigned short* WqkT = (unsigned short*)o;               // dead before phase C writes o
  unsigned short* WvgT = (unsigned short*)(o + 2097152);   // dead before phase C writes o
  unsigned short* yb   = (unsigned short*)ws;              // qk dead after phase C
  unsigned short* WoT  = (unsigned short*)(ws + 4194304);  // qk dead after phase C

  dim3 blk(256);
  convert_f32_bf16<<<dim3((2097152 + 255)/256), blk, 0, stream>>>(x, xb, 2097152);
  transpose_f32_bf16<<<dim3(1024/32, 2048/32), blk, 0, stream>>>(Wq, WqkT, 2048, 1024);
  transpose_f32_bf16<<<dim3(1024/32, 2048/32), blk, 0, stream>>>(Wk, WqkT + (size_t)1024*2048, 2048, 1024);
  transpose_f32_bf16<<<dim3(2048/32, 2048/32), blk, 0, stream>>>(Wv, WvgT, 2048, 2048);
  transpose_f32_bf16<<<dim3(2048/32, 2048/32), blk, 0, stream>>>(Wg, WvgT + (size_t)2048*2048, 2048, 2048);
  gemm_bf16<false><<<dim3(2048/128, 4096/128), blk, 0, stream>>>(xb, WqkT, qk, M_, 2048, HID_);
  gemm_bf16<true ><<<dim3(4096/128, 4096/128), blk, 0, stream>>>(xb, WvgT, vg, M_, 4096, HID_);
  lr1_kernel<<<M_, blk, 0, stream>>>(x, Wgk1, t1);
  lr2_kernel<<<M_, blk, 0, stream>>>(t1, Wgk2, bgk2, gkb);
  gla_phase_a<<<B_*H_*NSEG, blk, 0, stream>>>(qk, vg, gkb, Sseg, Dseg);
  gla_combine<<<B_*H_, blk, 0, stream>>>(Sseg, Dseg);
  gla_phase_c<<<B_*H_*NSEG, blk, 0, stream>>>(qk, vg, gkb, Sseg, o);
  epilogue_kernel<<<M_, blk, 0, stream>>>(o, vg, norm_w, yb);
  transpose_f32_bf16<<<dim3(2048/32, 2048/32), blk, 0, stream>>>(Wo, WoT, 2048, 2048);
  gemm_bf16<false><<<dim3(2048/128, 4096/128), blk, 0, stream>>>(yb, WoT, out, M_, HID_, HID_);
}

// Round 5
// 471.184 us; speedup vs baseline: 7.4028x; 1.0699x over previous
//
#include <hip/hip_runtime.h>
#include <hip/hip_bf16.h>
#include <math.h>

// Problem constants
#define B_    2
#define T_    2048
#define HID_  2048
#define H_    16
#define DK_   64
#define DV_   128
#define CC    16
#define NCHUNK (T_/CC)     // 128
#define NSEG  16           // segments per (b,h); 8 chunks each
#define M_    (B_*T_)      // 4096
#define SCALE_ 0.125f      // DK^-0.5

typedef __attribute__((ext_vector_type(8))) __bf16 bf16x8;
typedef __attribute__((ext_vector_type(4))) float f32x4;

__device__ __forceinline__ unsigned short f2bf(float f) {
  unsigned int u = __float_as_uint(f);
  u += 0x7fff + ((u >> 16) & 1);   // RNE
  return (unsigned short)(u >> 16);
}
__device__ __forceinline__ float bf2f(unsigned short u) {
  return __uint_as_float(((unsigned int)u) << 16);
}

typedef const __attribute__((address_space(1))) void* as1cv;
typedef __attribute__((address_space(3))) void* as3v;
__device__ __forceinline__ void gload16(const void* g, void* l) {
  __builtin_amdgcn_global_load_lds((as1cv)g, (as3v)l, 16, 0, 0);
}

// ---------------- f32 -> bf16 convert (vectorized) ----------------------------------------
__global__ __launch_bounds__(256) void convert_f32_bf16(const float* __restrict__ in,
                                                        unsigned short* __restrict__ out,
                                                        int n4) {
  int i = blockIdx.x * 256 + threadIdx.x;
  if (i >= n4) return;
  float4 f = reinterpret_cast<const float4*>(in)[i];
  ushort4 u;
  u.x = f2bf(f.x); u.y = f2bf(f.y); u.z = f2bf(f.z); u.w = f2bf(f.w);
  reinterpret_cast<ushort4*>(out)[i] = u;
}

// ---------------- transpose + convert: in[K][N] f32 -> out[N][K] bf16 ---------------------
__global__ __launch_bounds__(256) void transpose_f32_bf16(const float* __restrict__ in,
                                                          unsigned short* __restrict__ out,
                                                          int K, int N) {
  __shared__ float tile[32][33];
  const int n0 = blockIdx.x * 32;
  const int k0 = blockIdx.y * 32;
  const int tx = threadIdx.x & 31;
  const int ty = threadIdx.x >> 5;
  #pragma unroll
  for (int i = 0; i < 4; ++i)
    tile[ty + i*8][tx] = in[(size_t)(k0 + ty + i*8) * N + n0 + tx];
  __syncthreads();
  #pragma unroll
  for (int i = 0; i < 4; ++i) {
    int r = ty + i*8;
    out[(size_t)(n0 + r) * K + k0 + tx] = f2bf(tile[tx][r]);
  }
}

// ---------------- 256x256 8-phase bf16 MFMA GEMM (T2+T3+T4+T5) ----------------------------
// C[M,N] = A[M,K] @ Bt[N,K]^T. K % 64 == 0, M,N % 256 == 0.
// 8 waves (2Mx4N), per-wave 128x64 output. LDS 128KB: [buf][A/B][half][2 ksub][128 rows][64B].
// st_16x32 swizzle: byte ^= ((byte>>9)&1)<<5, applied to pre-swizzled global src + reads.
// Slot ledger: B(p) last read P2 -> restage P3; A(p) last read P3 -> restage P4.
// One counted vmcnt(8) per K-tile boundary (2 K-tiles of stages in flight); vmcnt(0) only
// at the last restage boundary.
template<bool OBF>
__global__ __launch_bounds__(512, 2) void gemm256(const unsigned short* __restrict__ A,
                                                  const unsigned short* __restrict__ Bt,
                                                  void* __restrict__ Cv,
                                                  int M, int N, int K) {
  __shared__ char ldsb[131072];
  const int t    = threadIdx.x;
  const int lane = t & 63;
  const int wid  = t >> 6;
  const int wr   = wid >> 2;        // 0..1
  const int wc   = wid & 3;         // 0..3
  const int lr   = lane & 15;
  const int lk   = lane >> 4;       // 0..3
  const int row0 = blockIdx.y * 256;
  const int col0 = blockIdx.x * 256;
  const int NKT  = K >> 6;
  const size_t K2 = (size_t)K * 2;

  // staging constants: thread covers row r_s, 16B at dest (t&3)*16 within a 64B panel row;
  // source k-byte is XOR-swizzled so linear gload_lds dest yields swizzled layout.
  const int r_s  = t >> 2;                                   // 0..127
  const int kx_s = ((t & 3) * 16) ^ (((t >> 5) & 1) << 5);

  const int ha = wr;                 // A half this wave reads
  const int hb = wc >> 1;            // B half this wave reads
  const int rbl = (wc & 1) * 64;     // B local row offset

  f32x4 acc[8][4];
  #pragma unroll
  for (int m = 0; m < 8; ++m)
    #pragma unroll
    for (int n = 0; n < 4; ++n) acc[m][n] = (f32x4){0.f, 0.f, 0.f, 0.f};

  auto stage_half = [&](int p, int o, int h, int kt) {
    const char* src = o ? (const char*)Bt : (const char*)A;
    const int R0 = (o ? col0 : row0) + h * 128;
    const char* g = src + (size_t)(R0 + r_s) * K2 + (size_t)kt * 128 + kx_s;
    char* l = ldsb + ((((p << 1) | o) << 1 | h) << 14) + t * 16;
    gload16(g, l);            // panel ks=0
    gload16(g + 64, l + 8192); // panel ks=1
  };
  auto lda = [&](int p, int mf, int ks) -> bf16x8 {
    int r = mf * 16 + lr;
    int a = ((((p << 1) | 0) << 1 | ha) << 14) + ks * 8192 + r * 64 + lk * 16;
    a ^= ((r >> 3) & 1) << 5;
    return *(const bf16x8*)(ldsb + a);
  };
  auto ldb = [&](int p, int nf, int ks) -> bf16x8 {
    int r = rbl + nf * 16 + lr;
    int a = ((((p << 1) | 1) << 1 | hb) << 14) + ks * 8192 + r * 64 + lk * 16;
    a ^= ((r >> 3) & 1) << 5;
    return *(const bf16x8*)(ldsb + a);
  };

  // prologue: stage K0 (B then A), K1 (B then A) -> 16 wave-VMEM; wait all but newest 8.
  stage_half(0, 1, 0, 0); stage_half(0, 1, 1, 0);
  stage_half(0, 0, 0, 0); stage_half(0, 0, 1, 0);
  if (1 < NKT) {
    stage_half(1, 1, 0, 1); stage_half(1, 1, 1, 1);
    stage_half(1, 0, 0, 1); stage_half(1, 0, 1, 1);
  }
  __builtin_amdgcn_sched_barrier(0);
  asm volatile("s_waitcnt vmcnt(8)" ::: "memory");
  __builtin_amdgcn_sched_barrier(0);
  __builtin_amdgcn_s_barrier();

  bf16x8 fa[4][2], fb[2][2], fb2[2][2];

  for (int kt = 0; kt < NKT; ++kt) {
    const int p = kt & 1;
    const bool st = (kt + 2 < NKT);
    // ---------- P1: quadrant (m0-3, n0-1); ds_read 12 ----------
    #pragma unroll
    for (int m = 0; m < 4; ++m) { fa[m][0] = lda(p, m, 0); fa[m][1] = lda(p, m, 1); }
    #pragma unroll
    for (int n = 0; n < 2; ++n) { fb[n][0] = ldb(p, n, 0); fb[n][1] = ldb(p, n, 1); }
    __builtin_amdgcn_sched_barrier(0);
    __builtin_amdgcn_s_barrier();
    asm volatile("s_waitcnt lgkmcnt(0)" ::: "memory");
    __builtin_amdgcn_sched_barrier(0);
    __builtin_amdgcn_s_setprio(1);
    #pragma unroll
    for (int m = 0; m < 4; ++m)
      #pragma unroll
      for (int n = 0; n < 2; ++n) {
        acc[m][n] = __builtin_amdgcn_mfma_f32_16x16x32_bf16(fa[m][0], fb[n][0], acc[m][n], 0, 0, 0);
        acc[m][n] = __builtin_amdgcn_mfma_f32_16x16x32_bf16(fa[m][1], fb[n][1], acc[m][n], 0, 0, 0);
      }
    __builtin_amdgcn_s_setprio(0);
    __builtin_amdgcn_sched_barrier(0);
    __builtin_amdgcn_s_barrier();
    // ---------- P2: quadrant (m0-3, n2-3); ds_read 4; last read of B(p) ----------
    #pragma unroll
    for (int n = 0; n < 2; ++n) { fb2[n][0] = ldb(p, n + 2, 0); fb2[n][1] = ldb(p, n + 2, 1); }
    __builtin_amdgcn_sched_barrier(0);
    __builtin_amdgcn_s_barrier();
    asm volatile("s_waitcnt lgkmcnt(0)" ::: "memory");
    __builtin_amdgcn_sched_barrier(0);
    __builtin_amdgcn_s_setprio(1);
    #pragma unroll
    for (int m = 0; m < 4; ++m)
      #pragma unroll
      for (int n = 0; n < 2; ++n) {
        acc[m][n+2] = __builtin_amdgcn_mfma_f32_16x16x32_bf16(fa[m][0], fb2[n][0], acc[m][n+2], 0, 0, 0);
        acc[m][n+2] = __builtin_amdgcn_mfma_f32_16x16x32_bf16(fa[m][1], fb2[n][1], acc[m][n+2], 0, 0, 0);
      }
    __builtin_amdgcn_s_setprio(0);
    __builtin_amdgcn_sched_barrier(0);
    __builtin_amdgcn_s_barrier();
    // ---------- P3: restage B(p)<-kt+2; quadrant (m4-7, n0-1); last read of A(p) ----------
    if (st) { stage_half(p, 1, 0, kt + 2); stage_half(p, 1, 1, kt + 2); }
    #pragma unroll
    for (int m = 0; m < 4; ++m) { fa[m][0] = lda(p, m + 4, 0); fa[m][1] = lda(p, m + 4, 1); }
    __builtin_amdgcn_sched_barrier(0);
    __builtin_amdgcn_s_barrier();
    asm volatile("s_waitcnt lgkmcnt(0)" ::: "memory");
    __builtin_amdgcn_sched_barrier(0);
    __builtin_amdgcn_s_setprio(1);
    #pragma unroll
    for (int m = 0; m < 4; ++m)
      #pragma unroll
      for (int n = 0; n < 2; ++n) {
        acc[m+4][n] = __builtin_amdgcn_mfma_f32_16x16x32_bf16(fa[m][0], fb[n][0], acc[m+4][n], 0, 0, 0);
        acc[m+4][n] = __builtin_amdgcn_mfma_f32_16x16x32_bf16(fa[m][1], fb[n][1], acc[m+4][n], 0, 0, 0);
      }
    __builtin_amdgcn_s_setprio(0);
    __builtin_amdgcn_sched_barrier(0);
    __builtin_amdgcn_s_barrier();
    // ---------- P4: restage A(p)<-kt+2; quadrant (m4-7, n2-3); counted vmcnt ----------
    if (st) { stage_half(p, 0, 0, kt + 2); stage_half(p, 0, 1, kt + 2); }
    __builtin_amdgcn_sched_barrier(0);
    __builtin_amdgcn_s_setprio(1);
    #pragma unroll
    for (int m = 0; m < 4; ++m)
      #pragma unroll
      for (int n = 0; n < 2; ++n) {
        acc[m+4][n+2] = __builtin_amdgcn_mfma_f32_16x16x32_bf16(fa[m][0], fb2[n][0], acc[m+4][n+2], 0, 0, 0);
        acc[m+4][n+2] = __builtin_amdgcn_mfma_f32_16x16x32_bf16(fa[m][1], fb2[n][1], acc[m+4][n+2], 0, 0, 0);
      }
    __builtin_amdgcn_s_setprio(0);
    __builtin_amdgcn_sched_barrier(0);
    if (kt == NKT - 2) asm volatile("s_waitcnt vmcnt(0)" ::: "memory");
    else               asm volatile("s_waitcnt vmcnt(8)" ::: "memory");
    __builtin_amdgcn_sched_barrier(0);
    __builtin_amdgcn_s_barrier();
  }

  #pragma unroll
  for (int m = 0; m < 8; ++m) {
    int row = row0 + wr*128 + m*16 + lk*4;
    #pragma unroll
    for (int n = 0; n < 4; ++n) {
      int col = col0 + wc*64 + n*16 + lr;
      #pragma unroll
      for (int j = 0; j < 4; ++j) {
        if (OBF) ((unsigned short*)Cv)[(size_t)(row + j) * N + col] = f2bf(acc[m][n][j]);
        else     ((float*)Cv)[(size_t)(row + j) * N + col] = acc[m][n][j];
      }
    }
  }
}

// ---------------- low-rank gate, stage 1 --------------------------------------------------
__global__ __launch_bounds__(256) void lr1_kernel(const float* __restrict__ x,
                                                  const float* __restrict__ w1,
                                                  float* __restrict__ t1) {
  __shared__ float part[16][17];
  const int row = blockIdx.x;
  const int j = threadIdx.x & 15;
  const int p = threadIdx.x >> 4;
  const float* xr = x + (size_t)row * HID_;
  float acc = 0.f;
  const int k0 = p * 128;
  for (int kk = k0; kk < k0 + 128; ++kk)
    acc = fmaf(xr[kk], w1[kk * 16 + j], acc);
  part[p][j] = acc;
  __syncthreads();
  if (threadIdx.x < 16) {
    float s = 0.f;
    #pragma unroll
    for (int pp = 0; pp < 16; ++pp) s += part[pp][threadIdx.x];
    t1[(size_t)row * 16 + threadIdx.x] = s;
  }
}

// ---------------- low-rank gate, stage 2 --------------------------------------------------
__global__ __launch_bounds__(256) void lr2_kernel(const float* __restrict__ t1,
                                                  const float* __restrict__ w2,
                                                  const float* __restrict__ bias,
                                                  float* __restrict__ gkout) {
  __shared__ float tr[16];
  const int row = blockIdx.x;
  if (threadIdx.x < 16) tr[threadIdx.x] = t1[(size_t)row * 16 + threadIdx.x];
  __syncthreads();
  for (int n = threadIdx.x; n < H_*DK_; n += 256) {
    float acc = bias[n];
    #pragma unroll
    for (int j = 0; j < 16; ++j) acc = fmaf(tr[j], w2[j * (H_*DK_) + n], acc);
    float z = acc;
    float ls = fminf(z, 0.f) - log1pf(expf(-fabsf(z)));
    gkout[(size_t)row * (H_*DK_) + n] = ls * (1.f / 16.f);
  }
}

// ---------------- GLA phase A: per-segment local state (from S=0), full DV ----------------
__global__ __launch_bounds__(256) void gla_phase_a(const float* __restrict__ qk,
                                                   const unsigned short* __restrict__ vg,
                                                   const float* __restrict__ gk,
                                                   float* __restrict__ Sseg,
                                                   float* __restrict__ Dseg) {
  const int seg = blockIdx.x & 15;
  const int h   = (blockIdx.x >> 4) & 15;
  const int b   = blockIdx.x >> 8;
  __shared__ float S [64][128];
  __shared__ float gc[16][68];
  __shared__ float kd[16][68];
  __shared__ float vv[16][128];
  __shared__ float dec_[64];
  const int t = threadIdx.x;
  for (int i = t; i < 2048; i += 256)
    *reinterpret_cast<float4*>(&S[i >> 5][(i & 31) * 4]) = (float4){0.f,0.f,0.f,0.f};
  float gt = 0.f;

  for (int c8 = 0; c8 < NCHUNK/NSEG; ++c8) {
    const int ch = seg * (NCHUNK/NSEG) + c8;
    __syncthreads();
    if (t < 64) {
      float acc = 0.f;
      #pragma unroll
      for (int c = 0; c < CC; ++c) {
        acc += gk[((size_t)(b*T_ + ch*CC + c)) * 1024 + h*DK_ + t];
        gc[c][t] = acc;
      }
      gt += acc;
    }
    __syncthreads();
    {
      int c = t >> 4, d0 = (t & 15) * 4;
      float4 k4 = *reinterpret_cast<const float4*>(
          &qk[((size_t)(b*T_ + ch*CC + c)) * 2048 + 1024 + h*DK_ + d0]);
      float ka[4] = {k4.x, k4.y, k4.z, k4.w};
      #pragma unroll
      for (int j = 0; j < 4; ++j)
        kd[c][d0 + j] = ka[j] * expf(gc[CC-1][d0 + j] - gc[c][d0 + j]);
    }
    if (t < 64) dec_[t] = expf(gc[CC-1][t]);
    for (int i = t; i < 512; i += 256) {
      int c = i >> 5, e0 = (i & 31) * 4;
      ushort4 u = *reinterpret_cast<const ushort4*>(
          &vg[((size_t)(b*T_ + ch*CC + c)) * 4096 + h*DV_ + e0]);
      vv[c][e0+0] = bf2f(u.x); vv[c][e0+1] = bf2f(u.y);
      vv[c][e0+2] = bf2f(u.z); vv[c][e0+3] = bf2f(u.w);
    }
    __syncthreads();
    #pragma unroll
    for (int rep = 0; rep < 4; ++rep) {
      int task = rep * 256 + t;
      int d0 = task >> 5, e0 = (task & 31) * 4;
      int d1 = d0 + 32;
      float4 s0 = *reinterpret_cast<float4*>(&S[d0][e0]);
      float4 s1 = *reinterpret_cast<float4*>(&S[d1][e0]);
      float m0 = dec_[d0], m1 = dec_[d1];
      s0.x *= m0; s0.y *= m0; s0.z *= m0; s0.w *= m0;
      s1.x *= m1; s1.y *= m1; s1.z *= m1; s1.w *= m1;
      #pragma unroll
      for (int c = 0; c < CC; ++c) {
        float4 vb = *reinterpret_cast<const float4*>(&vv[c][e0]);
        float k0v = kd[c][d0], k1v = kd[c][d1];
        s0.x = fmaf(k0v, vb.x, s0.x); s0.y = fmaf(k0v, vb.y, s0.y);
        s0.z = fmaf(k0v, vb.z, s0.z); s0.w = fmaf(k0v, vb.w, s0.w);
        s1.x = fmaf(k1v, vb.x, s1.x); s1.y = fmaf(k1v, vb.y, s1.y);
        s1.z = fmaf(k1v, vb.z, s1.z); s1.w = fmaf(k1v, vb.w, s1.w);
      }
      *reinterpret_cast<float4*>(&S[d0][e0]) = s0;
      *reinterpret_cast<float4*>(&S[d1][e0]) = s1;
    }
  }
  __syncthreads();
  const size_t base = ((size_t)((b*H_ + h)*NSEG + seg)) * (DK_*DV_);
  for (int i = t; i < 2048; i += 256)
    *reinterpret_cast<float4*>(&Sseg[base + i*4]) =
        *reinterpret_cast<float4*>(&S[i >> 5][(i & 31) * 4]);
  if (t < 64)
    Dseg[(size_t)((b*H_ + h)*NSEG + seg) * DK_ + t] = expf(gt);
}

// ---------------- GLA phase B: sequential combine over segments (in place) ----------------
__global__ __launch_bounds__(256) void gla_combine(float* __restrict__ Sseg,
                                                   const float* __restrict__ Dseg) {
  const int bh = blockIdx.x;
  const int t = threadIdx.x;
  __shared__ float Dl[64];
  float4 S_run[8];
  #pragma unroll
  for (int j = 0; j < 8; ++j) S_run[j] = (float4){0.f,0.f,0.f,0.f};
  for (int seg = 0; seg < NSEG; ++seg) {
    const size_t base = ((size_t)bh*NSEG + seg) * (DK_*DV_);
    if (t < 64) Dl[t] = Dseg[((size_t)bh*NSEG + seg) * DK_ + t];
    __syncthreads();
    #pragma unroll
    for (int j = 0; j < 8; ++j) {
      int idx = j*1024 + t*4;
      float dm = Dl[idx >> 7];
      float4 sl = *reinterpret_cast<float4*>(&Sseg[base + idx]);
      *reinterpret_cast<float4*>(&Sseg[base + idx]) = S_run[j];
      S_run[j].x = fmaf(dm, S_run[j].x, sl.x);
      S_run[j].y = fmaf(dm, S_run[j].y, sl.y);
      S_run[j].z = fmaf(dm, S_run[j].z, sl.z);
      S_run[j].w = fmaf(dm, S_run[j].w, sl.w);
    }
    __syncthreads();
  }
}

// ---------------- GLA phase C: outputs, starting from S_in, full DV -----------------------
__global__ __launch_bounds__(256) void gla_phase_c(const float* __restrict__ qk,
                                                   const unsigned short* __restrict__ vg,
                                                   const float* __restrict__ gk,
                                                   const float* __restrict__ Sseg,
                                                   float* __restrict__ o) {
  const int seg = blockIdx.x & 15;
  const int h   = (blockIdx.x >> 4) & 15;
  const int b   = blockIdx.x >> 8;
  __shared__ float S [64][128];
  __shared__ float gc[16][68];
  __shared__ float qe[16][68];
  __shared__ float ke[16][68];
  __shared__ float kd[16][68];
  __shared__ float vv[16][128];
  __shared__ float Am[16][16];
  __shared__ float dec_[64];
  const int t = threadIdx.x;
  {
    const size_t base = ((size_t)((b*H_ + h)*NSEG + seg)) * (DK_*DV_);
    for (int i = t; i < 2048; i += 256)
      *reinterpret_cast<float4*>(&S[i >> 5][(i & 31) * 4]) =
          *reinterpret_cast<const float4*>(&Sseg[base + i*4]);
  }

  for (int c8 = 0; c8 < NCHUNK/NSEG; ++c8) {
    const int ch = seg * (NCHUNK/NSEG) + c8;
    __syncthreads();
    if (t < 64) {
      float acc = 0.f;
      #pragma unroll
      for (int c = 0; c < CC; ++c) {
        acc += gk[((size_t)(b*T_ + ch*CC + c)) * 1024 + h*DK_ + t];
        gc[c][t] = acc;
      }
    }
    __syncthreads();
    {
      int c = t >> 4, d0 = (t & 15) * 4;
      const size_t base = ((size_t)(b*T_ + ch*CC + c)) * 2048 + h*DK_ + d0;
      float4 q4 = *reinterpret_cast<const float4*>(&qk[base]);
      float4 k4 = *reinterpret_cast<const float4*>(&qk[base + 1024]);
      float qa[4] = {q4.x, q4.y, q4.z, q4.w};
      float ka[4] = {k4.x, k4.y, k4.z, k4.w};
      #pragma unroll
      for (int j = 0; j < 4; ++j) {
        float gcv = gc[c][d0 + j];
        float gl  = gc[CC-1][d0 + j];
        qe[c][d0 + j] = qa[j] * expf(gcv) * SCALE_;
        ke[c][d0 + j] = ka[j] * expf(-gcv);
        kd[c][d0 + j] = ka[j] * expf(gl - gcv);
      }
    }
    if (t < 64) dec_[t] = expf(gc[CC-1][t]);
    for (int i = t; i < 512; i += 256) {
      int c = i >> 5, e0 = (i & 31) * 4;
      ushort4 u = *reinterpret_cast<const ushort4*>(
          &vg[((size_t)(b*T_ + ch*CC + c)) * 4096 + h*DV_ + e0]);
      vv[c][e0+0] = bf2f(u.x); vv[c][e0+1] = bf2f(u.y);
      vv[c][e0+2] = bf2f(u.z); vv[c][e0+3] = bf2f(u.w);
    }
    __syncthreads();
    {
      int c = t >> 4, m = t & 15;
      float a = 0.f;
      if (m <= c) {
        #pragma unroll
        for (int d4 = 0; d4 < 16; ++d4) {
          float4 qv = *reinterpret_cast<const float4*>(&qe[c][d4*4]);
          float4 kv = *reinterpret_cast<const float4*>(&ke[m][d4*4]);
          a = fmaf(qv.x, kv.x, a); a = fmaf(qv.y, kv.y, a);
          a = fmaf(qv.z, kv.z, a); a = fmaf(qv.w, kv.w, a);
        }
      }
      Am[c][m] = (m <= c) ? a : 0.f;
    }
    __syncthreads();
    {
      int p  = t >> 5;
      int e0 = (t & 31) * 4;
      int c0 = p, c1 = p + 8;
      float4 a0 = (float4){0.f,0.f,0.f,0.f};
      float4 a1 = (float4){0.f,0.f,0.f,0.f};
      #pragma unroll 16
      for (int d = 0; d < 64; ++d) {
        float4 sv = *reinterpret_cast<const float4*>(&S[d][e0]);
        float q0 = qe[c0][d], q1 = qe[c1][d];
        a0.x = fmaf(q0, sv.x, a0.x); a0.y = fmaf(q0, sv.y, a0.y);
        a0.z = fmaf(q0, sv.z, a0.z); a0.w = fmaf(q0, sv.w, a0.w);
        a1.x = fmaf(q1, sv.x, a1.x); a1.y = fmaf(q1, sv.y, a1.y);
        a1.z = fmaf(q1, sv.z, a1.z); a1.w = fmaf(q1, sv.w, a1.w);
      }
      for (int m = 0; m <= c1; ++m) {
        float4 vb = *reinterpret_cast<const float4*>(&vv[m][e0]);
        float w0 = Am[c0][m], w1 = Am[c1][m];
        a0.x = fmaf(w0, vb.x, a0.x); a0.y = fmaf(w0, vb.y, a0.y);
        a0.z = fmaf(w0, vb.z, a0.z); a0.w = fmaf(w0, vb.w, a0.w);
        a1.x = fmaf(w1, vb.x, a1.x); a1.y = fmaf(w1, vb.y, a1.y);
        a1.z = fmaf(w1, vb.z, a1.z); a1.w = fmaf(w1, vb.w, a1.w);
      }
      *reinterpret_cast<float4*>(&o[((size_t)(b*T_ + ch*CC + c0)) * 2048 + h*DV_ + e0]) = a0;
      *reinterpret_cast<float4*>(&o[((size_t)(b*T_ + ch*CC + c1)) * 2048 + h*DV_ + e0]) = a1;
    }
    __syncthreads();
    #pragma unroll
    for (int rep = 0; rep < 4; ++rep) {
      int task = rep * 256 + t;
      int d0 = task >> 5, e0 = (task & 31) * 4;
      int d1 = d0 + 32;
      float4 s0 = *reinterpret_cast<float4*>(&S[d0][e0]);
      float4 s1 = *reinterpret_cast<float4*>(&S[d1][e0]);
      float m0 = dec_[d0], m1 = dec_[d1];
      s0.x *= m0; s0.y *= m0; s0.z *= m0; s0.w *= m0;
      s1.x *= m1; s1.y *= m1; s1.z *= m1; s1.w *= m1;
      #pragma unroll
      for (int c = 0; c < CC; ++c) {
        float4 vb = *reinterpret_cast<const float4*>(&vv[c][e0]);
        float k0v = kd[c][d0], k1v = kd[c][d1];
        s0.x = fmaf(k0v, vb.x, s0.x); s0.y = fmaf(k0v, vb.y, s0.y);
        s0.z = fmaf(k0v, vb.z, s0.z); s0.w = fmaf(k0v, vb.w, s0.w);
        s1.x = fmaf(k1v, vb.x, s1.x); s1.y = fmaf(k1v, vb.y, s1.y);
        s1.z = fmaf(k1v, vb.z, s1.z); s1.w = fmaf(k1v, vb.w, s1.w);
      }
      *reinterpret_cast<float4*>(&S[d0][e0]) = s0;
      *reinterpret_cast<float4*>(&S[d1][e0]) = s1;
    }
  }
}

// ---------------- fused RMSNorm(DV) * norm_w * SiLU(g) -> bf16 y --------------------------
__global__ __launch_bounds__(256) void epilogue_kernel(const float* __restrict__ o,
                                                       const unsigned short* __restrict__ vg,
                                                       const float* __restrict__ norm_w,
                                                       unsigned short* __restrict__ yb) {
  const int row  = blockIdx.x;
  const int wave = threadIdx.x >> 6;
  const int lane = threadIdx.x & 63;
  #pragma unroll
  for (int it = 0; it < 4; ++it) {
    const int h = it * 4 + wave;
    const size_t ob = (size_t)row * 2048 + (size_t)h * DV_;
    const size_t gb = (size_t)row * 4096 + 2048 + (size_t)h * DV_;
    float o0 = o[ob + lane];
    float o1 = o[ob + 64 + lane];
    float ss = o0*o0 + o1*o1;
    #pragma unroll
    for (int off = 32; off > 0; off >>= 1) ss += __shfl_xor(ss, off, 64);
    float inv = rsqrtf(ss * (1.f/128.f) + 1e-5f);
    float g0 = bf2f(vg[gb + lane]);
    float g1 = bf2f(vg[gb + 64 + lane]);
    float s0 = g0 / (1.f + expf(-g0));
    float s1 = g1 / (1.f + expf(-g1));
    yb[ob + lane]      = f2bf(o0 * inv * norm_w[lane]      * s0);
    yb[ob + 64 + lane] = f2bf(o1 * inv * norm_w[64 + lane] * s1);
  }
}

// ------------------------------------------------------------------------------------------
extern "C" void kernel_launch(void* const* d_in, const int* in_sizes, int n_in,
                              void* d_out, int out_size, void* d_ws, size_t ws_size,
                              hipStream_t stream) {
  const float* x      = (const float*)d_in[0];
  const float* Wq     = (const float*)d_in[1];
  const float* Wk     = (const float*)d_in[2];
  const float* Wv     = (const float*)d_in[3];
  const float* Wg     = (const float*)d_in[4];
  const float* Wgk1   = (const float*)d_in[5];
  const float* Wgk2   = (const float*)d_in[6];
  const float* bgk2   = (const float*)d_in[7];
  const float* Wo     = (const float*)d_in[8];
  const float* norm_w = (const float*)d_in[9];
  float* out = (float*)d_out;
  float* ws  = (float*)d_ws;

  // ws layout (float-element offsets)
  float*          qk   = ws;                               // [0, 8388608) f32 [M][2048] q|k
  float*          gkb  = ws + 8388608;                     // [8388608, 12582912) f32 [M][1024]
  unsigned short* vg   = (unsigned short*)(ws + 12582912); // bf16 [M][4096] v|g
  float*          o    = ws + 20971520;                    // f32 [M][2048]
  float*          Sseg = ws + 29360128;                    // f32 [B*H*NSEG][64][128]
  float*          Dseg = ws + 33554432;                    // 32768 f32
  float*          t1   = ws + 33587200;                    // 65536 f32

  // lifetime-disjoint aliases (stream order makes these safe)
  unsigned short* xb   = (unsigned short*)gkb;             // dead before lr2 writes gkb
  unsigned short* WqkT = (unsigned short*)o;               // dead before phase C writes o
  unsigned short* WvgT = (unsigned short*)(o + 2097152);   // dead before phase C writes o
  unsigned short* yb   = (unsigned short*)ws;              // qk dead after phase C
  unsigned short* WoT  = (unsigned short*)(ws + 4194304);  // qk dead after phase C

  dim3 blk(256);
  convert_f32_bf16<<<dim3((2097152 + 255)/256), blk, 0, stream>>>(x, xb, 2097152);
  transpose_f32_bf16<<<dim3(1024/32, 2048/32), blk, 0, stream>>>(Wq, WqkT, 2048, 1024);
  transpose_f32_bf16<<<dim3(1024/32, 2048/32), blk, 0, stream>>>(Wk, WqkT + (size_t)1024*2048, 2048, 1024);
  transpose_f32_bf16<<<dim3(2048/32, 2048/32), blk, 0, stream>>>(Wv, WvgT, 2048, 2048);
  transpose_f32_bf16<<<dim3(2048/32, 2048/32), blk, 0, stream>>>(Wg, WvgT + (size_t)2048*2048, 2048, 2048);
  gemm256<false><<<dim3(2048/256, 4096/256), dim3(512), 0, stream>>>(xb, WqkT, qk, M_, 2048, HID_);
  gemm256<true ><<<dim3(4096/256, 4096/256), dim3(512), 0, stream>>>(xb, WvgT, vg, M_, 4096, HID_);
  lr1_kernel<<<M_, blk, 0, stream>>>(x, Wgk1, t1);
  lr2_kernel<<<M_, blk, 0, stream>>>(t1, Wgk2, bgk2, gkb);
  gla_phase_a<<<B_*H_*NSEG, blk, 0, stream>>>(qk, vg, gkb, Sseg, Dseg);
  gla_combine<<<B_*H_, blk, 0, stream>>>(Sseg, Dseg);
  gla_phase_c<<<B_*H_*NSEG, blk, 0, stream>>>(qk, vg, gkb, Sseg, o);
  epilogue_kernel<<<M_, blk, 0, stream>>>(o, vg, norm_w, yb);
  transpose_f32_bf16<<<dim3(2048/32, 2048/32), blk, 0, stream>>>(Wo, WoT, 2048, 2048);
  gemm256<false><<<dim3(2048/256, 4096/256), dim3(512), 0, stream>>>(yb, WoT, out, M_, HID_, HID_);
}

// Round 6
// 355.047 us; speedup vs baseline: 9.8242x; 1.3271x over previous
//
#include <hip/hip_runtime.h>
#include <hip/hip_bf16.h>
#include <math.h>

// Problem constants
#define B_    2
#define T_    2048
#define HID_  2048
#define H_    16
#define DK_   64
#define DV_   128
#define CC    16
#define NCHUNK (T_/CC)     // 128
#define NSEG  16           // segments per (b,h); 8 chunks each
#define M_    (B_*T_)      // 4096
#define SCALE_ 0.125f      // DK^-0.5

typedef __attribute__((ext_vector_type(8))) __bf16 bf16x8;
typedef __attribute__((ext_vector_type(4))) float f32x4;

__device__ __forceinline__ unsigned short f2bf(float f) {
  unsigned int u = __float_as_uint(f);
  u += 0x7fff + ((u >> 16) & 1);   // RNE
  return (unsigned short)(u >> 16);
}
__device__ __forceinline__ float bf2f(unsigned short u) {
  return __uint_as_float(((unsigned int)u) << 16);
}

typedef const __attribute__((address_space(1))) void* as1cv;
typedef __attribute__((address_space(3))) void* as3v;
__device__ __forceinline__ void gload16(const void* g, void* l) {
  __builtin_amdgcn_global_load_lds((as1cv)g, (as3v)l, 16, 0, 0);
}

// ---------------- f32 -> bf16 convert (vectorized) ----------------------------------------
__global__ __launch_bounds__(256) void convert_f32_bf16(const float* __restrict__ in,
                                                        unsigned short* __restrict__ out,
                                                        int n4) {
  int i = blockIdx.x * 256 + threadIdx.x;
  if (i >= n4) return;
  float4 f = reinterpret_cast<const float4*>(in)[i];
  ushort4 u;
  u.x = f2bf(f.x); u.y = f2bf(f.y); u.z = f2bf(f.z); u.w = f2bf(f.w);
  reinterpret_cast<ushort4*>(out)[i] = u;
}

// ---------------- transpose + convert: in[K][N] f32 -> out[N][K] bf16 ---------------------
__global__ __launch_bounds__(256) void transpose_f32_bf16(const float* __restrict__ in,
                                                          unsigned short* __restrict__ out,
                                                          int K, int N) {
  __shared__ float tile[32][33];
  const int n0 = blockIdx.x * 32;
  const int k0 = blockIdx.y * 32;
  const int tx = threadIdx.x & 31;
  const int ty = threadIdx.x >> 5;
  #pragma unroll
  for (int i = 0; i < 4; ++i)
    tile[ty + i*8][tx] = in[(size_t)(k0 + ty + i*8) * N + n0 + tx];
  __syncthreads();
  #pragma unroll
  for (int i = 0; i < 4; ++i) {
    int r = ty + i*8;
    out[(size_t)(n0 + r) * K + k0 + tx] = f2bf(tile[tx][r]);
  }
}

// ---------------- 256x256 8-phase bf16 MFMA GEMM (T2+T3+T4+T5) ----------------------------
template<bool OBF>
__global__ __launch_bounds__(512, 2) void gemm256(const unsigned short* __restrict__ A,
                                                  const unsigned short* __restrict__ Bt,
                                                  void* __restrict__ Cv,
                                                  int M, int N, int K) {
  __shared__ char ldsb[131072];
  const int t    = threadIdx.x;
  const int lane = t & 63;
  const int wid  = t >> 6;
  const int wr   = wid >> 2;        // 0..1
  const int wc   = wid & 3;         // 0..3
  const int lr   = lane & 15;
  const int lk   = lane >> 4;       // 0..3
  const int row0 = blockIdx.y * 256;
  const int col0 = blockIdx.x * 256;
  const int NKT  = K >> 6;
  const size_t K2 = (size_t)K * 2;

  const int r_s  = t >> 2;
  const int kx_s = ((t & 3) * 16) ^ (((t >> 5) & 1) << 5);

  const int ha = wr;
  const int hb = wc >> 1;
  const int rbl = (wc & 1) * 64;

  f32x4 acc[8][4];
  #pragma unroll
  for (int m = 0; m < 8; ++m)
    #pragma unroll
    for (int n = 0; n < 4; ++n) acc[m][n] = (f32x4){0.f, 0.f, 0.f, 0.f};

  auto stage_half = [&](int p, int o, int h, int kt) {
    const char* src = o ? (const char*)Bt : (const char*)A;
    const int R0 = (o ? col0 : row0) + h * 128;
    const char* g = src + (size_t)(R0 + r_s) * K2 + (size_t)kt * 128 + kx_s;
    char* l = ldsb + ((((p << 1) | o) << 1 | h) << 14) + t * 16;
    gload16(g, l);
    gload16(g + 64, l + 8192);
  };
  auto lda = [&](int p, int mf, int ks) -> bf16x8 {
    int r = mf * 16 + lr;
    int a = ((((p << 1) | 0) << 1 | ha) << 14) + ks * 8192 + r * 64 + lk * 16;
    a ^= ((r >> 3) & 1) << 5;
    return *(const bf16x8*)(ldsb + a);
  };
  auto ldb = [&](int p, int nf, int ks) -> bf16x8 {
    int r = rbl + nf * 16 + lr;
    int a = ((((p << 1) | 1) << 1 | hb) << 14) + ks * 8192 + r * 64 + lk * 16;
    a ^= ((r >> 3) & 1) << 5;
    return *(const bf16x8*)(ldsb + a);
  };

  stage_half(0, 1, 0, 0); stage_half(0, 1, 1, 0);
  stage_half(0, 0, 0, 0); stage_half(0, 0, 1, 0);
  if (1 < NKT) {
    stage_half(1, 1, 0, 1); stage_half(1, 1, 1, 1);
    stage_half(1, 0, 0, 1); stage_half(1, 0, 1, 1);
  }
  __builtin_amdgcn_sched_barrier(0);
  asm volatile("s_waitcnt vmcnt(8)" ::: "memory");
  __builtin_amdgcn_sched_barrier(0);
  __builtin_amdgcn_s_barrier();

  bf16x8 fa[4][2], fb[2][2], fb2[2][2];

  for (int kt = 0; kt < NKT; ++kt) {
    const int p = kt & 1;
    const bool st = (kt + 2 < NKT);
    #pragma unroll
    for (int m = 0; m < 4; ++m) { fa[m][0] = lda(p, m, 0); fa[m][1] = lda(p, m, 1); }
    #pragma unroll
    for (int n = 0; n < 2; ++n) { fb[n][0] = ldb(p, n, 0); fb[n][1] = ldb(p, n, 1); }
    __builtin_amdgcn_sched_barrier(0);
    __builtin_amdgcn_s_barrier();
    asm volatile("s_waitcnt lgkmcnt(0)" ::: "memory");
    __builtin_amdgcn_sched_barrier(0);
    __builtin_amdgcn_s_setprio(1);
    #pragma unroll
    for (int m = 0; m < 4; ++m)
      #pragma unroll
      for (int n = 0; n < 2; ++n) {
        acc[m][n] = __builtin_amdgcn_mfma_f32_16x16x32_bf16(fa[m][0], fb[n][0], acc[m][n], 0, 0, 0);
        acc[m][n] = __builtin_amdgcn_mfma_f32_16x16x32_bf16(fa[m][1], fb[n][1], acc[m][n], 0, 0, 0);
      }
    __builtin_amdgcn_s_setprio(0);
    __builtin_amdgcn_sched_barrier(0);
    __builtin_amdgcn_s_barrier();
    #pragma unroll
    for (int n = 0; n < 2; ++n) { fb2[n][0] = ldb(p, n + 2, 0); fb2[n][1] = ldb(p, n + 2, 1); }
    __builtin_amdgcn_sched_barrier(0);
    __builtin_amdgcn_s_barrier();
    asm volatile("s_waitcnt lgkmcnt(0)" ::: "memory");
    __builtin_amdgcn_sched_barrier(0);
    __builtin_amdgcn_s_setprio(1);
    #pragma unroll
    for (int m = 0; m < 4; ++m)
      #pragma unroll
      for (int n = 0; n < 2; ++n) {
        acc[m][n+2] = __builtin_amdgcn_mfma_f32_16x16x32_bf16(fa[m][0], fb2[n][0], acc[m][n+2], 0, 0, 0);
        acc[m][n+2] = __builtin_amdgcn_mfma_f32_16x16x32_bf16(fa[m][1], fb2[n][1], acc[m][n+2], 0, 0, 0);
      }
    __builtin_amdgcn_s_setprio(0);
    __builtin_amdgcn_sched_barrier(0);
    __builtin_amdgcn_s_barrier();
    if (st) { stage_half(p, 1, 0, kt + 2); stage_half(p, 1, 1, kt + 2); }
    #pragma unroll
    for (int m = 0; m < 4; ++m) { fa[m][0] = lda(p, m + 4, 0); fa[m][1] = lda(p, m + 4, 1); }
    __builtin_amdgcn_sched_barrier(0);
    __builtin_amdgcn_s_barrier();
    asm volatile("s_waitcnt lgkmcnt(0)" ::: "memory");
    __builtin_amdgcn_sched_barrier(0);
    __builtin_amdgcn_s_setprio(1);
    #pragma unroll
    for (int m = 0; m < 4; ++m)
      #pragma unroll
      for (int n = 0; n < 2; ++n) {
        acc[m+4][n] = __builtin_amdgcn_mfma_f32_16x16x32_bf16(fa[m][0], fb[n][0], acc[m+4][n], 0, 0, 0);
        acc[m+4][n] = __builtin_amdgcn_mfma_f32_16x16x32_bf16(fa[m][1], fb[n][1], acc[m+4][n], 0, 0, 0);
      }
    __builtin_amdgcn_s_setprio(0);
    __builtin_amdgcn_sched_barrier(0);
    __builtin_amdgcn_s_barrier();
    if (st) { stage_half(p, 0, 0, kt + 2); stage_half(p, 0, 1, kt + 2); }
    __builtin_amdgcn_sched_barrier(0);
    __builtin_amdgcn_s_setprio(1);
    #pragma unroll
    for (int m = 0; m < 4; ++m)
      #pragma unroll
      for (int n = 0; n < 2; ++n) {
        acc[m+4][n+2] = __builtin_amdgcn_mfma_f32_16x16x32_bf16(fa[m][0], fb2[n][0], acc[m+4][n+2], 0, 0, 0);
        acc[m+4][n+2] = __builtin_amdgcn_mfma_f32_16x16x32_bf16(fa[m][1], fb2[n][1], acc[m+4][n+2], 0, 0, 0);
      }
    __builtin_amdgcn_s_setprio(0);
    __builtin_amdgcn_sched_barrier(0);
    if (kt == NKT - 2) asm volatile("s_waitcnt vmcnt(0)" ::: "memory");
    else               asm volatile("s_waitcnt vmcnt(8)" ::: "memory");
    __builtin_amdgcn_sched_barrier(0);
    __builtin_amdgcn_s_barrier();
  }

  #pragma unroll
  for (int m = 0; m < 8; ++m) {
    int row = row0 + wr*128 + m*16 + lk*4;
    #pragma unroll
    for (int n = 0; n < 4; ++n) {
      int col = col0 + wc*64 + n*16 + lr;
      #pragma unroll
      for (int j = 0; j < 4; ++j) {
        if (OBF) ((unsigned short*)Cv)[(size_t)(row + j) * N + col] = f2bf(acc[m][n][j]);
        else     ((float*)Cv)[(size_t)(row + j) * N + col] = acc[m][n][j];
      }
    }
  }
}

// ---------------- low-rank gate, stage 1 --------------------------------------------------
__global__ __launch_bounds__(256) void lr1_kernel(const float* __restrict__ x,
                                                  const float* __restrict__ w1,
                                                  float* __restrict__ t1) {
  __shared__ float part[16][17];
  const int row = blockIdx.x;
  const int j = threadIdx.x & 15;
  const int p = threadIdx.x >> 4;
  const float* xr = x + (size_t)row * HID_;
  float acc = 0.f;
  const int k0 = p * 128;
  for (int kk = k0; kk < k0 + 128; ++kk)
    acc = fmaf(xr[kk], w1[kk * 16 + j], acc);
  part[p][j] = acc;
  __syncthreads();
  if (threadIdx.x < 16) {
    float s = 0.f;
    #pragma unroll
    for (int pp = 0; pp < 16; ++pp) s += part[pp][threadIdx.x];
    t1[(size_t)row * 16 + threadIdx.x] = s;
  }
}

// ---------------- low-rank gate, stage 2 --------------------------------------------------
__global__ __launch_bounds__(256) void lr2_kernel(const float* __restrict__ t1,
                                                  const float* __restrict__ w2,
                                                  const float* __restrict__ bias,
                                                  float* __restrict__ gkout) {
  __shared__ float tr[16];
  const int row = blockIdx.x;
  if (threadIdx.x < 16) tr[threadIdx.x] = t1[(size_t)row * 16 + threadIdx.x];
  __syncthreads();
  for (int n = threadIdx.x; n < H_*DK_; n += 256) {
    float acc = bias[n];
    #pragma unroll
    for (int j = 0; j < 16; ++j) acc = fmaf(tr[j], w2[j * (H_*DK_) + n], acc);
    float z = acc;
    float ls = fminf(z, 0.f) - log1pf(expf(-fabsf(z)));
    gkout[(size_t)row * (H_*DK_) + n] = ls * (1.f / 16.f);
  }
}

// ---------------- GLA phase A (MFMA): per-segment local state S^T in registers ------------
// 512 blocks = (b,h,seg), 4 waves. s_reg in delta-D layout: wave w owns e in [32w,32w+32).
// Sseg layout: [e][d] (e*64+d).
__global__ __launch_bounds__(256) void gla_phase_a(const float* __restrict__ qk,
                                                   const unsigned short* __restrict__ vg,
                                                   const float* __restrict__ gk,
                                                   float* __restrict__ Sseg,
                                                   float* __restrict__ Dseg) {
  const int seg = blockIdx.x & 15;
  const int h   = (blockIdx.x >> 4) & 15;
  const int b   = blockIdx.x >> 8;
  const int t    = threadIdx.x;
  const int lane = t & 63;
  const int wid  = t >> 6;
  const int q    = lane >> 4;
  const int lr   = lane & 15;
  __shared__ float gc[16][68];
  __shared__ float dec_[64];
  __shared__ unsigned short kdT[64][40];   // [d][c], c>=16 zero
  __shared__ unsigned short vvT[128][40];  // [e][c], c>=16 zero

  for (int i = t; i < 1024; i += 256) kdT[i >> 4][16 + (i & 15)] = 0;
  for (int i = t; i < 2048; i += 256) vvT[i >> 4][16 + (i & 15)] = 0;

  f32x4 s_reg[2][4];
  #pragma unroll
  for (int et = 0; et < 2; ++et)
    #pragma unroll
    for (int dt = 0; dt < 4; ++dt) s_reg[et][dt] = (f32x4){0.f,0.f,0.f,0.f};
  float gt = 0.f;

  for (int c8 = 0; c8 < NCHUNK/NSEG; ++c8) {
    const int ch = seg * (NCHUNK/NSEG) + c8;
    __syncthreads();
    // gc + dec (redundant per wave, identical values)
    {
      float acc = 0.f;
      #pragma unroll
      for (int c = 0; c < CC; ++c) {
        acc += gk[((size_t)(b*T_ + ch*CC + c)) * 1024 + h*DK_ + lane];
        gc[c][lane] = acc;
      }
      gt += acc;
      dec_[lane] = expf(acc);
    }
    __syncthreads();
    // kdT
    {
      int c = t >> 4, d0 = (t & 15) * 4;
      float4 k4 = *reinterpret_cast<const float4*>(
          &qk[((size_t)(b*T_ + ch*CC + c)) * 2048 + 1024 + h*DK_ + d0]);
      float ka[4] = {k4.x, k4.y, k4.z, k4.w};
      float gl;
      #pragma unroll
      for (int j = 0; j < 4; ++j) {
        gl = gc[CC-1][d0 + j];
        kdT[d0 + j][c] = f2bf(ka[j] * expf(gl - gc[c][d0 + j]));
      }
    }
    // vvT (bf16 passthrough)
    {
      int c = t & 15, e0 = (t >> 4) * 8;
      const ushort4* vp = reinterpret_cast<const ushort4*>(
          &vg[((size_t)(b*T_ + ch*CC + c)) * 4096 + h*DV_ + e0]);
      ushort4 a = vp[0], bb = vp[1];
      vvT[e0+0][c] = a.x;  vvT[e0+1][c] = a.y;  vvT[e0+2][c] = a.z;  vvT[e0+3][c] = a.w;
      vvT[e0+4][c] = bb.x; vvT[e0+5][c] = bb.y; vvT[e0+6][c] = bb.z; vvT[e0+7][c] = bb.w;
    }
    __syncthreads();
    // delta + state update (in-register)
    bf16x8 vf[2], kf[4];
    #pragma unroll
    for (int et = 0; et < 2; ++et)
      vf[et] = *(const bf16x8*)&vvT[wid*32 + et*16 + lr][q*8];
    #pragma unroll
    for (int dt = 0; dt < 4; ++dt)
      kf[dt] = *(const bf16x8*)&kdT[dt*16 + lr][q*8];
    #pragma unroll
    for (int et = 0; et < 2; ++et)
      #pragma unroll
      for (int dt = 0; dt < 4; ++dt) {
        f32x4 dl = __builtin_amdgcn_mfma_f32_16x16x32_bf16(vf[et], kf[dt],
                     (f32x4){0.f,0.f,0.f,0.f}, 0, 0, 0);
        float dv = dec_[dt*16 + lr];
        #pragma unroll
        for (int j = 0; j < 4; ++j)
          s_reg[et][dt][j] = fmaf(s_reg[et][dt][j], dv, dl[j]);
      }
  }
  // store S_local fragments: Sseg[e][d]
  const size_t base = ((size_t)((b*H_ + h)*NSEG + seg)) * (DK_*DV_);
  #pragma unroll
  for (int et = 0; et < 2; ++et)
    #pragma unroll
    for (int dt = 0; dt < 4; ++dt)
      #pragma unroll
      for (int j = 0; j < 4; ++j)
        Sseg[base + (size_t)(wid*32 + et*16 + q*4 + j) * 64 + dt*16 + lr] = s_reg[et][dt][j];
  if (t < 64)
    Dseg[(size_t)((b*H_ + h)*NSEG + seg) * DK_ + t] = expf(gt);
}

// ---------------- GLA phase B: sequential combine over segments (Sseg is [e][d]) ----------
__global__ __launch_bounds__(256) void gla_combine(float* __restrict__ Sseg,
                                                   const float* __restrict__ Dseg) {
  const int bh = blockIdx.x;
  const int t = threadIdx.x;
  __shared__ float Dl[64];
  float4 S_run[8];
  #pragma unroll
  for (int j = 0; j < 8; ++j) S_run[j] = (float4){0.f,0.f,0.f,0.f};
  const int d0 = (t * 4) & 63;
  for (int seg = 0; seg < NSEG; ++seg) {
    const size_t base = ((size_t)bh*NSEG + seg) * (DK_*DV_);
    if (t < 64) Dl[t] = Dseg[((size_t)bh*NSEG + seg) * DK_ + t];
    __syncthreads();
    #pragma unroll
    for (int j = 0; j < 8; ++j) {
      int idx = j*1024 + t*4;
      float4 sl = *reinterpret_cast<float4*>(&Sseg[base + idx]);
      *reinterpret_cast<float4*>(&Sseg[base + idx]) = S_run[j];
      S_run[j].x = fmaf(Dl[d0+0], S_run[j].x, sl.x);
      S_run[j].y = fmaf(Dl[d0+1], S_run[j].y, sl.y);
      S_run[j].z = fmaf(Dl[d0+2], S_run[j].z, sl.z);
      S_run[j].w = fmaf(Dl[d0+3], S_run[j].w, sl.w);
    }
    __syncthreads();
  }
}

// ---------------- GLA phase C (MFMA): outputs + state march -------------------------------
__global__ __launch_bounds__(256) void gla_phase_c(const float* __restrict__ qk,
                                                   const unsigned short* __restrict__ vg,
                                                   const float* __restrict__ gk,
                                                   const float* __restrict__ Sseg,
                                                   float* __restrict__ o) {
  const int seg = blockIdx.x & 15;
  const int h   = (blockIdx.x >> 4) & 15;
  const int b   = blockIdx.x >> 8;
  const int t    = threadIdx.x;
  const int lane = t & 63;
  const int wid  = t >> 6;
  const int q    = lane >> 4;
  const int lr   = lane & 15;
  __shared__ float gc[16][68];
  __shared__ float dec_[64];
  __shared__ unsigned short qe[16][72];    // [c][d]
  __shared__ unsigned short ke[16][72];    // [m][d]
  __shared__ unsigned short kdT[64][40];   // [d][c], c>=16 zero
  __shared__ unsigned short vvT[128][40];  // [e][c], c>=16 zero
  __shared__ unsigned short Am[16][40];    // [c][m], m>=16 zero
  __shared__ unsigned short Sb[128][72];   // [e][d] bf16 shadow of S^T

  for (int i = t; i < 1024; i += 256) kdT[i >> 4][16 + (i & 15)] = 0;
  for (int i = t; i < 2048; i += 256) vvT[i >> 4][16 + (i & 15)] = 0;
  if (t < 256) { int c = t >> 4, m = t & 15; Am[c][16 + m] = 0; }

  // load S_in fragments; init Sb shadow
  f32x4 s_reg[2][4];
  const size_t sbase = ((size_t)((b*H_ + h)*NSEG + seg)) * (DK_*DV_);
  #pragma unroll
  for (int et = 0; et < 2; ++et)
    #pragma unroll
    for (int dt = 0; dt < 4; ++dt)
      #pragma unroll
      for (int j = 0; j < 4; ++j) {
        int e = wid*32 + et*16 + q*4 + j, d = dt*16 + lr;
        float v = Sseg[sbase + (size_t)e * 64 + d];
        s_reg[et][dt][j] = v;
        Sb[e][d] = f2bf(v);
      }

  for (int c8 = 0; c8 < NCHUNK/NSEG; ++c8) {
    const int ch = seg * (NCHUNK/NSEG) + c8;
    __syncthreads();   // prev chunk fully consumed; Sb/stage writable-safe next
    // gc + dec (redundant per wave)
    {
      float acc = 0.f;
      #pragma unroll
      for (int c = 0; c < CC; ++c) {
        acc += gk[((size_t)(b*T_ + ch*CC + c)) * 1024 + h*DK_ + lane];
        gc[c][lane] = acc;
      }
      dec_[lane] = expf(acc);
    }
    __syncthreads();
    // qe / ke / kdT
    {
      int c = t >> 4, d0 = (t & 15) * 4;
      const size_t gbq = ((size_t)(b*T_ + ch*CC + c)) * 2048 + h*DK_ + d0;
      float4 q4 = *reinterpret_cast<const float4*>(&qk[gbq]);
      float4 k4 = *reinterpret_cast<const float4*>(&qk[gbq + 1024]);
      float qa[4] = {q4.x, q4.y, q4.z, q4.w};
      float ka[4] = {k4.x, k4.y, k4.z, k4.w};
      ushort4 qw, kw;
      unsigned short* qwp = (unsigned short*)&qw;
      unsigned short* kwp = (unsigned short*)&kw;
      #pragma unroll
      for (int j = 0; j < 4; ++j) {
        float gcv = gc[c][d0 + j];
        float gl  = gc[CC-1][d0 + j];
        qwp[j] = f2bf(qa[j] * expf(gcv) * SCALE_);
        kwp[j] = f2bf(ka[j] * expf(-gcv));
        kdT[d0 + j][c] = f2bf(ka[j] * expf(gl - gcv));
      }
      *reinterpret_cast<ushort4*>(&qe[c][d0]) = qw;
      *reinterpret_cast<ushort4*>(&ke[c][d0]) = kw;
    }
    // vvT (bf16 passthrough)
    {
      int c = t & 15, e0 = (t >> 4) * 8;
      const ushort4* vp = reinterpret_cast<const ushort4*>(
          &vg[((size_t)(b*T_ + ch*CC + c)) * 4096 + h*DV_ + e0]);
      ushort4 a = vp[0], bb = vp[1];
      vvT[e0+0][c] = a.x;  vvT[e0+1][c] = a.y;  vvT[e0+2][c] = a.z;  vvT[e0+3][c] = a.w;
      vvT[e0+4][c] = bb.x; vvT[e0+5][c] = bb.y; vvT[e0+6][c] = bb.z; vvT[e0+7][c] = bb.w;
    }
    __syncthreads();
    // QK^T (redundant on all waves; identical Am writes are benign)
    bf16x8 qA0 = *(const bf16x8*)&qe[lr][q*8];
    bf16x8 qA1 = *(const bf16x8*)&qe[lr][32 + q*8];
    {
      bf16x8 kB0 = *(const bf16x8*)&ke[lr][q*8];
      bf16x8 kB1 = *(const bf16x8*)&ke[lr][32 + q*8];
      f32x4 accA = __builtin_amdgcn_mfma_f32_16x16x32_bf16(qA0, kB0,
                     (f32x4){0.f,0.f,0.f,0.f}, 0, 0, 0);
      accA = __builtin_amdgcn_mfma_f32_16x16x32_bf16(qA1, kB1, accA, 0, 0, 0);
      #pragma unroll
      for (int j = 0; j < 4; ++j) {
        int c = q*4 + j;
        Am[c][lr] = (lr <= c) ? f2bf(accA[j]) : (unsigned short)0;
      }
    }
    // delta MFMAs + in-register state update (uses this chunk's dec)
    bf16x8 vf[2], kf[4];
    #pragma unroll
    for (int et = 0; et < 2; ++et)
      vf[et] = *(const bf16x8*)&vvT[wid*32 + et*16 + lr][q*8];
    #pragma unroll
    for (int dt = 0; dt < 4; ++dt)
      kf[dt] = *(const bf16x8*)&kdT[dt*16 + lr][q*8];
    #pragma unroll
    for (int et = 0; et < 2; ++et)
      #pragma unroll
      for (int dt = 0; dt < 4; ++dt) {
        f32x4 dl = __builtin_amdgcn_mfma_f32_16x16x32_bf16(vf[et], kf[dt],
                     (f32x4){0.f,0.f,0.f,0.f}, 0, 0, 0);
        float dv = dec_[dt*16 + lr];
        #pragma unroll
        for (int j = 0; j < 4; ++j)
          s_reg[et][dt][j] = fmaf(s_reg[et][dt][j], dv, dl[j]);
      }
    __syncthreads();   // Am ready; Sb still holds S_in for this chunk
    // o = qe @ S_in + Am @ v   (D tile [c x e], wave owns e-slice 32)
    {
      bf16x8 amA = *(const bf16x8*)&Am[lr][q*8];
      #pragma unroll
      for (int et = 0; et < 2; ++et) {
        int e0 = wid*32 + et*16;
        bf16x8 sB0 = *(const bf16x8*)&Sb[e0 + lr][q*8];
        bf16x8 sB1 = *(const bf16x8*)&Sb[e0 + lr][32 + q*8];
        f32x4 accO = __builtin_amdgcn_mfma_f32_16x16x32_bf16(qA0, sB0,
                       (f32x4){0.f,0.f,0.f,0.f}, 0, 0, 0);
        accO = __builtin_amdgcn_mfma_f32_16x16x32_bf16(qA1, sB1, accO, 0, 0, 0);
        accO = __builtin_amdgcn_mfma_f32_16x16x32_bf16(amA, vf[et], accO, 0, 0, 0);
        #pragma unroll
        for (int j = 0; j < 4; ++j)
          o[((size_t)(b*T_ + ch*CC + q*4 + j)) * 2048 + h*DV_ + e0 + lr] = accO[j];
      }
    }
    __syncthreads();   // all o-reads of Sb done -> safe to refresh shadow
    #pragma unroll
    for (int et = 0; et < 2; ++et)
      #pragma unroll
      for (int dt = 0; dt < 4; ++dt)
        #pragma unroll
        for (int j = 0; j < 4; ++j)
          Sb[wid*32 + et*16 + q*4 + j][dt*16 + lr] = f2bf(s_reg[et][dt][j]);
  }
}

// ---------------- fused RMSNorm(DV) * norm_w * SiLU(g) -> bf16 y --------------------------
__global__ __launch_bounds__(256) void epilogue_kernel(const float* __restrict__ o,
                                                       const unsigned short* __restrict__ vg,
                                                       const float* __restrict__ norm_w,
                                                       unsigned short* __restrict__ yb) {
  const int row  = blockIdx.x;
  const int wave = threadIdx.x >> 6;
  const int lane = threadIdx.x & 63;
  #pragma unroll
  for (int it = 0; it < 4; ++it) {
    const int h = it * 4 + wave;
    const size_t ob = (size_t)row * 2048 + (size_t)h * DV_;
    const size_t gb = (size_t)row * 4096 + 2048 + (size_t)h * DV_;
    float o0 = o[ob + lane];
    float o1 = o[ob + 64 + lane];
    float ss = o0*o0 + o1*o1;
    #pragma unroll
    for (int off = 32; off > 0; off >>= 1) ss += __shfl_xor(ss, off, 64);
    float inv = rsqrtf(ss * (1.f/128.f) + 1e-5f);
    float g0 = bf2f(vg[gb + lane]);
    float g1 = bf2f(vg[gb + 64 + lane]);
    float s0 = g0 / (1.f + expf(-g0));
    float s1 = g1 / (1.f + expf(-g1));
    yb[ob + lane]      = f2bf(o0 * inv * norm_w[lane]      * s0);
    yb[ob + 64 + lane] = f2bf(o1 * inv * norm_w[64 + lane] * s1);
  }
}

// ------------------------------------------------------------------------------------------
extern "C" void kernel_launch(void* const* d_in, const int* in_sizes, int n_in,
                              void* d_out, int out_size, void* d_ws, size_t ws_size,
                              hipStream_t stream) {
  const float* x      = (const float*)d_in[0];
  const float* Wq     = (const float*)d_in[1];
  const float* Wk     = (const float*)d_in[2];
  const float* Wv     = (const float*)d_in[3];
  const float* Wg     = (const float*)d_in[4];
  const float* Wgk1   = (const float*)d_in[5];
  const float* Wgk2   = (const float*)d_in[6];
  const float* bgk2   = (const float*)d_in[7];
  const float* Wo     = (const float*)d_in[8];
  const float* norm_w = (const float*)d_in[9];
  float* out = (float*)d_out;
  float* ws  = (float*)d_ws;

  // ws layout (float-element offsets)
  float*          qk   = ws;                               // f32 [M][2048] q|k
  float*          gkb  = ws + 8388608;                     // f32 [M][1024]
  unsigned short* vg   = (unsigned short*)(ws + 12582912); // bf16 [M][4096] v|g
  float*          o    = ws + 20971520;                    // f32 [M][2048]
  float*          Sseg = ws + 29360128;                    // f32 [B*H*NSEG][128e][64d]
  float*          Dseg = ws + 33554432;                    // 32768 f32
  float*          t1   = ws + 33587200;                    // 65536 f32

  // lifetime-disjoint aliases (stream order makes these safe)
  unsigned short* xb   = (unsigned short*)gkb;             // dead before lr2 writes gkb
  unsigned short* WqkT = (unsigned short*)o;               // dead before phase C writes o
  unsigned short* WvgT = (unsigned short*)(o + 2097152);   // dead before phase C writes o
  unsigned short* yb   = (unsigned short*)ws;              // qk dead after phase C
  unsigned short* WoT  = (unsigned short*)(ws + 4194304);  // qk dead after phase C

  dim3 blk(256);
  convert_f32_bf16<<<dim3((2097152 + 255)/256), blk, 0, stream>>>(x, xb, 2097152);
  transpose_f32_bf16<<<dim3(1024/32, 2048/32), blk, 0, stream>>>(Wq, WqkT, 2048, 1024);
  transpose_f32_bf16<<<dim3(1024/32, 2048/32), blk, 0, stream>>>(Wk, WqkT + (size_t)1024*2048, 2048, 1024);
  transpose_f32_bf16<<<dim3(2048/32, 2048/32), blk, 0, stream>>>(Wv, WvgT, 2048, 2048);
  transpose_f32_bf16<<<dim3(2048/32, 2048/32), blk, 0, stream>>>(Wg, WvgT + (size_t)2048*2048, 2048, 2048);
  gemm256<false><<<dim3(2048/256, 4096/256), dim3(512), 0, stream>>>(xb, WqkT, qk, M_, 2048, HID_);
  gemm256<true ><<<dim3(4096/256, 4096/256), dim3(512), 0, stream>>>(xb, WvgT, vg, M_, 4096, HID_);
  lr1_kernel<<<M_, blk, 0, stream>>>(x, Wgk1, t1);
  lr2_kernel<<<M_, blk, 0, stream>>>(t1, Wgk2, bgk2, gkb);
  gla_phase_a<<<B_*H_*NSEG, blk, 0, stream>>>(qk, vg, gkb, Sseg, Dseg);
  gla_combine<<<B_*H_, blk, 0, stream>>>(Sseg, Dseg);
  gla_phase_c<<<B_*H_*NSEG, blk, 0, stream>>>(qk, vg, gkb, Sseg, o);
  epilogue_kernel<<<M_, blk, 0, stream>>>(o, vg, norm_w, yb);
  transpose_f32_bf16<<<dim3(2048/32, 2048/32), blk, 0, stream>>>(Wo, WoT, 2048, 2048);
  gemm256<false><<<dim3(2048/256, 4096/256), dim3(512), 0, stream>>>(yb, WoT, out, M_, HID_, HID_);
}

// Round 7
// 303.240 us; speedup vs baseline: 11.5027x; 1.1708x over previous
//
#include <hip/hip_runtime.h>
#include <hip/hip_bf16.h>
#include <math.h>

// Problem constants
#define B_    2
#define T_    2048
#define HID_  2048
#define H_    16
#define DK_   64
#define DV_   128
#define CC    16
#define NCHUNK (T_/CC)     // 128
#define NSEG  16           // segments per (b,h); 8 chunks each
#define M_    (B_*T_)      // 4096
#define SCALE_ 0.125f      // DK^-0.5

typedef __attribute__((ext_vector_type(8))) __bf16 bf16x8;
typedef __attribute__((ext_vector_type(4))) float f32x4;

__device__ __forceinline__ unsigned short f2bf(float f) {
  unsigned int u = __float_as_uint(f);
  u += 0x7fff + ((u >> 16) & 1);   // RNE
  return (unsigned short)(u >> 16);
}
__device__ __forceinline__ float bf2f(unsigned short u) {
  return __uint_as_float(((unsigned int)u) << 16);
}

typedef const __attribute__((address_space(1))) void* as1cv;
typedef __attribute__((address_space(3))) void* as3v;
__device__ __forceinline__ void gload16(const void* g, void* l) {
  __builtin_amdgcn_global_load_lds((as1cv)g, (as3v)l, 16, 0, 0);
}

// ---------------- fused prep: x->bf16 convert + 5 weight transposes -----------------------
// grid: [0,8192) convert tiles; [8192, 8192+16384) transpose tiles.
__global__ __launch_bounds__(256) void prep_kernel(const float* __restrict__ x,
                                                   unsigned short* __restrict__ xb,
                                                   const float* __restrict__ Wq,
                                                   const float* __restrict__ Wk,
                                                   const float* __restrict__ Wv,
                                                   const float* __restrict__ Wg,
                                                   const float* __restrict__ Wo,
                                                   unsigned short* __restrict__ WqkT,
                                                   unsigned short* __restrict__ WvgT,
                                                   unsigned short* __restrict__ WoT) {
  int id = blockIdx.x;
  if (id < 8192) {
    int i = id * 256 + threadIdx.x;
    float4 f = reinterpret_cast<const float4*>(x)[i];
    ushort4 u;
    u.x = f2bf(f.x); u.y = f2bf(f.y); u.z = f2bf(f.z); u.w = f2bf(f.w);
    reinterpret_cast<ushort4*>(xb)[i] = u;
    return;
  }
  id -= 8192;
  const float* in; unsigned short* out; int N;
  if (id < 2048)       { in = Wq; out = WqkT;                         N = 1024; }
  else if (id < 4096)  { in = Wk; out = WqkT + (size_t)1024*2048;     N = 1024; id -= 2048; }
  else if (id < 8192)  { in = Wv; out = WvgT;                         N = 2048; id -= 4096; }
  else if (id < 12288) { in = Wg; out = WvgT + (size_t)2048*2048;     N = 2048; id -= 8192; }
  else                 { in = Wo; out = WoT;                          N = 2048; id -= 12288; }
  const int K = 2048;
  const int nx = N / 32;
  const int n0 = (id % nx) * 32;
  const int k0 = (id / nx) * 32;
  __shared__ float tile[32][33];
  const int tx = threadIdx.x & 31;
  const int ty = threadIdx.x >> 5;
  #pragma unroll
  for (int i = 0; i < 4; ++i)
    tile[ty + i*8][tx] = in[(size_t)(k0 + ty + i*8) * N + n0 + tx];
  __syncthreads();
  #pragma unroll
  for (int i = 0; i < 4; ++i) {
    int r = ty + i*8;
    out[(size_t)(n0 + r) * K + k0 + tx] = f2bf(tile[tx][r]);
  }
}

// ---------------- 256x256 8-phase bf16 MFMA GEMM (T1+T2+T3+T4+T5) -------------------------
template<bool OBF>
__global__ __launch_bounds__(512, 2) void gemm256(const unsigned short* __restrict__ A,
                                                  const unsigned short* __restrict__ Bt,
                                                  void* __restrict__ Cv,
                                                  int M, int N, int K) {
  __shared__ char ldsb[131072];
  const int t    = threadIdx.x;
  const int lane = t & 63;
  const int wid  = t >> 6;
  const int wr   = wid >> 2;        // 0..1
  const int wc   = wid & 3;         // 0..3
  const int lr   = lane & 15;
  const int lk   = lane >> 4;       // 0..3
  int flat = blockIdx.y * gridDim.x + blockIdx.x;
  if (gridDim.x * gridDim.y == 256) flat = (flat & 7) * 32 + (flat >> 3);  // XCD-chunked
  const int row0 = (flat / gridDim.x) * 256;
  const int col0 = (flat % gridDim.x) * 256;
  const int NKT  = K >> 6;
  const size_t K2 = (size_t)K * 2;

  const int r_s  = t >> 2;
  const int kx_s = ((t & 3) * 16) ^ (((t >> 5) & 1) << 5);

  const int ha = wr;
  const int hb = wc >> 1;
  const int rbl = (wc & 1) * 64;

  f32x4 acc[8][4];
  #pragma unroll
  for (int m = 0; m < 8; ++m)
    #pragma unroll
    for (int n = 0; n < 4; ++n) acc[m][n] = (f32x4){0.f, 0.f, 0.f, 0.f};

  auto stage_half = [&](int p, int o, int h, int kt) {
    const char* src = o ? (const char*)Bt : (const char*)A;
    const int R0 = (o ? col0 : row0) + h * 128;
    const char* g = src + (size_t)(R0 + r_s) * K2 + (size_t)kt * 128 + kx_s;
    char* l = ldsb + ((((p << 1) | o) << 1 | h) << 14) + t * 16;
    gload16(g, l);
    gload16(g + 64, l + 8192);
  };
  auto lda = [&](int p, int mf, int ks) -> bf16x8 {
    int r = mf * 16 + lr;
    int a = ((((p << 1) | 0) << 1 | ha) << 14) + ks * 8192 + r * 64 + lk * 16;
    a ^= ((r >> 3) & 1) << 5;
    return *(const bf16x8*)(ldsb + a);
  };
  auto ldb = [&](int p, int nf, int ks) -> bf16x8 {
    int r = rbl + nf * 16 + lr;
    int a = ((((p << 1) | 1) << 1 | hb) << 14) + ks * 8192 + r * 64 + lk * 16;
    a ^= ((r >> 3) & 1) << 5;
    return *(const bf16x8*)(ldsb + a);
  };

  stage_half(0, 1, 0, 0); stage_half(0, 1, 1, 0);
  stage_half(0, 0, 0, 0); stage_half(0, 0, 1, 0);
  if (1 < NKT) {
    stage_half(1, 1, 0, 1); stage_half(1, 1, 1, 1);
    stage_half(1, 0, 0, 1); stage_half(1, 0, 1, 1);
  }
  __builtin_amdgcn_sched_barrier(0);
  asm volatile("s_waitcnt vmcnt(8)" ::: "memory");
  __builtin_amdgcn_sched_barrier(0);
  __builtin_amdgcn_s_barrier();

  bf16x8 fa[4][2], fb[2][2], fb2[2][2];

  for (int kt = 0; kt < NKT; ++kt) {
    const int p = kt & 1;
    const bool st = (kt + 2 < NKT);
    #pragma unroll
    for (int m = 0; m < 4; ++m) { fa[m][0] = lda(p, m, 0); fa[m][1] = lda(p, m, 1); }
    #pragma unroll
    for (int n = 0; n < 2; ++n) { fb[n][0] = ldb(p, n, 0); fb[n][1] = ldb(p, n, 1); }
    __builtin_amdgcn_sched_barrier(0);
    __builtin_amdgcn_s_barrier();
    asm volatile("s_waitcnt lgkmcnt(0)" ::: "memory");
    __builtin_amdgcn_sched_barrier(0);
    __builtin_amdgcn_s_setprio(1);
    #pragma unroll
    for (int m = 0; m < 4; ++m)
      #pragma unroll
      for (int n = 0; n < 2; ++n) {
        acc[m][n] = __builtin_amdgcn_mfma_f32_16x16x32_bf16(fa[m][0], fb[n][0], acc[m][n], 0, 0, 0);
        acc[m][n] = __builtin_amdgcn_mfma_f32_16x16x32_bf16(fa[m][1], fb[n][1], acc[m][n], 0, 0, 0);
      }
    __builtin_amdgcn_s_setprio(0);
    __builtin_amdgcn_sched_barrier(0);
    __builtin_amdgcn_s_barrier();
    #pragma unroll
    for (int n = 0; n < 2; ++n) { fb2[n][0] = ldb(p, n + 2, 0); fb2[n][1] = ldb(p, n + 2, 1); }
    __builtin_amdgcn_sched_barrier(0);
    __builtin_amdgcn_s_barrier();
    asm volatile("s_waitcnt lgkmcnt(0)" ::: "memory");
    __builtin_amdgcn_sched_barrier(0);
    __builtin_amdgcn_s_setprio(1);
    #pragma unroll
    for (int m = 0; m < 4; ++m)
      #pragma unroll
      for (int n = 0; n < 2; ++n) {
        acc[m][n+2] = __builtin_amdgcn_mfma_f32_16x16x32_bf16(fa[m][0], fb2[n][0], acc[m][n+2], 0, 0, 0);
        acc[m][n+2] = __builtin_amdgcn_mfma_f32_16x16x32_bf16(fa[m][1], fb2[n][1], acc[m][n+2], 0, 0, 0);
      }
    __builtin_amdgcn_s_setprio(0);
    __builtin_amdgcn_sched_barrier(0);
    __builtin_amdgcn_s_barrier();
    if (st) { stage_half(p, 1, 0, kt + 2); stage_half(p, 1, 1, kt + 2); }
    #pragma unroll
    for (int m = 0; m < 4; ++m) { fa[m][0] = lda(p, m + 4, 0); fa[m][1] = lda(p, m + 4, 1); }
    __builtin_amdgcn_sched_barrier(0);
    __builtin_amdgcn_s_barrier();
    asm volatile("s_waitcnt lgkmcnt(0)" ::: "memory");
    __builtin_amdgcn_sched_barrier(0);
    __builtin_amdgcn_s_setprio(1);
    #pragma unroll
    for (int m = 0; m < 4; ++m)
      #pragma unroll
      for (int n = 0; n < 2; ++n) {
        acc[m+4][n] = __builtin_amdgcn_mfma_f32_16x16x32_bf16(fa[m][0], fb[n][0], acc[m+4][n], 0, 0, 0);
        acc[m+4][n] = __builtin_amdgcn_mfma_f32_16x16x32_bf16(fa[m][1], fb[n][1], acc[m+4][n], 0, 0, 0);
      }
    __builtin_amdgcn_s_setprio(0);
    __builtin_amdgcn_sched_barrier(0);
    __builtin_amdgcn_s_barrier();
    if (st) { stage_half(p, 0, 0, kt + 2); stage_half(p, 0, 1, kt + 2); }
    __builtin_amdgcn_sched_barrier(0);
    __builtin_amdgcn_s_setprio(1);
    #pragma unroll
    for (int m = 0; m < 4; ++m)
      #pragma unroll
      for (int n = 0; n < 2; ++n) {
        acc[m+4][n+2] = __builtin_amdgcn_mfma_f32_16x16x32_bf16(fa[m][0], fb2[n][0], acc[m+4][n+2], 0, 0, 0);
        acc[m+4][n+2] = __builtin_amdgcn_mfma_f32_16x16x32_bf16(fa[m][1], fb2[n][1], acc[m+4][n+2], 0, 0, 0);
      }
    __builtin_amdgcn_s_setprio(0);
    __builtin_amdgcn_sched_barrier(0);
    if (kt == NKT - 2) asm volatile("s_waitcnt vmcnt(0)" ::: "memory");
    else               asm volatile("s_waitcnt vmcnt(8)" ::: "memory");
    __builtin_amdgcn_sched_barrier(0);
    __builtin_amdgcn_s_barrier();
  }

  #pragma unroll
  for (int m = 0; m < 8; ++m) {
    int row = row0 + wr*128 + m*16 + lk*4;
    #pragma unroll
    for (int n = 0; n < 4; ++n) {
      int col = col0 + wc*64 + n*16 + lr;
      #pragma unroll
      for (int j = 0; j < 4; ++j) {
        if (OBF) ((unsigned short*)Cv)[(size_t)(row + j) * N + col] = f2bf(acc[m][n][j]);
        else     ((float*)Cv)[(size_t)(row + j) * N + col] = acc[m][n][j];
      }
    }
  }
}

// ---------------- 256x128 4-phase bf16 MFMA GEMM (for N=2048: fills 256 blocks) -----------
// Same machinery as gemm256, BM=256 BN=128. 8 waves (4Mx2N), per-wave 64x64 out.
// LDS 96KB: [buf][slot(A0,A1,B)][2 ks][128r][64B]. 6 gloads/thread/ktile -> vmcnt(6).
template<bool OBF>
__global__ __launch_bounds__(512, 2) void gemm256x128(const unsigned short* __restrict__ A,
                                                      const unsigned short* __restrict__ Bt,
                                                      void* __restrict__ Cv,
                                                      int M, int N, int K) {
  __shared__ char ldsb[98304];
  const int t    = threadIdx.x;
  const int lane = t & 63;
  const int wid  = t >> 6;
  const int wr   = wid >> 1;        // 0..3
  const int wc   = wid & 1;         // 0..1
  const int lr   = lane & 15;
  const int lk   = lane >> 4;       // 0..3
  int flat = blockIdx.y * gridDim.x + blockIdx.x;
  if (gridDim.x * gridDim.y == 256) flat = (flat & 7) * 32 + (flat >> 3);  // XCD-chunked
  const int row0 = (flat / gridDim.x) * 256;
  const int col0 = (flat % gridDim.x) * 128;
  const int NKT  = K >> 6;
  const size_t K2 = (size_t)K * 2;

  const int r_s  = t >> 2;
  const int kx_s = ((t & 3) * 16) ^ (((t >> 5) & 1) << 5);

  const int ha  = wr >> 1;          // A half this wave reads
  const int ral = (wr & 1) * 64;    // A local row base within half
  const int rbl = wc * 64;          // B local row base

  f32x4 acc[4][4];
  #pragma unroll
  for (int m = 0; m < 4; ++m)
    #pragma unroll
    for (int n = 0; n < 4; ++n) acc[m][n] = (f32x4){0.f, 0.f, 0.f, 0.f};

  auto stage_slot = [&](int p, int slot, int kt) {   // slot 0/1 = A halves, 2 = B
    const char* src = (slot == 2) ? (const char*)Bt : (const char*)A;
    const int R0 = (slot == 2) ? col0 : (row0 + slot * 128);
    const char* g = src + (size_t)(R0 + r_s) * K2 + (size_t)kt * 128 + kx_s;
    char* l = ldsb + p * 49152 + slot * 16384 + t * 16;
    gload16(g, l);
    gload16(g + 64, l + 8192);
  };
  auto lda = [&](int p, int mf, int ks) -> bf16x8 {
    int r = ral + mf * 16 + lr;
    int a = p * 49152 + ha * 16384 + ks * 8192 + r * 64 + lk * 16;
    a ^= ((r >> 3) & 1) << 5;
    return *(const bf16x8*)(ldsb + a);
  };
  auto ldb = [&](int p, int nf, int ks) -> bf16x8 {
    int r = rbl + nf * 16 + lr;
    int a = p * 49152 + 32768 + ks * 8192 + r * 64 + lk * 16;
    a ^= ((r >> 3) & 1) << 5;
    return *(const bf16x8*)(ldsb + a);
  };

  // prologue: kt0 {B, A0, A1}, kt1 {B, A0, A1} -> 12 gloads; wait all but newest 6.
  stage_slot(0, 2, 0); stage_slot(0, 0, 0); stage_slot(0, 1, 0);
  if (1 < NKT) { stage_slot(1, 2, 1); stage_slot(1, 0, 1); stage_slot(1, 1, 1); }
  __builtin_amdgcn_sched_barrier(0);
  asm volatile("s_waitcnt vmcnt(6)" ::: "memory");
  __builtin_amdgcn_sched_barrier(0);
  __builtin_amdgcn_s_barrier();

  bf16x8 fa[2][2], fa2[2][2], fb[2][2], fb2[2][2];

  for (int kt = 0; kt < NKT; ++kt) {
    const int p = kt & 1;
    const bool st = (kt + 2 < NKT);
    // P1: fa(m0-1), fb(n0-1); MFMA (m0-1)x(n0-1)
    #pragma unroll
    for (int m = 0; m < 2; ++m) { fa[m][0] = lda(p, m, 0); fa[m][1] = lda(p, m, 1); }
    #pragma unroll
    for (int n = 0; n < 2; ++n) { fb[n][0] = ldb(p, n, 0); fb[n][1] = ldb(p, n, 1); }
    __builtin_amdgcn_sched_barrier(0);
    __builtin_amdgcn_s_barrier();
    asm volatile("s_waitcnt lgkmcnt(0)" ::: "memory");
    __builtin_amdgcn_sched_barrier(0);
    __builtin_amdgcn_s_setprio(1);
    #pragma unroll
    for (int m = 0; m < 2; ++m)
      #pragma unroll
      for (int n = 0; n < 2; ++n) {
        acc[m][n] = __builtin_amdgcn_mfma_f32_16x16x32_bf16(fa[m][0], fb[n][0], acc[m][n], 0, 0, 0);
        acc[m][n] = __builtin_amdgcn_mfma_f32_16x16x32_bf16(fa[m][1], fb[n][1], acc[m][n], 0, 0, 0);
      }
    __builtin_amdgcn_s_setprio(0);
    __builtin_amdgcn_sched_barrier(0);
    __builtin_amdgcn_s_barrier();
    // P2: fb2(n2-3); MFMA (m0-1)x(n2-3)
    #pragma unroll
    for (int n = 0; n < 2; ++n) { fb2[n][0] = ldb(p, n + 2, 0); fb2[n][1] = ldb(p, n + 2, 1); }
    __builtin_amdgcn_sched_barrier(0);
    __builtin_amdgcn_s_barrier();
    asm volatile("s_waitcnt lgkmcnt(0)" ::: "memory");
    __builtin_amdgcn_sched_barrier(0);
    __builtin_amdgcn_s_setprio(1);
    #pragma unroll
    for (int m = 0; m < 2; ++m)
      #pragma unroll
      for (int n = 0; n < 2; ++n) {
        acc[m][n+2] = __builtin_amdgcn_mfma_f32_16x16x32_bf16(fa[m][0], fb2[n][0], acc[m][n+2], 0, 0, 0);
        acc[m][n+2] = __builtin_amdgcn_mfma_f32_16x16x32_bf16(fa[m][1], fb2[n][1], acc[m][n+2], 0, 0, 0);
      }
    __builtin_amdgcn_s_setprio(0);
    __builtin_amdgcn_sched_barrier(0);
    __builtin_amdgcn_s_barrier();
    // P3: restage B(p)<-kt+2; fa2(m2-3); MFMA (m2-3)x(n0-1); last read of fb slot
    if (st) stage_slot(p, 2, kt + 2);
    #pragma unroll
    for (int m = 0; m < 2; ++m) { fa2[m][0] = lda(p, m + 2, 0); fa2[m][1] = lda(p, m + 2, 1); }
    __builtin_amdgcn_sched_barrier(0);
    __builtin_amdgcn_s_barrier();
    asm volatile("s_waitcnt lgkmcnt(0)" ::: "memory");
    __builtin_amdgcn_sched_barrier(0);
    __builtin_amdgcn_s_setprio(1);
    #pragma unroll
    for (int m = 0; m < 2; ++m)
      #pragma unroll
      for (int n = 0; n < 2; ++n) {
        acc[m+2][n] = __builtin_amdgcn_mfma_f32_16x16x32_bf16(fa2[m][0], fb[n][0], acc[m+2][n], 0, 0, 0);
        acc[m+2][n] = __builtin_amdgcn_mfma_f32_16x16x32_bf16(fa2[m][1], fb[n][1], acc[m+2][n], 0, 0, 0);
      }
    __builtin_amdgcn_s_setprio(0);
    __builtin_amdgcn_sched_barrier(0);
    __builtin_amdgcn_s_barrier();
    // P4: restage A halves(p)<-kt+2; MFMA (m2-3)x(n2-3); counted vmcnt
    if (st) { stage_slot(p, 0, kt + 2); stage_slot(p, 1, kt + 2); }
    __builtin_amdgcn_sched_barrier(0);
    __builtin_amdgcn_s_setprio(1);
    #pragma unroll
    for (int m = 0; m < 2; ++m)
      #pragma unroll
      for (int n = 0; n < 2; ++n) {
        acc[m+2][n+2] = __builtin_amdgcn_mfma_f32_16x16x32_bf16(fa2[m][0], fb2[n][0], acc[m+2][n+2], 0, 0, 0);
        acc[m+2][n+2] = __builtin_amdgcn_mfma_f32_16x16x32_bf16(fa2[m][1], fb2[n][1], acc[m+2][n+2], 0, 0, 0);
      }
    __builtin_amdgcn_s_setprio(0);
    __builtin_amdgcn_sched_barrier(0);
    if (kt == NKT - 2) asm volatile("s_waitcnt vmcnt(0)" ::: "memory");
    else               asm volatile("s_waitcnt vmcnt(6)" ::: "memory");
    __builtin_amdgcn_sched_barrier(0);
    __builtin_amdgcn_s_barrier();
  }

  #pragma unroll
  for (int m = 0; m < 4; ++m) {
    int row = row0 + wr*64 + m*16 + lk*4;
    #pragma unroll
    for (int n = 0; n < 4; ++n) {
      int col = col0 + wc*64 + n*16 + lr;
      #pragma unroll
      for (int j = 0; j < 4; ++j) {
        if (OBF) ((unsigned short*)Cv)[(size_t)(row + j) * N + col] = f2bf(acc[m][n][j]);
        else     ((float*)Cv)[(size_t)(row + j) * N + col] = acc[m][n][j];
      }
    }
  }
}

// ---------------- fused low-rank gate: gk = log_sigmoid(x@W1@W2 + b)/16 -------------------
__global__ __launch_bounds__(256) void lr_kernel(const float* __restrict__ x,
                                                 const float* __restrict__ w1,
                                                 const float* __restrict__ w2,
                                                 const float* __restrict__ bias,
                                                 float* __restrict__ gkout) {
  __shared__ float part[16][17];
  __shared__ float tr[16];
  const int row = blockIdx.x;
  const int j = threadIdx.x & 15;
  const int p = threadIdx.x >> 4;
  const float* xr = x + (size_t)row * HID_;
  float acc = 0.f;
  const int k0 = p * 128;
  for (int kk = k0; kk < k0 + 128; kk += 4) {
    float4 xv = *reinterpret_cast<const float4*>(&xr[kk]);
    acc = fmaf(xv.x, w1[(kk+0)*16 + j], acc);
    acc = fmaf(xv.y, w1[(kk+1)*16 + j], acc);
    acc = fmaf(xv.z, w1[(kk+2)*16 + j], acc);
    acc = fmaf(xv.w, w1[(kk+3)*16 + j], acc);
  }
  part[p][j] = acc;
  __syncthreads();
  if (threadIdx.x < 16) {
    float s = 0.f;
    #pragma unroll
    for (int pp = 0; pp < 16; ++pp) s += part[pp][threadIdx.x];
    tr[threadIdx.x] = s;
  }
  __syncthreads();
  for (int n = threadIdx.x; n < H_*DK_; n += 256) {
    float a2 = bias[n];
    #pragma unroll
    for (int jj = 0; jj < 16; ++jj) a2 = fmaf(tr[jj], w2[jj * (H_*DK_) + n], a2);
    float ls = fminf(a2, 0.f) - log1pf(expf(-fabsf(a2)));
    gkout[(size_t)row * (H_*DK_) + n] = ls * (1.f / 16.f);
  }
}

// ---------------- GLA phase A (MFMA): per-segment local state S^T in registers ------------
__global__ __launch_bounds__(256) void gla_phase_a(const float* __restrict__ qk,
                                                   const unsigned short* __restrict__ vg,
                                                   const float* __restrict__ gk,
                                                   float* __restrict__ Sseg,
                                                   float* __restrict__ Dseg) {
  const int seg = blockIdx.x & 15;
  const int h   = (blockIdx.x >> 4) & 15;
  const int b   = blockIdx.x >> 8;
  const int t    = threadIdx.x;
  const int lane = t & 63;
  const int wid  = t >> 6;
  const int q    = lane >> 4;
  const int lr   = lane & 15;
  __shared__ float gc[16][68];
  __shared__ float dec_[64];
  __shared__ unsigned short kdT[64][40];   // [d][c], c>=16 zero
  __shared__ unsigned short vvT[128][40];  // [e][c], c>=16 zero

  for (int i = t; i < 1024; i += 256) kdT[i >> 4][16 + (i & 15)] = 0;
  for (int i = t; i < 2048; i += 256) vvT[i >> 4][16 + (i & 15)] = 0;

  f32x4 s_reg[2][4];
  #pragma unroll
  for (int et = 0; et < 2; ++et)
    #pragma unroll
    for (int dt = 0; dt < 4; ++dt) s_reg[et][dt] = (f32x4){0.f,0.f,0.f,0.f};
  float gt = 0.f;

  for (int c8 = 0; c8 < NCHUNK/NSEG; ++c8) {
    const int ch = seg * (NCHUNK/NSEG) + c8;
    __syncthreads();
    {
      float acc = 0.f;
      #pragma unroll
      for (int c = 0; c < CC; ++c) {
        acc += gk[((size_t)(b*T_ + ch*CC + c)) * 1024 + h*DK_ + lane];
        gc[c][lane] = acc;
      }
      gt += acc;
      dec_[lane] = expf(acc);
    }
    __syncthreads();
    {
      int c = t >> 4, d0 = (t & 15) * 4;
      float4 k4 = *reinterpret_cast<const float4*>(
          &qk[((size_t)(b*T_ + ch*CC + c)) * 2048 + 1024 + h*DK_ + d0]);
      float ka[4] = {k4.x, k4.y, k4.z, k4.w};
      #pragma unroll
      for (int j = 0; j < 4; ++j)
        kdT[d0 + j][c] = f2bf(ka[j] * expf(gc[CC-1][d0 + j] - gc[c][d0 + j]));
    }
    {
      int c = t & 15, e0 = (t >> 4) * 8;
      const ushort4* vp = reinterpret_cast<const ushort4*>(
          &vg[((size_t)(b*T_ + ch*CC + c)) * 4096 + h*DV_ + e0]);
      ushort4 a = vp[0], bb = vp[1];
      vvT[e0+0][c] = a.x;  vvT[e0+1][c] = a.y;  vvT[e0+2][c] = a.z;  vvT[e0+3][c] = a.w;
      vvT[e0+4][c] = bb.x; vvT[e0+5][c] = bb.y; vvT[e0+6][c] = bb.z; vvT[e0+7][c] = bb.w;
    }
    __syncthreads();
    bf16x8 vf[2], kf[4];
    #pragma unroll
    for (int et = 0; et < 2; ++et)
      vf[et] = *(const bf16x8*)&vvT[wid*32 + et*16 + lr][q*8];
    #pragma unroll
    for (int dt = 0; dt < 4; ++dt)
      kf[dt] = *(const bf16x8*)&kdT[dt*16 + lr][q*8];
    #pragma unroll
    for (int et = 0; et < 2; ++et)
      #pragma unroll
      for (int dt = 0; dt < 4; ++dt) {
        f32x4 dl = __builtin_amdgcn_mfma_f32_16x16x32_bf16(vf[et], kf[dt],
                     (f32x4){0.f,0.f,0.f,0.f}, 0, 0, 0);
        float dv = dec_[dt*16 + lr];
        #pragma unroll
        for (int j = 0; j < 4; ++j)
          s_reg[et][dt][j] = fmaf(s_reg[et][dt][j], dv, dl[j]);
      }
  }
  const size_t base = ((size_t)((b*H_ + h)*NSEG + seg)) * (DK_*DV_);
  #pragma unroll
  for (int et = 0; et < 2; ++et)
    #pragma unroll
    for (int dt = 0; dt < 4; ++dt)
      #pragma unroll
      for (int j = 0; j < 4; ++j)
        Sseg[base + (size_t)(wid*32 + et*16 + q*4 + j) * 64 + dt*16 + lr] = s_reg[et][dt][j];
  if (t < 64)
    Dseg[(size_t)((b*H_ + h)*NSEG + seg) * DK_ + t] = expf(gt);
}

// ---------------- GLA phase B: sequential combine over segments (Sseg is [e][d]) ----------
__global__ __launch_bounds__(256) void gla_combine(float* __restrict__ Sseg,
                                                   const float* __restrict__ Dseg) {
  const int bh = blockIdx.x;
  const int t = threadIdx.x;
  __shared__ float Dl[64];
  float4 S_run[8];
  #pragma unroll
  for (int j = 0; j < 8; ++j) S_run[j] = (float4){0.f,0.f,0.f,0.f};
  const int d0 = (t * 4) & 63;
  for (int seg = 0; seg < NSEG; ++seg) {
    const size_t base = ((size_t)bh*NSEG + seg) * (DK_*DV_);
    if (t < 64) Dl[t] = Dseg[((size_t)bh*NSEG + seg) * DK_ + t];
    __syncthreads();
    #pragma unroll
    for (int j = 0; j < 8; ++j) {
      int idx = j*1024 + t*4;
      float4 sl = *reinterpret_cast<float4*>(&Sseg[base + idx]);
      *reinterpret_cast<float4*>(&Sseg[base + idx]) = S_run[j];
      S_run[j].x = fmaf(Dl[d0+0], S_run[j].x, sl.x);
      S_run[j].y = fmaf(Dl[d0+1], S_run[j].y, sl.y);
      S_run[j].z = fmaf(Dl[d0+2], S_run[j].z, sl.z);
      S_run[j].w = fmaf(Dl[d0+3], S_run[j].w, sl.w);
    }
    __syncthreads();
  }
}

// ---------------- GLA phase C (MFMA): outputs + state march -------------------------------
__global__ __launch_bounds__(256) void gla_phase_c(const float* __restrict__ qk,
                                                   const unsigned short* __restrict__ vg,
                                                   const float* __restrict__ gk,
                                                   const float* __restrict__ Sseg,
                                                   float* __restrict__ o) {
  const int seg = blockIdx.x & 15;
  const int h   = (blockIdx.x >> 4) & 15;
  const int b   = blockIdx.x >> 8;
  const int t    = threadIdx.x;
  const int lane = t & 63;
  const int wid  = t >> 6;
  const int q    = lane >> 4;
  const int lr   = lane & 15;
  __shared__ float gc[16][68];
  __shared__ float dec_[64];
  __shared__ unsigned short qe[16][72];    // [c][d]
  __shared__ unsigned short ke[16][72];    // [m][d]
  __shared__ unsigned short kdT[64][40];   // [d][c], c>=16 zero
  __shared__ unsigned short vvT[128][40];  // [e][c], c>=16 zero
  __shared__ unsigned short Am[16][40];    // [c][m], m>=16 zero
  __shared__ unsigned short Sb[128][72];   // [e][d] bf16 shadow of S^T

  for (int i = t; i < 1024; i += 256) kdT[i >> 4][16 + (i & 15)] = 0;
  for (int i = t; i < 2048; i += 256) vvT[i >> 4][16 + (i & 15)] = 0;
  if (t < 256) { int c = t >> 4, m = t & 15; Am[c][16 + m] = 0; }

  f32x4 s_reg[2][4];
  const size_t sbase = ((size_t)((b*H_ + h)*NSEG + seg)) * (DK_*DV_);
  #pragma unroll
  for (int et = 0; et < 2; ++et)
    #pragma unroll
    for (int dt = 0; dt < 4; ++dt)
      #pragma unroll
      for (int j = 0; j < 4; ++j) {
        int e = wid*32 + et*16 + q*4 + j, d = dt*16 + lr;
        float v = Sseg[sbase + (size_t)e * 64 + d];
        s_reg[et][dt][j] = v;
        Sb[e][d] = f2bf(v);
      }

  for (int c8 = 0; c8 < NCHUNK/NSEG; ++c8) {
    const int ch = seg * (NCHUNK/NSEG) + c8;
    __syncthreads();
    {
      float acc = 0.f;
      #pragma unroll
      for (int c = 0; c < CC; ++c) {
        acc += gk[((size_t)(b*T_ + ch*CC + c)) * 1024 + h*DK_ + lane];
        gc[c][lane] = acc;
      }
      dec_[lane] = expf(acc);
    }
    __syncthreads();
    {
      int c = t >> 4, d0 = (t & 15) * 4;
      const size_t gbq = ((size_t)(b*T_ + ch*CC + c)) * 2048 + h*DK_ + d0;
      float4 q4 = *reinterpret_cast<const float4*>(&qk[gbq]);
      float4 k4 = *reinterpret_cast<const float4*>(&qk[gbq + 1024]);
      float qa[4] = {q4.x, q4.y, q4.z, q4.w};
      float ka[4] = {k4.x, k4.y, k4.z, k4.w};
      ushort4 qw, kw;
      unsigned short* qwp = (unsigned short*)&qw;
      unsigned short* kwp = (unsigned short*)&kw;
      #pragma unroll
      for (int j = 0; j < 4; ++j) {
        float gcv = gc[c][d0 + j];
        float gl  = gc[CC-1][d0 + j];
        qwp[j] = f2bf(qa[j] * expf(gcv) * SCALE_);
        kwp[j] = f2bf(ka[j] * expf(-gcv));
        kdT[d0 + j][c] = f2bf(ka[j] * expf(gl - gcv));
      }
      *reinterpret_cast<ushort4*>(&qe[c][d0]) = qw;
      *reinterpret_cast<ushort4*>(&ke[c][d0]) = kw;
    }
    {
      int c = t & 15, e0 = (t >> 4) * 8;
      const ushort4* vp = reinterpret_cast<const ushort4*>(
          &vg[((size_t)(b*T_ + ch*CC + c)) * 4096 + h*DV_ + e0]);
      ushort4 a = vp[0], bb = vp[1];
      vvT[e0+0][c] = a.x;  vvT[e0+1][c] = a.y;  vvT[e0+2][c] = a.z;  vvT[e0+3][c] = a.w;
      vvT[e0+4][c] = bb.x; vvT[e0+5][c] = bb.y; vvT[e0+6][c] = bb.z; vvT[e0+7][c] = bb.w;
    }
    __syncthreads();
    bf16x8 qA0 = *(const bf16x8*)&qe[lr][q*8];
    bf16x8 qA1 = *(const bf16x8*)&qe[lr][32 + q*8];
    {
      bf16x8 kB0 = *(const bf16x8*)&ke[lr][q*8];
      bf16x8 kB1 = *(const bf16x8*)&ke[lr][32 + q*8];
      f32x4 accA = __builtin_amdgcn_mfma_f32_16x16x32_bf16(qA0, kB0,
                     (f32x4){0.f,0.f,0.f,0.f}, 0, 0, 0);
      accA = __builtin_amdgcn_mfma_f32_16x16x32_bf16(qA1, kB1, accA, 0, 0, 0);
      #pragma unroll
      for (int j = 0; j < 4; ++j) {
        int c = q*4 + j;
        Am[c][lr] = (lr <= c) ? f2bf(accA[j]) : (unsigned short)0;
      }
    }
    bf16x8 vf[2], kf[4];
    #pragma unroll
    for (int et = 0; et < 2; ++et)
      vf[et] = *(const bf16x8*)&vvT[wid*32 + et*16 + lr][q*8];
    #pragma unroll
    for (int dt = 0; dt < 4; ++dt)
      kf[dt] = *(const bf16x8*)&kdT[dt*16 + lr][q*8];
    #pragma unroll
    for (int et = 0; et < 2; ++et)
      #pragma unroll
      for (int dt = 0; dt < 4; ++dt) {
        f32x4 dl = __builtin_amdgcn_mfma_f32_16x16x32_bf16(vf[et], kf[dt],
                     (f32x4){0.f,0.f,0.f,0.f}, 0, 0, 0);
        float dv = dec_[dt*16 + lr];
        #pragma unroll
        for (int j = 0; j < 4; ++j)
          s_reg[et][dt][j] = fmaf(s_reg[et][dt][j], dv, dl[j]);
      }
    __syncthreads();
    {
      bf16x8 amA = *(const bf16x8*)&Am[lr][q*8];
      #pragma unroll
      for (int et = 0; et < 2; ++et) {
        int e0 = wid*32 + et*16;
        bf16x8 sB0 = *(const bf16x8*)&Sb[e0 + lr][q*8];
        bf16x8 sB1 = *(const bf16x8*)&Sb[e0 + lr][32 + q*8];
        f32x4 accO = __builtin_amdgcn_mfma_f32_16x16x32_bf16(qA0, sB0,
                       (f32x4){0.f,0.f,0.f,0.f}, 0, 0, 0);
        accO = __builtin_amdgcn_mfma_f32_16x16x32_bf16(qA1, sB1, accO, 0, 0, 0);
        accO = __builtin_amdgcn_mfma_f32_16x16x32_bf16(amA, vf[et], accO, 0, 0, 0);
        #pragma unroll
        for (int j = 0; j < 4; ++j)
          o[((size_t)(b*T_ + ch*CC + q*4 + j)) * 2048 + h*DV_ + e0 + lr] = accO[j];
      }
    }
    __syncthreads();
    #pragma unroll
    for (int et = 0; et < 2; ++et)
      #pragma unroll
      for (int dt = 0; dt < 4; ++dt)
        #pragma unroll
        for (int j = 0; j < 4; ++j)
          Sb[wid*32 + et*16 + q*4 + j][dt*16 + lr] = f2bf(s_reg[et][dt][j]);
  }
}

// ---------------- fused RMSNorm(DV) * norm_w * SiLU(g) -> bf16 y --------------------------
__global__ __launch_bounds__(256) void epilogue_kernel(const float* __restrict__ o,
                                                       const unsigned short* __restrict__ vg,
                                                       const float* __restrict__ norm_w,
                                                       unsigned short* __restrict__ yb) {
  const int row  = blockIdx.x;
  const int wave = threadIdx.x >> 6;
  const int lane = threadIdx.x & 63;
  #pragma unroll
  for (int it = 0; it < 4; ++it) {
    const int h = it * 4 + wave;
    const size_t ob = (size_t)row * 2048 + (size_t)h * DV_;
    const size_t gb = (size_t)row * 4096 + 2048 + (size_t)h * DV_;
    float o0 = o[ob + lane];
    float o1 = o[ob + 64 + lane];
    float ss = o0*o0 + o1*o1;
    #pragma unroll
    for (int off = 32; off > 0; off >>= 1) ss += __shfl_xor(ss, off, 64);
    float inv = rsqrtf(ss * (1.f/128.f) + 1e-5f);
    float g0 = bf2f(vg[gb + lane]);
    float g1 = bf2f(vg[gb + 64 + lane]);
    float s0 = g0 / (1.f + expf(-g0));
    float s1 = g1 / (1.f + expf(-g1));
    yb[ob + lane]      = f2bf(o0 * inv * norm_w[lane]      * s0);
    yb[ob + 64 + lane] = f2bf(o1 * inv * norm_w[64 + lane] * s1);
  }
}

// ------------------------------------------------------------------------------------------
extern "C" void kernel_launch(void* const* d_in, const int* in_sizes, int n_in,
                              void* d_out, int out_size, void* d_ws, size_t ws_size,
                              hipStream_t stream) {
  const float* x      = (const float*)d_in[0];
  const float* Wq     = (const float*)d_in[1];
  const float* Wk     = (const float*)d_in[2];
  const float* Wv     = (const float*)d_in[3];
  const float* Wg     = (const float*)d_in[4];
  const float* Wgk1   = (const float*)d_in[5];
  const float* Wgk2   = (const float*)d_in[6];
  const float* bgk2   = (const float*)d_in[7];
  const float* Wo     = (const float*)d_in[8];
  const float* norm_w = (const float*)d_in[9];
  float* out = (float*)d_out;
  float* ws  = (float*)d_ws;

  // ws layout (float-element offsets)
  float*          qk   = ws;                               // f32 [M][2048] q|k
  float*          gkb  = ws + 8388608;                     // f32 [M][1024]
  unsigned short* vg   = (unsigned short*)(ws + 12582912); // bf16 [M][4096] v|g
  float*          o    = ws + 20971520;                    // f32 [M][2048]
  float*          Sseg = ws + 29360128;                    // f32 [B*H*NSEG][128e][64d]
  float*          Dseg = ws + 33554432;                    // 32768 f32
  float*          t1u  = ws + 33587200;                    // (unused, kept for layout)
  unsigned short* WoT  = (unsigned short*)(ws + 33652736); // bf16 [2048][2048] (dedicated)

  // lifetime-disjoint aliases (stream order makes these safe)
  unsigned short* xb   = (unsigned short*)gkb;             // dead before lr writes gkb
  unsigned short* WqkT = (unsigned short*)o;               // dead before phase C writes o
  unsigned short* WvgT = (unsigned short*)(o + 2097152);   // dead before phase C writes o
  unsigned short* yb   = (unsigned short*)ws;              // qk dead after phase C
  (void)t1u;

  dim3 blk(256);
  // convert x + all 5 weight transposes in one dispatch
  prep_kernel<<<dim3(24576), blk, 0, stream>>>(x, xb, Wq, Wk, Wv, Wg, Wo, WqkT, WvgT, WoT);
  // projections
  gemm256x128<false><<<dim3(2048/128, 4096/256), dim3(512), 0, stream>>>(xb, WqkT, qk, M_, 2048, HID_);
  gemm256<true     ><<<dim3(4096/256, 4096/256), dim3(512), 0, stream>>>(xb, WvgT, vg, M_, 4096, HID_);
  // gate path (after GEMMs: gkb overwrites xb)
  lr_kernel<<<M_, blk, 0, stream>>>(x, Wgk1, Wgk2, bgk2, gkb);
  // GLA scan
  gla_phase_a<<<B_*H_*NSEG, blk, 0, stream>>>(qk, vg, gkb, Sseg, Dseg);
  gla_combine<<<B_*H_, blk, 0, stream>>>(Sseg, Dseg);
  gla_phase_c<<<B_*H_*NSEG, blk, 0, stream>>>(qk, vg, gkb, Sseg, o);
  // epilogue -> bf16 y
  epilogue_kernel<<<M_, blk, 0, stream>>>(o, vg, norm_w, yb);
  // output projection
  gemm256x128<false><<<dim3(2048/128, 4096/256), dim3(512), 0, stream>>>(yb, WoT, out, M_, HID_, HID_);
}

// Round 8
// 296.299 us; speedup vs baseline: 11.7722x; 1.0234x over previous
//
#include <hip/hip_runtime.h>
#include <hip/hip_bf16.h>
#include <math.h>

// Problem constants
#define B_    2
#define T_    2048
#define HID_  2048
#define H_    16
#define DK_   64
#define DV_   128
#define CC    16
#define NCHUNK (T_/CC)     // 128
#define NSEG  16           // segments per (b,h); 8 chunks each
#define M_    (B_*T_)      // 4096
#define SCALE_ 0.125f      // DK^-0.5

typedef __attribute__((ext_vector_type(8))) __bf16 bf16x8;
typedef __attribute__((ext_vector_type(4))) float f32x4;

__device__ __forceinline__ unsigned short f2bf(float f) {
  unsigned int u = __float_as_uint(f);
  u += 0x7fff + ((u >> 16) & 1);   // RNE
  return (unsigned short)(u >> 16);
}
__device__ __forceinline__ float bf2f(unsigned short u) {
  return __uint_as_float(((unsigned int)u) << 16);
}

typedef const __attribute__((address_space(1))) void* as1cv;
typedef __attribute__((address_space(3))) void* as3v;
__device__ __forceinline__ void gload16(const void* g, void* l) {
  __builtin_amdgcn_global_load_lds((as1cv)g, (as3v)l, 16, 0, 0);
}

// ---------------- fused prep: x->bf16 convert + 5 weight transposes -----------------------
__global__ __launch_bounds__(256) void prep_kernel(const float* __restrict__ x,
                                                   unsigned short* __restrict__ xb,
                                                   const float* __restrict__ Wq,
                                                   const float* __restrict__ Wk,
                                                   const float* __restrict__ Wv,
                                                   const float* __restrict__ Wg,
                                                   const float* __restrict__ Wo,
                                                   unsigned short* __restrict__ WqkT,
                                                   unsigned short* __restrict__ WvgT,
                                                   unsigned short* __restrict__ WoT) {
  int id = blockIdx.x;
  if (id < 8192) {
    int i = id * 256 + threadIdx.x;
    float4 f = reinterpret_cast<const float4*>(x)[i];
    ushort4 u;
    u.x = f2bf(f.x); u.y = f2bf(f.y); u.z = f2bf(f.z); u.w = f2bf(f.w);
    reinterpret_cast<ushort4*>(xb)[i] = u;
    return;
  }
  id -= 8192;
  const float* in; unsigned short* out; int N;
  if (id < 2048)       { in = Wq; out = WqkT;                         N = 1024; }
  else if (id < 4096)  { in = Wk; out = WqkT + (size_t)1024*2048;     N = 1024; id -= 2048; }
  else if (id < 8192)  { in = Wv; out = WvgT;                         N = 2048; id -= 4096; }
  else if (id < 12288) { in = Wg; out = WvgT + (size_t)2048*2048;     N = 2048; id -= 8192; }
  else                 { in = Wo; out = WoT;                          N = 2048; id -= 12288; }
  const int K = 2048;
  const int nx = N / 32;
  const int n0 = (id % nx) * 32;
  const int k0 = (id / nx) * 32;
  __shared__ float tile[32][33];
  const int tx = threadIdx.x & 31;
  const int ty = threadIdx.x >> 5;
  #pragma unroll
  for (int i = 0; i < 4; ++i)
    tile[ty + i*8][tx] = in[(size_t)(k0 + ty + i*8) * N + n0 + tx];
  __syncthreads();
  #pragma unroll
  for (int i = 0; i < 4; ++i) {
    int r = ty + i*8;
    out[(size_t)(n0 + r) * K + k0 + tx] = f2bf(tile[tx][r]);
  }
}

// ---------------- 256x256 8-phase bf16 MFMA GEMM (T1+T2+T3+T4+T5) -------------------------
template<bool OBF>
__global__ __launch_bounds__(512, 2) void gemm256(const unsigned short* __restrict__ A,
                                                  const unsigned short* __restrict__ Bt,
                                                  void* __restrict__ Cv,
                                                  int M, int N, int K) {
  __shared__ char ldsb[131072];
  const int t    = threadIdx.x;
  const int lane = t & 63;
  const int wid  = t >> 6;
  const int wr   = wid >> 2;        // 0..1
  const int wc   = wid & 3;         // 0..3
  const int lr   = lane & 15;
  const int lk   = lane >> 4;       // 0..3
  int flat = blockIdx.y * gridDim.x + blockIdx.x;
  if (gridDim.x * gridDim.y == 256) flat = (flat & 7) * 32 + (flat >> 3);  // XCD-chunked
  const int row0 = (flat / gridDim.x) * 256;
  const int col0 = (flat % gridDim.x) * 256;
  const int NKT  = K >> 6;
  const size_t K2 = (size_t)K * 2;

  const int r_s  = t >> 2;
  const int kx_s = ((t & 3) * 16) ^ (((t >> 5) & 1) << 5);

  const int ha = wr;
  const int hb = wc >> 1;
  const int rbl = (wc & 1) * 64;

  f32x4 acc[8][4];
  #pragma unroll
  for (int m = 0; m < 8; ++m)
    #pragma unroll
    for (int n = 0; n < 4; ++n) acc[m][n] = (f32x4){0.f, 0.f, 0.f, 0.f};

  auto stage_half = [&](int p, int o, int h, int kt) {
    const char* src = o ? (const char*)Bt : (const char*)A;
    const int R0 = (o ? col0 : row0) + h * 128;
    const char* g = src + (size_t)(R0 + r_s) * K2 + (size_t)kt * 128 + kx_s;
    char* l = ldsb + ((((p << 1) | o) << 1 | h) << 14) + t * 16;
    gload16(g, l);
    gload16(g + 64, l + 8192);
  };
  auto lda = [&](int p, int mf, int ks) -> bf16x8 {
    int r = mf * 16 + lr;
    int a = ((((p << 1) | 0) << 1 | ha) << 14) + ks * 8192 + r * 64 + lk * 16;
    a ^= ((r >> 3) & 1) << 5;
    return *(const bf16x8*)(ldsb + a);
  };
  auto ldb = [&](int p, int nf, int ks) -> bf16x8 {
    int r = rbl + nf * 16 + lr;
    int a = ((((p << 1) | 1) << 1 | hb) << 14) + ks * 8192 + r * 64 + lk * 16;
    a ^= ((r >> 3) & 1) << 5;
    return *(const bf16x8*)(ldsb + a);
  };

  stage_half(0, 1, 0, 0); stage_half(0, 1, 1, 0);
  stage_half(0, 0, 0, 0); stage_half(0, 0, 1, 0);
  if (1 < NKT) {
    stage_half(1, 1, 0, 1); stage_half(1, 1, 1, 1);
    stage_half(1, 0, 0, 1); stage_half(1, 0, 1, 1);
  }
  __builtin_amdgcn_sched_barrier(0);
  asm volatile("s_waitcnt vmcnt(8)" ::: "memory");
  __builtin_amdgcn_sched_barrier(0);
  __builtin_amdgcn_s_barrier();

  bf16x8 fa[4][2], fb[2][2], fb2[2][2];

  for (int kt = 0; kt < NKT; ++kt) {
    const int p = kt & 1;
    const bool st = (kt + 2 < NKT);
    #pragma unroll
    for (int m = 0; m < 4; ++m) { fa[m][0] = lda(p, m, 0); fa[m][1] = lda(p, m, 1); }
    #pragma unroll
    for (int n = 0; n < 2; ++n) { fb[n][0] = ldb(p, n, 0); fb[n][1] = ldb(p, n, 1); }
    __builtin_amdgcn_sched_barrier(0);
    __builtin_amdgcn_s_barrier();
    asm volatile("s_waitcnt lgkmcnt(0)" ::: "memory");
    __builtin_amdgcn_sched_barrier(0);
    __builtin_amdgcn_s_setprio(1);
    #pragma unroll
    for (int m = 0; m < 4; ++m)
      #pragma unroll
      for (int n = 0; n < 2; ++n) {
        acc[m][n] = __builtin_amdgcn_mfma_f32_16x16x32_bf16(fa[m][0], fb[n][0], acc[m][n], 0, 0, 0);
        acc[m][n] = __builtin_amdgcn_mfma_f32_16x16x32_bf16(fa[m][1], fb[n][1], acc[m][n], 0, 0, 0);
      }
    __builtin_amdgcn_s_setprio(0);
    __builtin_amdgcn_sched_barrier(0);
    __builtin_amdgcn_s_barrier();
    #pragma unroll
    for (int n = 0; n < 2; ++n) { fb2[n][0] = ldb(p, n + 2, 0); fb2[n][1] = ldb(p, n + 2, 1); }
    __builtin_amdgcn_sched_barrier(0);
    __builtin_amdgcn_s_barrier();
    asm volatile("s_waitcnt lgkmcnt(0)" ::: "memory");
    __builtin_amdgcn_sched_barrier(0);
    __builtin_amdgcn_s_setprio(1);
    #pragma unroll
    for (int m = 0; m < 4; ++m)
      #pragma unroll
      for (int n = 0; n < 2; ++n) {
        acc[m][n+2] = __builtin_amdgcn_mfma_f32_16x16x32_bf16(fa[m][0], fb2[n][0], acc[m][n+2], 0, 0, 0);
        acc[m][n+2] = __builtin_amdgcn_mfma_f32_16x16x32_bf16(fa[m][1], fb2[n][1], acc[m][n+2], 0, 0, 0);
      }
    __builtin_amdgcn_s_setprio(0);
    __builtin_amdgcn_sched_barrier(0);
    __builtin_amdgcn_s_barrier();
    if (st) { stage_half(p, 1, 0, kt + 2); stage_half(p, 1, 1, kt + 2); }
    #pragma unroll
    for (int m = 0; m < 4; ++m) { fa[m][0] = lda(p, m + 4, 0); fa[m][1] = lda(p, m + 4, 1); }
    __builtin_amdgcn_sched_barrier(0);
    __builtin_amdgcn_s_barrier();
    asm volatile("s_waitcnt lgkmcnt(0)" ::: "memory");
    __builtin_amdgcn_sched_barrier(0);
    __builtin_amdgcn_s_setprio(1);
    #pragma unroll
    for (int m = 0; m < 4; ++m)
      #pragma unroll
      for (int n = 0; n < 2; ++n) {
        acc[m+4][n] = __builtin_amdgcn_mfma_f32_16x16x32_bf16(fa[m][0], fb[n][0], acc[m+4][n], 0, 0, 0);
        acc[m+4][n] = __builtin_amdgcn_mfma_f32_16x16x32_bf16(fa[m][1], fb[n][1], acc[m+4][n], 0, 0, 0);
      }
    __builtin_amdgcn_s_setprio(0);
    __builtin_amdgcn_sched_barrier(0);
    __builtin_amdgcn_s_barrier();
    if (st) { stage_half(p, 0, 0, kt + 2); stage_half(p, 0, 1, kt + 2); }
    __builtin_amdgcn_sched_barrier(0);
    __builtin_amdgcn_s_setprio(1);
    #pragma unroll
    for (int m = 0; m < 4; ++m)
      #pragma unroll
      for (int n = 0; n < 2; ++n) {
        acc[m+4][n+2] = __builtin_amdgcn_mfma_f32_16x16x32_bf16(fa[m][0], fb2[n][0], acc[m+4][n+2], 0, 0, 0);
        acc[m+4][n+2] = __builtin_amdgcn_mfma_f32_16x16x32_bf16(fa[m][1], fb2[n][1], acc[m+4][n+2], 0, 0, 0);
      }
    __builtin_amdgcn_s_setprio(0);
    __builtin_amdgcn_sched_barrier(0);
    if (kt == NKT - 2) asm volatile("s_waitcnt vmcnt(0)" ::: "memory");
    else               asm volatile("s_waitcnt vmcnt(8)" ::: "memory");
    __builtin_amdgcn_sched_barrier(0);
    __builtin_amdgcn_s_barrier();
  }

  #pragma unroll
  for (int m = 0; m < 8; ++m) {
    int row = row0 + wr*128 + m*16 + lk*4;
    #pragma unroll
    for (int n = 0; n < 4; ++n) {
      int col = col0 + wc*64 + n*16 + lr;
      #pragma unroll
      for (int j = 0; j < 4; ++j) {
        if (OBF) ((unsigned short*)Cv)[(size_t)(row + j) * N + col] = f2bf(acc[m][n][j]);
        else     ((float*)Cv)[(size_t)(row + j) * N + col] = acc[m][n][j];
      }
    }
  }
}

// ---------------- 256x128 4-phase bf16 MFMA GEMM (for N=2048: fills 256 blocks) -----------
template<bool OBF>
__global__ __launch_bounds__(512, 2) void gemm256x128(const unsigned short* __restrict__ A,
                                                      const unsigned short* __restrict__ Bt,
                                                      void* __restrict__ Cv,
                                                      int M, int N, int K) {
  __shared__ char ldsb[98304];
  const int t    = threadIdx.x;
  const int lane = t & 63;
  const int wid  = t >> 6;
  const int wr   = wid >> 1;        // 0..3
  const int wc   = wid & 1;         // 0..1
  const int lr   = lane & 15;
  const int lk   = lane >> 4;       // 0..3
  int flat = blockIdx.y * gridDim.x + blockIdx.x;
  if (gridDim.x * gridDim.y == 256) flat = (flat & 7) * 32 + (flat >> 3);  // XCD-chunked
  const int row0 = (flat / gridDim.x) * 256;
  const int col0 = (flat % gridDim.x) * 128;
  const int NKT  = K >> 6;
  const size_t K2 = (size_t)K * 2;

  const int r_s  = t >> 2;
  const int kx_s = ((t & 3) * 16) ^ (((t >> 5) & 1) << 5);

  const int ha  = wr >> 1;
  const int ral = (wr & 1) * 64;
  const int rbl = wc * 64;

  f32x4 acc[4][4];
  #pragma unroll
  for (int m = 0; m < 4; ++m)
    #pragma unroll
    for (int n = 0; n < 4; ++n) acc[m][n] = (f32x4){0.f, 0.f, 0.f, 0.f};

  auto stage_slot = [&](int p, int slot, int kt) {   // slot 0/1 = A halves, 2 = B
    const char* src = (slot == 2) ? (const char*)Bt : (const char*)A;
    const int R0 = (slot == 2) ? col0 : (row0 + slot * 128);
    const char* g = src + (size_t)(R0 + r_s) * K2 + (size_t)kt * 128 + kx_s;
    char* l = ldsb + p * 49152 + slot * 16384 + t * 16;
    gload16(g, l);
    gload16(g + 64, l + 8192);
  };
  auto lda = [&](int p, int mf, int ks) -> bf16x8 {
    int r = ral + mf * 16 + lr;
    int a = p * 49152 + ha * 16384 + ks * 8192 + r * 64 + lk * 16;
    a ^= ((r >> 3) & 1) << 5;
    return *(const bf16x8*)(ldsb + a);
  };
  auto ldb = [&](int p, int nf, int ks) -> bf16x8 {
    int r = rbl + nf * 16 + lr;
    int a = p * 49152 + 32768 + ks * 8192 + r * 64 + lk * 16;
    a ^= ((r >> 3) & 1) << 5;
    return *(const bf16x8*)(ldsb + a);
  };

  stage_slot(0, 2, 0); stage_slot(0, 0, 0); stage_slot(0, 1, 0);
  if (1 < NKT) { stage_slot(1, 2, 1); stage_slot(1, 0, 1); stage_slot(1, 1, 1); }
  __builtin_amdgcn_sched_barrier(0);
  asm volatile("s_waitcnt vmcnt(6)" ::: "memory");
  __builtin_amdgcn_sched_barrier(0);
  __builtin_amdgcn_s_barrier();

  bf16x8 fa[2][2], fa2[2][2], fb[2][2], fb2[2][2];

  for (int kt = 0; kt < NKT; ++kt) {
    const int p = kt & 1;
    const bool st = (kt + 2 < NKT);
    #pragma unroll
    for (int m = 0; m < 2; ++m) { fa[m][0] = lda(p, m, 0); fa[m][1] = lda(p, m, 1); }
    #pragma unroll
    for (int n = 0; n < 2; ++n) { fb[n][0] = ldb(p, n, 0); fb[n][1] = ldb(p, n, 1); }
    __builtin_amdgcn_sched_barrier(0);
    __builtin_amdgcn_s_barrier();
    asm volatile("s_waitcnt lgkmcnt(0)" ::: "memory");
    __builtin_amdgcn_sched_barrier(0);
    __builtin_amdgcn_s_setprio(1);
    #pragma unroll
    for (int m = 0; m < 2; ++m)
      #pragma unroll
      for (int n = 0; n < 2; ++n) {
        acc[m][n] = __builtin_amdgcn_mfma_f32_16x16x32_bf16(fa[m][0], fb[n][0], acc[m][n], 0, 0, 0);
        acc[m][n] = __builtin_amdgcn_mfma_f32_16x16x32_bf16(fa[m][1], fb[n][1], acc[m][n], 0, 0, 0);
      }
    __builtin_amdgcn_s_setprio(0);
    __builtin_amdgcn_sched_barrier(0);
    __builtin_amdgcn_s_barrier();
    #pragma unroll
    for (int n = 0; n < 2; ++n) { fb2[n][0] = ldb(p, n + 2, 0); fb2[n][1] = ldb(p, n + 2, 1); }
    __builtin_amdgcn_sched_barrier(0);
    __builtin_amdgcn_s_barrier();
    asm volatile("s_waitcnt lgkmcnt(0)" ::: "memory");
    __builtin_amdgcn_sched_barrier(0);
    __builtin_amdgcn_s_setprio(1);
    #pragma unroll
    for (int m = 0; m < 2; ++m)
      #pragma unroll
      for (int n = 0; n < 2; ++n) {
        acc[m][n+2] = __builtin_amdgcn_mfma_f32_16x16x32_bf16(fa[m][0], fb2[n][0], acc[m][n+2], 0, 0, 0);
        acc[m][n+2] = __builtin_amdgcn_mfma_f32_16x16x32_bf16(fa[m][1], fb2[n][1], acc[m][n+2], 0, 0, 0);
      }
    __builtin_amdgcn_s_setprio(0);
    __builtin_amdgcn_sched_barrier(0);
    __builtin_amdgcn_s_barrier();
    if (st) stage_slot(p, 2, kt + 2);
    #pragma unroll
    for (int m = 0; m < 2; ++m) { fa2[m][0] = lda(p, m + 2, 0); fa2[m][1] = lda(p, m + 2, 1); }
    __builtin_amdgcn_sched_barrier(0);
    __builtin_amdgcn_s_barrier();
    asm volatile("s_waitcnt lgkmcnt(0)" ::: "memory");
    __builtin_amdgcn_sched_barrier(0);
    __builtin_amdgcn_s_setprio(1);
    #pragma unroll
    for (int m = 0; m < 2; ++m)
      #pragma unroll
      for (int n = 0; n < 2; ++n) {
        acc[m+2][n] = __builtin_amdgcn_mfma_f32_16x16x32_bf16(fa2[m][0], fb[n][0], acc[m+2][n], 0, 0, 0);
        acc[m+2][n] = __builtin_amdgcn_mfma_f32_16x16x32_bf16(fa2[m][1], fb[n][1], acc[m+2][n], 0, 0, 0);
      }
    __builtin_amdgcn_s_setprio(0);
    __builtin_amdgcn_sched_barrier(0);
    __builtin_amdgcn_s_barrier();
    if (st) { stage_slot(p, 0, kt + 2); stage_slot(p, 1, kt + 2); }
    __builtin_amdgcn_sched_barrier(0);
    __builtin_amdgcn_s_setprio(1);
    #pragma unroll
    for (int m = 0; m < 2; ++m)
      #pragma unroll
      for (int n = 0; n < 2; ++n) {
        acc[m+2][n+2] = __builtin_amdgcn_mfma_f32_16x16x32_bf16(fa2[m][0], fb2[n][0], acc[m+2][n+2], 0, 0, 0);
        acc[m+2][n+2] = __builtin_amdgcn_mfma_f32_16x16x32_bf16(fa2[m][1], fb2[n][1], acc[m+2][n+2], 0, 0, 0);
      }
    __builtin_amdgcn_s_setprio(0);
    __builtin_amdgcn_sched_barrier(0);
    if (kt == NKT - 2) asm volatile("s_waitcnt vmcnt(0)" ::: "memory");
    else               asm volatile("s_waitcnt vmcnt(6)" ::: "memory");
    __builtin_amdgcn_sched_barrier(0);
    __builtin_amdgcn_s_barrier();
  }

  #pragma unroll
  for (int m = 0; m < 4; ++m) {
    int row = row0 + wr*64 + m*16 + lk*4;
    #pragma unroll
    for (int n = 0; n < 4; ++n) {
      int col = col0 + wc*64 + n*16 + lr;
      #pragma unroll
      for (int j = 0; j < 4; ++j) {
        if (OBF) ((unsigned short*)Cv)[(size_t)(row + j) * N + col] = f2bf(acc[m][n][j]);
        else     ((float*)Cv)[(size_t)(row + j) * N + col] = acc[m][n][j];
      }
    }
  }
}

// ---------------- fused low-rank gate: gk = log_sigmoid(x@W1@W2 + b)/16 -------------------
__global__ __launch_bounds__(256) void lr_kernel(const float* __restrict__ x,
                                                 const float* __restrict__ w1,
                                                 const float* __restrict__ w2,
                                                 const float* __restrict__ bias,
                                                 float* __restrict__ gkout) {
  __shared__ float part[16][17];
  __shared__ float tr[16];
  const int row = blockIdx.x;
  const int j = threadIdx.x & 15;
  const int p = threadIdx.x >> 4;
  const float* xr = x + (size_t)row * HID_;
  float acc = 0.f;
  const int k0 = p * 128;
  for (int kk = k0; kk < k0 + 128; kk += 4) {
    float4 xv = *reinterpret_cast<const float4*>(&xr[kk]);
    acc = fmaf(xv.x, w1[(kk+0)*16 + j], acc);
    acc = fmaf(xv.y, w1[(kk+1)*16 + j], acc);
    acc = fmaf(xv.z, w1[(kk+2)*16 + j], acc);
    acc = fmaf(xv.w, w1[(kk+3)*16 + j], acc);
  }
  part[p][j] = acc;
  __syncthreads();
  if (threadIdx.x < 16) {
    float s = 0.f;
    #pragma unroll
    for (int pp = 0; pp < 16; ++pp) s += part[pp][threadIdx.x];
    tr[threadIdx.x] = s;
  }
  __syncthreads();
  for (int n = threadIdx.x; n < H_*DK_; n += 256) {
    float a2 = bias[n];
    #pragma unroll
    for (int jj = 0; jj < 16; ++jj) a2 = fmaf(tr[jj], w2[jj * (H_*DK_) + n], a2);
    float ls = fminf(a2, 0.f) - log1pf(expf(-fabsf(a2)));
    gkout[(size_t)row * (H_*DK_) + n] = ls * (1.f / 16.f);
  }
}

// ---------------- GLA phase A (MFMA): per-segment local state S^T in registers ------------
__global__ __launch_bounds__(256) void gla_phase_a(const float* __restrict__ qk,
                                                   const unsigned short* __restrict__ vg,
                                                   const float* __restrict__ gk,
                                                   float* __restrict__ Sseg,
                                                   float* __restrict__ Dseg) {
  const int seg = blockIdx.x & 15;
  const int h   = (blockIdx.x >> 4) & 15;
  const int b   = blockIdx.x >> 8;
  const int t    = threadIdx.x;
  const int lane = t & 63;
  const int wid  = t >> 6;
  const int q    = lane >> 4;
  const int lr   = lane & 15;
  __shared__ float gc[16][68];
  __shared__ float dec_[64];
  __shared__ unsigned short kdT[64][40];   // [d][c], c>=16 zero
  __shared__ unsigned short vvT[128][40];  // [e][c], c>=16 zero

  for (int i = t; i < 1024; i += 256) kdT[i >> 4][16 + (i & 15)] = 0;
  for (int i = t; i < 2048; i += 256) vvT[i >> 4][16 + (i & 15)] = 0;

  f32x4 s_reg[2][4];
  #pragma unroll
  for (int et = 0; et < 2; ++et)
    #pragma unroll
    for (int dt = 0; dt < 4; ++dt) s_reg[et][dt] = (f32x4){0.f,0.f,0.f,0.f};
  float gt = 0.f;

  for (int c8 = 0; c8 < NCHUNK/NSEG; ++c8) {
    const int ch = seg * (NCHUNK/NSEG) + c8;
    __syncthreads();
    {
      float acc = 0.f;
      #pragma unroll
      for (int c = 0; c < CC; ++c) {
        acc += gk[((size_t)(b*T_ + ch*CC + c)) * 1024 + h*DK_ + lane];
        gc[c][lane] = acc;
      }
      gt += acc;
      dec_[lane] = expf(acc);
    }
    __syncthreads();
    {
      int c = t >> 4, d0 = (t & 15) * 4;
      float4 k4 = *reinterpret_cast<const float4*>(
          &qk[((size_t)(b*T_ + ch*CC + c)) * 2048 + 1024 + h*DK_ + d0]);
      float ka[4] = {k4.x, k4.y, k4.z, k4.w};
      #pragma unroll
      for (int j = 0; j < 4; ++j)
        kdT[d0 + j][c] = f2bf(ka[j] * expf(gc[CC-1][d0 + j] - gc[c][d0 + j]));
    }
    {
      int c = t & 15, e0 = (t >> 4) * 8;
      const ushort4* vp = reinterpret_cast<const ushort4*>(
          &vg[((size_t)(b*T_ + ch*CC + c)) * 4096 + h*DV_ + e0]);
      ushort4 a = vp[0], bb = vp[1];
      vvT[e0+0][c] = a.x;  vvT[e0+1][c] = a.y;  vvT[e0+2][c] = a.z;  vvT[e0+3][c] = a.w;
      vvT[e0+4][c] = bb.x; vvT[e0+5][c] = bb.y; vvT[e0+6][c] = bb.z; vvT[e0+7][c] = bb.w;
    }
    __syncthreads();
    bf16x8 vf[2], kf[4];
    #pragma unroll
    for (int et = 0; et < 2; ++et)
      vf[et] = *(const bf16x8*)&vvT[wid*32 + et*16 + lr][q*8];
    #pragma unroll
    for (int dt = 0; dt < 4; ++dt)
      kf[dt] = *(const bf16x8*)&kdT[dt*16 + lr][q*8];
    #pragma unroll
    for (int et = 0; et < 2; ++et)
      #pragma unroll
      for (int dt = 0; dt < 4; ++dt) {
        f32x4 dl = __builtin_amdgcn_mfma_f32_16x16x32_bf16(vf[et], kf[dt],
                     (f32x4){0.f,0.f,0.f,0.f}, 0, 0, 0);
        float dv = dec_[dt*16 + lr];
        #pragma unroll
        for (int j = 0; j < 4; ++j)
          s_reg[et][dt][j] = fmaf(s_reg[et][dt][j], dv, dl[j]);
      }
  }
  const size_t base = ((size_t)((b*H_ + h)*NSEG + seg)) * (DK_*DV_);
  #pragma unroll
  for (int et = 0; et < 2; ++et)
    #pragma unroll
    for (int dt = 0; dt < 4; ++dt)
      #pragma unroll
      for (int j = 0; j < 4; ++j)
        Sseg[base + (size_t)(wid*32 + et*16 + q*4 + j) * 64 + dt*16 + lr] = s_reg[et][dt][j];
  if (t < 64)
    Dseg[(size_t)((b*H_ + h)*NSEG + seg) * DK_ + t] = expf(gt);
}

// ---------------- GLA phase B: sequential combine over segments (Sseg is [e][d]) ----------
__global__ __launch_bounds__(256) void gla_combine(float* __restrict__ Sseg,
                                                   const float* __restrict__ Dseg) {
  const int bh = blockIdx.x;
  const int t = threadIdx.x;
  __shared__ float Dl[64];
  float4 S_run[8];
  #pragma unroll
  for (int j = 0; j < 8; ++j) S_run[j] = (float4){0.f,0.f,0.f,0.f};
  const int d0 = (t * 4) & 63;
  for (int seg = 0; seg < NSEG; ++seg) {
    const size_t base = ((size_t)bh*NSEG + seg) * (DK_*DV_);
    if (t < 64) Dl[t] = Dseg[((size_t)bh*NSEG + seg) * DK_ + t];
    __syncthreads();
    #pragma unroll
    for (int j = 0; j < 8; ++j) {
      int idx = j*1024 + t*4;
      float4 sl = *reinterpret_cast<float4*>(&Sseg[base + idx]);
      *reinterpret_cast<float4*>(&Sseg[base + idx]) = S_run[j];
      S_run[j].x = fmaf(Dl[d0+0], S_run[j].x, sl.x);
      S_run[j].y = fmaf(Dl[d0+1], S_run[j].y, sl.y);
      S_run[j].z = fmaf(Dl[d0+2], S_run[j].z, sl.z);
      S_run[j].w = fmaf(Dl[d0+3], S_run[j].w, sl.w);
    }
    __syncthreads();
  }
}

// ---------------- GLA phase C (MFMA): outputs + state march + fused RMSNorm/SiLU epilogue -
__global__ __launch_bounds__(256) void gla_phase_c(const float* __restrict__ qk,
                                                   const unsigned short* __restrict__ vg,
                                                   const float* __restrict__ gk,
                                                   const float* __restrict__ Sseg,
                                                   const float* __restrict__ norm_w,
                                                   unsigned short* __restrict__ yb) {
  const int seg = blockIdx.x & 15;
  const int h   = (blockIdx.x >> 4) & 15;
  const int b   = blockIdx.x >> 8;
  const int t    = threadIdx.x;
  const int lane = t & 63;
  const int wid  = t >> 6;
  const int q    = lane >> 4;
  const int lr   = lane & 15;
  __shared__ float gc[16][68];
  __shared__ float dec_[64];
  __shared__ unsigned short qe[16][72];    // [c][d]
  __shared__ unsigned short ke[16][72];    // [m][d]
  __shared__ unsigned short kdT[64][40];   // [d][c], c>=16 zero
  __shared__ unsigned short vvT[128][40];  // [e][c], c>=16 zero
  __shared__ unsigned short Am[16][40];    // [c][m], m>=16 zero
  __shared__ unsigned short Sb[128][72];   // [e][d] bf16 shadow of S^T
  __shared__ float ss_lds[4][16];          // per-wave row sum-of-squares partials
  __shared__ float nw[128];                // norm_w

  for (int i = t; i < 1024; i += 256) kdT[i >> 4][16 + (i & 15)] = 0;
  for (int i = t; i < 2048; i += 256) vvT[i >> 4][16 + (i & 15)] = 0;
  if (t < 256) { int c = t >> 4, m = t & 15; Am[c][16 + m] = 0; }
  if (t < 128) nw[t] = norm_w[t];

  f32x4 s_reg[2][4];
  const size_t sbase = ((size_t)((b*H_ + h)*NSEG + seg)) * (DK_*DV_);
  #pragma unroll
  for (int et = 0; et < 2; ++et)
    #pragma unroll
    for (int dt = 0; dt < 4; ++dt)
      #pragma unroll
      for (int j = 0; j < 4; ++j) {
        int e = wid*32 + et*16 + q*4 + j, d = dt*16 + lr;
        float v = Sseg[sbase + (size_t)e * 64 + d];
        s_reg[et][dt][j] = v;
        Sb[e][d] = f2bf(v);
      }

  for (int c8 = 0; c8 < NCHUNK/NSEG; ++c8) {
    const int ch = seg * (NCHUNK/NSEG) + c8;
    __syncthreads();
    {
      float acc = 0.f;
      #pragma unroll
      for (int c = 0; c < CC; ++c) {
        acc += gk[((size_t)(b*T_ + ch*CC + c)) * 1024 + h*DK_ + lane];
        gc[c][lane] = acc;
      }
      dec_[lane] = expf(acc);
    }
    __syncthreads();
    {
      int c = t >> 4, d0 = (t & 15) * 4;
      const size_t gbq = ((size_t)(b*T_ + ch*CC + c)) * 2048 + h*DK_ + d0;
      float4 q4 = *reinterpret_cast<const float4*>(&qk[gbq]);
      float4 k4 = *reinterpret_cast<const float4*>(&qk[gbq + 1024]);
      float qa[4] = {q4.x, q4.y, q4.z, q4.w};
      float ka[4] = {k4.x, k4.y, k4.z, k4.w};
      ushort4 qw, kw;
      unsigned short* qwp = (unsigned short*)&qw;
      unsigned short* kwp = (unsigned short*)&kw;
      #pragma unroll
      for (int j = 0; j < 4; ++j) {
        float gcv = gc[c][d0 + j];
        float gl  = gc[CC-1][d0 + j];
        qwp[j] = f2bf(qa[j] * expf(gcv) * SCALE_);
        kwp[j] = f2bf(ka[j] * expf(-gcv));
        kdT[d0 + j][c] = f2bf(ka[j] * expf(gl - gcv));
      }
      *reinterpret_cast<ushort4*>(&qe[c][d0]) = qw;
      *reinterpret_cast<ushort4*>(&ke[c][d0]) = kw;
    }
    {
      int c = t & 15, e0 = (t >> 4) * 8;
      const ushort4* vp = reinterpret_cast<const ushort4*>(
          &vg[((size_t)(b*T_ + ch*CC + c)) * 4096 + h*DV_ + e0]);
      ushort4 a = vp[0], bb = vp[1];
      vvT[e0+0][c] = a.x;  vvT[e0+1][c] = a.y;  vvT[e0+2][c] = a.z;  vvT[e0+3][c] = a.w;
      vvT[e0+4][c] = bb.x; vvT[e0+5][c] = bb.y; vvT[e0+6][c] = bb.z; vvT[e0+7][c] = bb.w;
    }
    __syncthreads();
    bf16x8 qA0 = *(const bf16x8*)&qe[lr][q*8];
    bf16x8 qA1 = *(const bf16x8*)&qe[lr][32 + q*8];
    {
      bf16x8 kB0 = *(const bf16x8*)&ke[lr][q*8];
      bf16x8 kB1 = *(const bf16x8*)&ke[lr][32 + q*8];
      f32x4 accA = __builtin_amdgcn_mfma_f32_16x16x32_bf16(qA0, kB0,
                     (f32x4){0.f,0.f,0.f,0.f}, 0, 0, 0);
      accA = __builtin_amdgcn_mfma_f32_16x16x32_bf16(qA1, kB1, accA, 0, 0, 0);
      #pragma unroll
      for (int j = 0; j < 4; ++j) {
        int c = q*4 + j;
        Am[c][lr] = (lr <= c) ? f2bf(accA[j]) : (unsigned short)0;
      }
    }
    bf16x8 vf[2], kf[4];
    #pragma unroll
    for (int et = 0; et < 2; ++et)
      vf[et] = *(const bf16x8*)&vvT[wid*32 + et*16 + lr][q*8];
    #pragma unroll
    for (int dt = 0; dt < 4; ++dt)
      kf[dt] = *(const bf16x8*)&kdT[dt*16 + lr][q*8];
    #pragma unroll
    for (int et = 0; et < 2; ++et)
      #pragma unroll
      for (int dt = 0; dt < 4; ++dt) {
        f32x4 dl = __builtin_amdgcn_mfma_f32_16x16x32_bf16(vf[et], kf[dt],
                     (f32x4){0.f,0.f,0.f,0.f}, 0, 0, 0);
        float dv = dec_[dt*16 + lr];
        #pragma unroll
        for (int j = 0; j < 4; ++j)
          s_reg[et][dt][j] = fmaf(s_reg[et][dt][j], dv, dl[j]);
      }
    __syncthreads();   // Am ready; Sb still holds S_in for this chunk
    // o = qe @ S_in + Am @ v, then fused RMSNorm * norm_w * SiLU(g) -> yb (bf16)
    {
      bf16x8 amA = *(const bf16x8*)&Am[lr][q*8];
      f32x4 accO[2];
      #pragma unroll
      for (int et = 0; et < 2; ++et) {
        int e0 = wid*32 + et*16;
        bf16x8 sB0 = *(const bf16x8*)&Sb[e0 + lr][q*8];
        bf16x8 sB1 = *(const bf16x8*)&Sb[e0 + lr][32 + q*8];
        accO[et] = __builtin_amdgcn_mfma_f32_16x16x32_bf16(qA0, sB0,
                     (f32x4){0.f,0.f,0.f,0.f}, 0, 0, 0);
        accO[et] = __builtin_amdgcn_mfma_f32_16x16x32_bf16(qA1, sB1, accO[et], 0, 0, 0);
        accO[et] = __builtin_amdgcn_mfma_f32_16x16x32_bf16(amA, vf[et], accO[et], 0, 0, 0);
      }
      // per-row sum of squares: lane covers rows q*4+j at cols {wid*32+lr, wid*32+16+lr}
      #pragma unroll
      for (int j = 0; j < 4; ++j) {
        float pj = accO[0][j]*accO[0][j] + accO[1][j]*accO[1][j];
        pj += __shfl_xor(pj, 1, 64);
        pj += __shfl_xor(pj, 2, 64);
        pj += __shfl_xor(pj, 4, 64);
        pj += __shfl_xor(pj, 8, 64);
        if (lr == 0) ss_lds[wid][q*4 + j] = pj;
      }
      __syncthreads();
      #pragma unroll
      for (int j = 0; j < 4; ++j) {
        int r = q*4 + j;
        float tot = ss_lds[0][r] + ss_lds[1][r] + ss_lds[2][r] + ss_lds[3][r];
        float inv = rsqrtf(tot * (1.f/128.f) + 1e-5f);
        const size_t rowg = (size_t)(b*T_ + ch*CC + r);
        #pragma unroll
        for (int et = 0; et < 2; ++et) {
          int e = wid*32 + et*16 + lr;
          float gv = bf2f(vg[rowg * 4096 + 2048 + h*DV_ + e]);
          float si = gv / (1.f + expf(-gv));
          yb[rowg * 2048 + h*DV_ + e] = f2bf(accO[et][j] * inv * nw[e] * si);
        }
      }
    }
    __syncthreads();   // all Sb reads + ss_lds use done -> safe to refresh shadow
    #pragma unroll
    for (int et = 0; et < 2; ++et)
      #pragma unroll
      for (int dt = 0; dt < 4; ++dt)
        #pragma unroll
        for (int j = 0; j < 4; ++j)
          Sb[wid*32 + et*16 + q*4 + j][dt*16 + lr] = f2bf(s_reg[et][dt][j]);
  }
}

// ------------------------------------------------------------------------------------------
extern "C" void kernel_launch(void* const* d_in, const int* in_sizes, int n_in,
                              void* d_out, int out_size, void* d_ws, size_t ws_size,
                              hipStream_t stream) {
  const float* x      = (const float*)d_in[0];
  const float* Wq     = (const float*)d_in[1];
  const float* Wk     = (const float*)d_in[2];
  const float* Wv     = (const float*)d_in[3];
  const float* Wg     = (const float*)d_in[4];
  const float* Wgk1   = (const float*)d_in[5];
  const float* Wgk2   = (const float*)d_in[6];
  const float* bgk2   = (const float*)d_in[7];
  const float* Wo     = (const float*)d_in[8];
  const float* norm_w = (const float*)d_in[9];
  float* out = (float*)d_out;
  float* ws  = (float*)d_ws;

  // ws layout (float-element offsets)
  float*          qk   = ws;                               // f32 [M][2048] q|k  [0, 8388608)
  float*          gkb  = ws + 8388608;                     // f32 [M][1024]      [8388608, 12582912)
  unsigned short* vg   = (unsigned short*)(ws + 12582912); // bf16 [M][4096] v|g [12582912, 20971520)
  float*          wbuf = ws + 20971520;                    // transient weights / yb region
  float*          Sseg = ws + 29360128;                    // f32 [B*H*NSEG][128e][64d]
  float*          Dseg = ws + 33554432;                    // 32768 f32
  unsigned short* WoT  = (unsigned short*)(ws + 33652736); // bf16 [2048][2048] (dedicated)

  // lifetime-disjoint aliases (stream order makes these safe)
  unsigned short* xb   = (unsigned short*)gkb;             // dead before lr writes gkb
  unsigned short* WqkT = (unsigned short*)wbuf;            // dead after qk GEMM
  unsigned short* WvgT = (unsigned short*)(wbuf + 2097152);// dead after vg GEMM
  unsigned short* yb   = (unsigned short*)wbuf;            // written by phase_c (WqkT/WvgT dead)

  dim3 blk(256);
  // convert x + all 5 weight transposes in one dispatch
  prep_kernel<<<dim3(24576), blk, 0, stream>>>(x, xb, Wq, Wk, Wv, Wg, Wo, WqkT, WvgT, WoT);
  // projections
  gemm256x128<false><<<dim3(2048/128, 4096/256), dim3(512), 0, stream>>>(xb, WqkT, qk, M_, 2048, HID_);
  gemm256<true     ><<<dim3(4096/256, 4096/256), dim3(512), 0, stream>>>(xb, WvgT, vg, M_, 4096, HID_);
  // gate path (after GEMMs: gkb overwrites xb)
  lr_kernel<<<M_, blk, 0, stream>>>(x, Wgk1, Wgk2, bgk2, gkb);
  // GLA scan
  gla_phase_a<<<B_*H_*NSEG, blk, 0, stream>>>(qk, vg, gkb, Sseg, Dseg);
  gla_combine<<<B_*H_, blk, 0, stream>>>(Sseg, Dseg);
  // phase C with fused RMSNorm/SiLU epilogue -> yb (bf16)
  gla_phase_c<<<B_*H_*NSEG, blk, 0, stream>>>(qk, vg, gkb, Sseg, norm_w, yb);
  // output projection
  gemm256x128<false><<<dim3(2048/128, 4096/256), dim3(512), 0, stream>>>(yb, WoT, out, M_, HID_, HID_);
}